// Round 1
// baseline (681.205 us; speedup 1.0000x reference)
//
#include <hip/hip_runtime.h>
#include <math.h>

#define THREADS 256

// ---------------- problem constants (fixed by reference setup) ----------------
constexpr int NLEV  = 5;
constexpr int NB    = 16;     // batch
constexpr int NC    = 80;     // classes (label = c+1)
constexpr int TOPN  = 300;
constexpr int KC    = NLEV * TOPN;   // 1500 candidates per image
constexpr int KROWS = 1536;          // padded rows for NMS bitmask
constexpr int WORDS = 24;            // 1536 / 64
constexpr int POSTN = 100;
constexpr int CAP   = 4096;          // per-(b,level) candidate pool
constexpr int NBINS = 2048;          // score-histogram bins over [0.25, 1.0)
constexpr int NPAIR = NLEV * NB;     // 80

constexpr int HW0 = 12800, HW1 = 3200, HW2 = 800, HW3 = 208, HW4 = 56;
constexpr int CH0 = 63, CH1 = 16, CH2 = 4, CH3 = 2, CH4 = 1;  // 16384-elem chunks per (b,level)
constexpr int CHUNKS = CH0 + CH1 + CH2 + CH3 + CH4;           // 86
constexpr int CHUNK_ELEMS = 16384;

// ---------------- workspace layout ----------------
constexpr size_t align256(size_t x) { return (x + 255) & ~(size_t)255; }
constexpr size_t OFF_HIST = 0;
constexpr size_t OFF_T    = OFF_HIST + (size_t)NPAIR * NBINS * 4;
constexpr size_t OFF_CNT  = OFF_T + (size_t)NPAIR * 4;
constexpr size_t OFF_CAND = align256(OFF_CNT + (size_t)NPAIR * 4);
constexpr size_t OFF_CBOX = align256(OFF_CAND + (size_t)NPAIR * CAP * 8);
constexpr size_t OFF_CSC  = align256(OFF_CBOX + (size_t)NB * KC * 4 * 4);
constexpr size_t OFF_CLB  = align256(OFF_CSC  + (size_t)NB * KC * 4);
constexpr size_t OFF_SSC  = align256(OFF_CLB  + (size_t)NB * KC * 4);
constexpr size_t OFF_SLB  = align256(OFF_SSC  + (size_t)NB * KC * 4);
constexpr size_t OFF_SBOX = align256(OFF_SLB  + (size_t)NB * KC * 4);
constexpr size_t OFF_OBOX = align256(OFF_SBOX + (size_t)NB * KC * 4 * 4);
constexpr size_t OFF_M    = align256(OFF_OBOX + (size_t)NB * KC * 4 * 4);
// total ~9.6 MB

struct Cand { float s; int i; };

// ---------------- helpers ----------------
__device__ __forceinline__ float sigm(float x) { return 1.0f / (1.0f + expf(-x)); }

// monotone key over score in (0,1): 2048 bins over [0.25,1.0), everything below -> bin 0
__device__ __forceinline__ unsigned scoreKey(float s) {
    unsigned b = __float_as_uint(s);
    return (b < 0x3E800000u) ? 0u : ((b - 0x3E800000u) >> 13);
}

__device__ void bitonicShared(float* ss, int* si, int N) {
    for (int k = 2; k <= N; k <<= 1) {
        for (int j = k >> 1; j > 0; j >>= 1) {
            __syncthreads();
            for (int i = threadIdx.x; i < N; i += THREADS) {
                int ixj = i ^ j;
                if (ixj > i) {
                    float s1 = ss[i], s2 = ss[ixj];
                    int a1 = si[i], a2 = si[ixj];
                    bool bef = (s1 > s2) || (s1 == s2 && a1 < a2);   // desc, idx asc
                    bool up = ((i & k) == 0);
                    if (up ? !bef : bef) { ss[i] = s2; ss[ixj] = s1; si[i] = a2; si[ixj] = a1; }
                }
            }
        }
    }
    __syncthreads();
}

// ---------------- K0: zero hist + counters ----------------
__global__ void k_zero(unsigned* p, int n) {
    int i = blockIdx.x * THREADS + threadIdx.x;
    if (i < n) p[i] = 0;
}

// ---------------- K1: histogram ----------------
template<int HW>
__device__ __forceinline__ void histChunk(int chunkLocal, int b,
        const float* __restrict__ cls, const float* __restrict__ ctr, unsigned* __restrict__ h) {
    constexpr int NE = HW * NC;
    int base = chunkLocal * CHUNK_ELEMS;
    int eend = min(base + CHUNK_ELEMS, NE);
    const float* cp = cls + (size_t)b * NE;
    const float* tp = ctr + (size_t)b * HW;
    for (int e = base + threadIdx.x; e < eend; e += THREADS) {
        int c = e / HW; int hw = e - c * HW;
        float scls = sigm(cp[e]);
        if (scls > 0.05f) {
            float s = __fmul_rn(scls, sigm(tp[hw]));
            unsigned key = scoreKey(s);
            if (key) atomicAdd(&h[key], 1u);   // skip hot bin0 (never reaches threshold)
        }
    }
}

__global__ __launch_bounds__(THREADS) void k_hist(
        const float* c0, const float* c1, const float* c2, const float* c3, const float* c4,
        const float* t0, const float* t1, const float* t2, const float* t3, const float* t4,
        unsigned* ghist) {
    __shared__ unsigned h[NBINS];
    for (int k = threadIdx.x; k < NBINS; k += THREADS) h[k] = 0;
    __syncthreads();
    int cx = blockIdx.x, b = blockIdx.y;
    int li;
    if (cx < CH0)                 { histChunk<HW0>(cx, b, c0, t0, h); li = 0; }
    else if (cx < CH0+CH1)        { histChunk<HW1>(cx-CH0, b, c1, t1, h); li = 1; }
    else if (cx < CH0+CH1+CH2)    { histChunk<HW2>(cx-CH0-CH1, b, c2, t2, h); li = 2; }
    else if (cx < CH0+CH1+CH2+CH3){ histChunk<HW3>(cx-CH0-CH1-CH2, b, c3, t3, h); li = 3; }
    else                          { histChunk<HW4>(cx-CH0-CH1-CH2-CH3, b, c4, t4, h); li = 4; }
    __syncthreads();
    unsigned* gp = ghist + (size_t)(li * NB + b) * NBINS;
    for (int k = threadIdx.x; k < NBINS; k += THREADS) {
        unsigned v = h[k];
        if (v) atomicAdd(&gp[k], v);
    }
}

// ---------------- K2: find per-(b,level) key threshold ----------------
__global__ __launch_bounds__(THREADS) void k_thresh(const unsigned* __restrict__ ghist, unsigned* __restrict__ T) {
    int pid = blockIdx.x;
    const unsigned* h = ghist + (size_t)pid * NBINS;
    __shared__ unsigned seg[THREADS];
    constexpr int SB = NBINS / THREADS;   // 8
    unsigned s = 0;
    for (int k = 0; k < SB; ++k) s += h[threadIdx.x * SB + k];
    seg[threadIdx.x] = s;
    __syncthreads();
    if (threadIdx.x == 0) {
        unsigned acc = 0; unsigned Tv = 0;
        int t = THREADS - 1;
        for (; t >= 0; --t) {
            if (acc + seg[t] >= (unsigned)TOPN) break;
            acc += seg[t];
        }
        if (t >= 0) {
            int lo = t * SB;
            int bin = lo + SB - 1;
            for (; bin >= lo; --bin) { acc += h[bin]; if (acc >= (unsigned)TOPN) break; }
            Tv = (unsigned)max(bin, lo);
        }
        T[pid] = Tv;   // 0 => collect everything (degenerate, <300 passing)
    }
}

// ---------------- K3: compact candidates >= threshold ----------------
template<int HW>
__device__ __forceinline__ void collectChunk(int chunkLocal, int b, int li,
        const float* __restrict__ cls, const float* __restrict__ ctr,
        const unsigned* __restrict__ T, Cand* __restrict__ candAll, unsigned* __restrict__ cnt) {
    constexpr int NE = HW * NC;
    int pid = li * NB + b;
    unsigned Tv = T[pid];
    Cand* cd = candAll + (size_t)pid * CAP;
    int base = chunkLocal * CHUNK_ELEMS;
    int eend = min(base + CHUNK_ELEMS, NE);
    const float* cp = cls + (size_t)b * NE;
    const float* tp = ctr + (size_t)b * HW;
    for (int e = base + threadIdx.x; e < eend; e += THREADS) {
        int c = e / HW; int hw = e - c * HW;
        float scls = sigm(cp[e]);
        if (scls > 0.05f) {
            float s = __fmul_rn(scls, sigm(tp[hw]));
            unsigned key = scoreKey(s);
            if (key >= Tv) {
                unsigned slot = atomicAdd(&cnt[pid], 1u);
                if (slot < (unsigned)CAP) { cd[slot].s = s; cd[slot].i = hw * NC + c; }
            }
        }
    }
}

__global__ __launch_bounds__(THREADS) void k_collect(
        const float* c0, const float* c1, const float* c2, const float* c3, const float* c4,
        const float* t0, const float* t1, const float* t2, const float* t3, const float* t4,
        const unsigned* T, Cand* cand, unsigned* cnt) {
    int cx = blockIdx.x, b = blockIdx.y;
    if (cx < CH0)                  collectChunk<HW0>(cx, b, 0, c0, t0, T, cand, cnt);
    else if (cx < CH0+CH1)         collectChunk<HW1>(cx-CH0, b, 1, c1, t1, T, cand, cnt);
    else if (cx < CH0+CH1+CH2)     collectChunk<HW2>(cx-CH0-CH1, b, 2, c2, t2, T, cand, cnt);
    else if (cx < CH0+CH1+CH2+CH3) collectChunk<HW3>(cx-CH0-CH1-CH2, b, 3, c3, t3, T, cand, cnt);
    else                           collectChunk<HW4>(cx-CH0-CH1-CH2-CH3, b, 4, c4, t4, T, cand, cnt);
}

// ---------------- K4: exact top-300 per (b,level) + decode ----------------
__global__ __launch_bounds__(THREADS) void k_select(
        const Cand* __restrict__ candAll, const unsigned* __restrict__ cntAll,
        const float* l0, const float* l1, const float* l2, const float* l3, const float* l4,
        const float* b0, const float* b1, const float* b2, const float* b3, const float* b4,
        float* __restrict__ cbox, float* __restrict__ csc, int* __restrict__ clb) {
    __shared__ float ss[CAP];
    __shared__ int si[CAP];
    int pid = blockIdx.x;
    int li = pid / NB, b = pid - li * NB;
    int n = (int)min(cntAll[pid], (unsigned)CAP);
    const Cand* cd = candAll + (size_t)pid * CAP;
    int N = 2; while (N < n) N <<= 1;
    for (int k = threadIdx.x; k < N; k += THREADS) {
        if (k < n) { ss[k] = cd[k].s; si[k] = cd[k].i; }
        else       { ss[k] = -INFINITY; si[k] = 0x40000000 + k; }
    }
    __syncthreads();
    bitonicShared(ss, si, N);

    const float* locp; const float* boxp; int HW;
    switch (li) {
        case 0: locp = l0; boxp = b0; HW = HW0; break;
        case 1: locp = l1; boxp = b1; HW = HW1; break;
        case 2: locp = l2; boxp = b2; HW = HW2; break;
        case 3: locp = l3; boxp = b3; HW = HW3; break;
        default: locp = l4; boxp = b4; HW = HW4; break;
    }
    for (int j = threadIdx.x; j < TOPN; j += THREADS) {
        int cidx = b * KC + li * TOPN + j;
        bool ok = (j < n);
        float s = ok ? ss[j] : -INFINITY;
        ok = ok && (s > 0.0f);
        if (ok) {
            int idx = si[j];
            int hw = idx / NC, c = idx - hw * NC;
            float lx = locp[hw * 2 + 0], ly = locp[hw * 2 + 1];
            const float* bp = boxp + (size_t)b * 4 * HW + hw;
            float bl = bp[0], bt = bp[HW], br = bp[2 * HW], bb = bp[3 * HW];
            float x1 = fminf(fmaxf(__fsub_rn(lx, bl), 0.0f), 1023.0f);
            float y1 = fminf(fmaxf(__fsub_rn(ly, bt), 0.0f),  799.0f);
            float x2 = fminf(fmaxf(__fadd_rn(lx, br), 0.0f), 1023.0f);
            float y2 = fminf(fmaxf(__fadd_rn(ly, bb), 0.0f),  799.0f);
            cbox[cidx * 4 + 0] = x1; cbox[cidx * 4 + 1] = y1;
            cbox[cidx * 4 + 2] = x2; cbox[cidx * 4 + 3] = y2;
            csc[cidx] = sqrtf(fmaxf(s, 1e-12f));
            clb[cidx] = c + 1;
        } else {
            cbox[cidx * 4 + 0] = 0.0f; cbox[cidx * 4 + 1] = 0.0f;
            cbox[cidx * 4 + 2] = 0.0f; cbox[cidx * 4 + 3] = 0.0f;
            csc[cidx] = -INFINITY;
            clb[cidx] = 0;
        }
    }
}

// ---------------- K5a: per-image sort by score desc ----------------
__global__ __launch_bounds__(THREADS) void k_sortimg(
        const float* __restrict__ csc, const int* __restrict__ clb, const float* __restrict__ cbox,
        float* __restrict__ ssc, int* __restrict__ slb, float* __restrict__ sbox, float* __restrict__ obox) {
    int b = blockIdx.x;
    __shared__ float ss[2048];
    __shared__ int si[2048];
    for (int k = threadIdx.x; k < 2048; k += THREADS) {
        if (k < KC) { ss[k] = csc[b * KC + k]; si[k] = k; }
        else        { ss[k] = -INFINITY; si[k] = 0x40000000 + k; }
    }
    __syncthreads();
    bitonicShared(ss, si, 2048);
    for (int k = threadIdx.x; k < KC; k += THREADS) {
        int sl = si[k];                 // all 1500 real entries sort before pads
        int src = b * KC + sl;
        int dst = b * KC + k;
        float sc = ss[k];
        int lab = clb[src];
        ssc[dst] = sc; slb[dst] = lab;
        float off = __fmul_rn((float)lab, 1025.0f);   // offset = max(800,1024)+1
        #pragma unroll
        for (int q = 0; q < 4; ++q) {
            float v = cbox[src * 4 + q];
            sbox[dst * 4 + q] = v;
            obox[dst * 4 + q] = __fadd_rn(v, off);
        }
    }
}

// ---------------- K5b: suppression bitmask (iou > 0.6 && j > i) ----------------
__global__ __launch_bounds__(THREADS) void k_iou(const float* __restrict__ obox,
                                                 unsigned long long* __restrict__ M) {
    int b = blockIdx.y, tile = blockIdx.x;
    __shared__ float4 cb[KC];
    __shared__ float car[KC];
    const float4* op = (const float4*)obox + (size_t)b * KC;
    for (int j = threadIdx.x; j < KC; j += THREADS) {
        float4 v = op[j];
        cb[j] = v;
        car[j] = __fmul_rn(__fsub_rn(v.z, v.x), __fsub_rn(v.w, v.y));
    }
    __syncthreads();
    for (int task = threadIdx.x; task < 64 * WORDS; task += THREADS) {
        int r = task / WORDS, w = task - (task / WORDS) * WORDS;
        int i = tile * 64 + r;
        unsigned long long bits = 0;
        if (i < KC) {
            float4 bi = cb[i]; float ai = car[i];
            int j0 = w * 64;
            if (j0 + 63 > i) {
                int j1 = min(j0 + 64, KC);
                for (int j = max(j0, i + 1); j < j1; ++j) {
                    float4 bj = cb[j];
                    float xx1 = fmaxf(bi.x, bj.x), yy1 = fmaxf(bi.y, bj.y);
                    float xx2 = fminf(bi.z, bj.z), yy2 = fminf(bi.w, bj.w);
                    float ww = fmaxf(__fsub_rn(xx2, xx1), 0.0f);
                    float hh = fmaxf(__fsub_rn(yy2, yy1), 0.0f);
                    float inter = __fmul_rn(ww, hh);
                    float uni = __fsub_rn(__fadd_rn(ai, car[j]), inter);
                    float iou = __fdiv_rn(inter, fmaxf(uni, 1e-9f));
                    if (iou > 0.6f) bits |= (1ull << (j - j0));
                }
            }
        }
        M[((size_t)b * KROWS + i) * WORDS + w] = bits;
    }
}

// ---------------- K5c: sequential greedy scan (1 wave/image) + emit ----------------
__global__ __launch_bounds__(64) void k_nms(
        const unsigned long long* __restrict__ M, const float* __restrict__ ssc,
        const int* __restrict__ slb, const float* __restrict__ sbox, float* __restrict__ out) {
    int b = blockIdx.x, lane = threadIdx.x;
    // zero-fill this image's output slices (d_out is poisoned before every launch)
    for (int k = lane; k < POSTN * 5; k += 64) out[(size_t)b * POSTN * 5 + k] = 0.0f;
    for (int k = lane; k < POSTN; k += 64) {
        out[(size_t)NB * POSTN * 5 + b * POSTN + k] = 0.0f;                 // labels
        out[(size_t)NB * POSTN * 5 + NB * POSTN + b * POSTN + k] = 0.0f;    // valid
    }
    // valid bitmask (lane l holds word l); invalid entries start "removed"
    const float* sp = ssc + b * KC;
    unsigned long long myValid = 0;
    for (int c = 0; c < WORDS; ++c) {
        int i = c * 64 + lane;
        bool f = (i < KC) && (sp[i] > 0.0f);
        unsigned long long m = __ballot(f);
        if (lane == c) myValid = m;
    }
    unsigned long long removed = ~myValid;
    unsigned long long keepW = 0;
    __syncthreads();

    const unsigned long long* Mb = M + (size_t)b * KROWS * WORDS + (lane < WORDS ? lane : WORDS - 1);
    auto ld = [&](int i) { return Mb[(size_t)i * WORDS]; };
    unsigned long long p0 = ld(0), p1 = ld(1), p2 = ld(2), p3 = ld(3);
    auto step = [&](int i, unsigned long long row) {
        int w = i >> 6, bb = i & 63;
        unsigned long long rm = __shfl(removed, w);
        bool keep = ((rm >> bb) & 1ull) == 0ull;
        removed |= keep ? row : 0ull;
        if (keep && lane == w) keepW |= (1ull << bb);
    };
    for (int i = 0; i < KC; i += 4) {      // rows up to 1503 prefetched; KROWS=1536 allocated
        step(i + 0, p0); p0 = ld(i + 4);
        step(i + 1, p1); p1 = ld(i + 5);
        step(i + 2, p2); p2 = ld(i + 6);
        step(i + 3, p3); p3 = ld(i + 7);
    }
    // emit first 100 kept in score order
    int base = 0;
    for (int c = 0; c < WORDS && base < POSTN; ++c) {
        unsigned long long kw = __shfl(keepW, c);
        bool f = (kw >> lane) & 1ull;
        int rank = base + __popcll(kw & ((1ull << lane) - 1ull));
        if (f && rank < POSTN) {
            int i = c * 64 + lane;
            int src = b * KC + i;
            float* o5 = out + ((size_t)b * POSTN + rank) * 5;
            o5[0] = sbox[src * 4 + 0]; o5[1] = sbox[src * 4 + 1];
            o5[2] = sbox[src * 4 + 2]; o5[3] = sbox[src * 4 + 3];
            o5[4] = ssc[src];
            out[(size_t)NB * POSTN * 5 + b * POSTN + rank] = (float)slb[src];
            out[(size_t)NB * POSTN * 5 + NB * POSTN + b * POSTN + rank] = 1.0f;
        }
        base += __popcll(kw);
    }
}

// ---------------- launch ----------------
extern "C" void kernel_launch(void* const* d_in, const int* in_sizes, int n_in,
                              void* d_out, int out_size, void* d_ws, size_t ws_size,
                              hipStream_t stream) {
    // setup_inputs dict order: per level: location, cls, box, ctr; then img_h, img_w
    const float *loc[5], *cls[5], *box[5], *ctr[5];
    for (int l = 0; l < 5; ++l) {
        loc[l] = (const float*)d_in[l * 4 + 0];
        cls[l] = (const float*)d_in[l * 4 + 1];
        box[l] = (const float*)d_in[l * 4 + 2];
        ctr[l] = (const float*)d_in[l * 4 + 3];
    }
    char* ws = (char*)d_ws;
    unsigned* hist = (unsigned*)(ws + OFF_HIST);
    unsigned* T    = (unsigned*)(ws + OFF_T);
    unsigned* cnt  = (unsigned*)(ws + OFF_CNT);
    Cand* cand     = (Cand*)(ws + OFF_CAND);
    float* cbox    = (float*)(ws + OFF_CBOX);
    float* csc     = (float*)(ws + OFF_CSC);
    int*   clb     = (int*)(ws + OFF_CLB);
    float* ssc     = (float*)(ws + OFF_SSC);
    int*   slb     = (int*)(ws + OFF_SLB);
    float* sbox    = (float*)(ws + OFF_SBOX);
    float* obox    = (float*)(ws + OFF_OBOX);
    unsigned long long* M = (unsigned long long*)(ws + OFF_M);
    float* out = (float*)d_out;

    int zn = (int)(OFF_CAND / 4);
    k_zero<<<(zn + THREADS - 1) / THREADS, THREADS, 0, stream>>>((unsigned*)ws, zn);
    k_hist<<<dim3(CHUNKS, NB), THREADS, 0, stream>>>(
        cls[0], cls[1], cls[2], cls[3], cls[4],
        ctr[0], ctr[1], ctr[2], ctr[3], ctr[4], hist);
    k_thresh<<<NPAIR, THREADS, 0, stream>>>(hist, T);
    k_collect<<<dim3(CHUNKS, NB), THREADS, 0, stream>>>(
        cls[0], cls[1], cls[2], cls[3], cls[4],
        ctr[0], ctr[1], ctr[2], ctr[3], ctr[4], T, cand, cnt);
    k_select<<<NPAIR, THREADS, 0, stream>>>(
        cand, cnt,
        loc[0], loc[1], loc[2], loc[3], loc[4],
        box[0], box[1], box[2], box[3], box[4],
        cbox, csc, clb);
    k_sortimg<<<NB, THREADS, 0, stream>>>(csc, clb, cbox, ssc, slb, sbox, obox);
    k_iou<<<dim3(WORDS, NB), THREADS, 0, stream>>>(obox, M);
    k_nms<<<NB, 64, 0, stream>>>(M, ssc, slb, sbox, out);
}

// Round 2
// 607.118 us; speedup vs baseline: 1.1220x; 1.1220x over previous
//
#include <hip/hip_runtime.h>
#include <math.h>

#define THREADS 256
#define SORTT 1024

// ---------------- problem constants (fixed by reference setup) ----------------
constexpr int NLEV  = 5;
constexpr int NB    = 16;     // batch
constexpr int NC    = 80;     // classes (label = c+1)
constexpr int TOPN  = 300;
constexpr int KC    = NLEV * TOPN;   // 1500 candidates per image
constexpr int KROWS = 1536;          // padded rows for NMS bitmask
constexpr int WORDS = 24;            // 1536 / 64
constexpr int POSTN = 100;
constexpr int CAP   = 4096;          // per-(b,level) candidate pool
constexpr int NBINS = 2048;          // score-histogram bins over [0.25, 1.0)
constexpr int NPAIR = NLEV * NB;     // 80

constexpr int HW0 = 12800, HW1 = 3200, HW2 = 800, HW3 = 208, HW4 = 56;
constexpr int CH0 = 63, CH1 = 16, CH2 = 4, CH3 = 2, CH4 = 1;  // 16384-elem chunks per (b,level)
constexpr int CHUNKS = CH0 + CH1 + CH2 + CH3 + CH4;           // 86
constexpr int CHUNK_ELEMS = 16384;

// ---------------- workspace layout ----------------
constexpr size_t align256(size_t x) { return (x + 255) & ~(size_t)255; }
constexpr size_t OFF_HIST = 0;
constexpr size_t OFF_T    = OFF_HIST + (size_t)NPAIR * NBINS * 4;
constexpr size_t OFF_CNT  = OFF_T + (size_t)NPAIR * 4;
constexpr size_t OFF_CAND = align256(OFF_CNT + (size_t)NPAIR * 4);
constexpr size_t OFF_CBOX = align256(OFF_CAND + (size_t)NPAIR * CAP * 8);
constexpr size_t OFF_CSC  = align256(OFF_CBOX + (size_t)NB * KC * 4 * 4);
constexpr size_t OFF_CLB  = align256(OFF_CSC  + (size_t)NB * KC * 4);
constexpr size_t OFF_SSC  = align256(OFF_CLB  + (size_t)NB * KC * 4);
constexpr size_t OFF_SLB  = align256(OFF_SSC  + (size_t)NB * KC * 4);
constexpr size_t OFF_SBOX = align256(OFF_SLB  + (size_t)NB * KC * 4);
constexpr size_t OFF_OBOX = align256(OFF_SBOX + (size_t)NB * KC * 4 * 4);
constexpr size_t OFF_M    = align256(OFF_OBOX + (size_t)NB * KC * 4 * 4);
// total ~9.6 MB

struct Cand { float s; int i; };

// ---------------- helpers ----------------
__device__ __forceinline__ float sigm(float x) { return 1.0f / (1.0f + expf(-x)); }

// monotone key over score in (0,1): 2048 bins over [0.25,1.0), everything below -> bin 0
__device__ __forceinline__ unsigned scoreKey(float s) {
    unsigned b = __float_as_uint(s);
    unsigned k = (b < 0x3E800000u) ? 0u : ((b - 0x3E800000u) >> 13);
    return (k > 2047u) ? 2047u : k;
}

__device__ void bitonicShared(float* ss, int* si, int N) {
    for (int k = 2; k <= N; k <<= 1) {
        for (int j = k >> 1; j > 0; j >>= 1) {
            __syncthreads();
            for (int i = threadIdx.x; i < N; i += blockDim.x) {
                int ixj = i ^ j;
                if (ixj > i) {
                    float s1 = ss[i], s2 = ss[ixj];
                    int a1 = si[i], a2 = si[ixj];
                    bool bef = (s1 > s2) || (s1 == s2 && a1 < a2);   // desc, idx asc
                    bool up = ((i & k) == 0);
                    if (up ? !bef : bef) { ss[i] = s2; ss[ixj] = s1; si[i] = a2; si[ixj] = a1; }
                }
            }
        }
    }
    __syncthreads();
}

// ---------------- K0: zero hist + counters ----------------
__global__ void k_zero(unsigned* p, int n) {
    int i = blockIdx.x * THREADS + threadIdx.x;
    if (i < n) p[i] = 0;
}

// ---------------- K1: histogram ----------------
template<int HW>
__device__ __forceinline__ void histChunk(int chunkLocal, int b,
        const float* __restrict__ cls, const float* __restrict__ ctr, unsigned* __restrict__ h) {
    constexpr int NE = HW * NC;
    int base = chunkLocal * CHUNK_ELEMS;
    int eend = min(base + CHUNK_ELEMS, NE);
    const float* cp = cls + (size_t)b * NE;
    const float* tp = ctr + (size_t)b * HW;
    for (int e = base + threadIdx.x; e < eend; e += THREADS) {
        int c = e / HW; int hw = e - c * HW;
        float scls = sigm(cp[e]);
        if (scls > 0.05f) {
            float s = __fmul_rn(scls, sigm(tp[hw]));
            unsigned key = scoreKey(s);
            if (key) atomicAdd(&h[key], 1u);   // skip hot bin0 (never reaches threshold)
        }
    }
}

__global__ __launch_bounds__(THREADS) void k_hist(
        const float* c0, const float* c1, const float* c2, const float* c3, const float* c4,
        const float* t0, const float* t1, const float* t2, const float* t3, const float* t4,
        unsigned* ghist) {
    __shared__ unsigned h[NBINS];
    for (int k = threadIdx.x; k < NBINS; k += THREADS) h[k] = 0;
    __syncthreads();
    int cx = blockIdx.x, b = blockIdx.y;
    int li;
    if (cx < CH0)                 { histChunk<HW0>(cx, b, c0, t0, h); li = 0; }
    else if (cx < CH0+CH1)        { histChunk<HW1>(cx-CH0, b, c1, t1, h); li = 1; }
    else if (cx < CH0+CH1+CH2)    { histChunk<HW2>(cx-CH0-CH1, b, c2, t2, h); li = 2; }
    else if (cx < CH0+CH1+CH2+CH3){ histChunk<HW3>(cx-CH0-CH1-CH2, b, c3, t3, h); li = 3; }
    else                          { histChunk<HW4>(cx-CH0-CH1-CH2-CH3, b, c4, t4, h); li = 4; }
    __syncthreads();
    unsigned* gp = ghist + (size_t)(li * NB + b) * NBINS;
    for (int k = threadIdx.x; k < NBINS; k += THREADS) {
        unsigned v = h[k];
        if (v) atomicAdd(&gp[k], v);
    }
}

// ---------------- K2: find per-(b,level) key threshold ----------------
__global__ __launch_bounds__(THREADS) void k_thresh(const unsigned* __restrict__ ghist, unsigned* __restrict__ T) {
    int pid = blockIdx.x;
    const unsigned* h = ghist + (size_t)pid * NBINS;
    __shared__ unsigned seg[THREADS];
    constexpr int SB = NBINS / THREADS;   // 8
    unsigned s = 0;
    for (int k = 0; k < SB; ++k) s += h[threadIdx.x * SB + k];
    seg[threadIdx.x] = s;
    __syncthreads();
    if (threadIdx.x == 0) {
        unsigned acc = 0; unsigned Tv = 0;
        int t = THREADS - 1;
        for (; t >= 0; --t) {
            if (acc + seg[t] >= (unsigned)TOPN) break;
            acc += seg[t];
        }
        if (t >= 0) {
            int lo = t * SB;
            int bin = lo + SB - 1;
            for (; bin >= lo; --bin) { acc += h[bin]; if (acc >= (unsigned)TOPN) break; }
            Tv = (unsigned)max(bin, lo);
        }
        T[pid] = Tv;   // 0 => collect everything (degenerate, <300 passing)
    }
}

// ---------------- K3: compact candidates >= threshold (LDS-staged) ----------------
constexpr int LBUF = 1024;

template<int HW>
__device__ __forceinline__ void collectChunk(int chunkLocal, int b, int li,
        const float* __restrict__ cls, const float* __restrict__ ctr,
        const unsigned* __restrict__ T, Cand* __restrict__ candAll, unsigned* __restrict__ cnt,
        Cand* __restrict__ lbuf, unsigned* __restrict__ lcnt) {
    constexpr int NE = HW * NC;
    int pid = li * NB + b;
    unsigned Tv = T[pid];
    Cand* cd = candAll + (size_t)pid * CAP;
    int base = chunkLocal * CHUNK_ELEMS;
    int eend = min(base + CHUNK_ELEMS, NE);
    const float* cp = cls + (size_t)b * NE;
    const float* tp = ctr + (size_t)b * HW;
    for (int e = base + threadIdx.x; e < eend; e += THREADS) {
        int c = e / HW; int hw = e - c * HW;
        float scls = sigm(cp[e]);
        if (scls > 0.05f) {
            float s = __fmul_rn(scls, sigm(tp[hw]));
            unsigned key = scoreKey(s);
            if (key >= Tv) {
                unsigned slot = atomicAdd(lcnt, 1u);
                if (slot < (unsigned)LBUF) { lbuf[slot].s = s; lbuf[slot].i = hw * NC + c; }
                else {
                    unsigned gs = atomicAdd(&cnt[pid], 1u);   // rare fallback
                    if (gs < (unsigned)CAP) { cd[gs].s = s; cd[gs].i = hw * NC + c; }
                }
            }
        }
    }
}

__global__ __launch_bounds__(THREADS) void k_collect(
        const float* c0, const float* c1, const float* c2, const float* c3, const float* c4,
        const float* t0, const float* t1, const float* t2, const float* t3, const float* t4,
        const unsigned* T, Cand* cand, unsigned* cnt) {
    __shared__ Cand lbuf[LBUF];
    __shared__ unsigned lcnt, gbase;
    if (threadIdx.x == 0) lcnt = 0;
    __syncthreads();
    int cx = blockIdx.x, b = blockIdx.y;
    int li;
    if (cx < CH0)                 { collectChunk<HW0>(cx, b, 0, c0, t0, T, cand, cnt, lbuf, &lcnt); li = 0; }
    else if (cx < CH0+CH1)        { collectChunk<HW1>(cx-CH0, b, 1, c1, t1, T, cand, cnt, lbuf, &lcnt); li = 1; }
    else if (cx < CH0+CH1+CH2)    { collectChunk<HW2>(cx-CH0-CH1, b, 2, c2, t2, T, cand, cnt, lbuf, &lcnt); li = 2; }
    else if (cx < CH0+CH1+CH2+CH3){ collectChunk<HW3>(cx-CH0-CH1-CH2, b, 3, c3, t3, T, cand, cnt, lbuf, &lcnt); li = 3; }
    else                          { collectChunk<HW4>(cx-CH0-CH1-CH2-CH3, b, 4, c4, t4, T, cand, cnt, lbuf, &lcnt); li = 4; }
    __syncthreads();
    int pid = li * NB + b;
    unsigned n = lcnt; if (n > (unsigned)LBUF) n = LBUF;
    if (threadIdx.x == 0) gbase = n ? atomicAdd(&cnt[pid], n) : 0u;
    __syncthreads();
    Cand* cd = cand + (size_t)pid * CAP;
    for (unsigned i = threadIdx.x; i < n; i += THREADS) {
        unsigned s = gbase + i;
        if (s < (unsigned)CAP) cd[s] = lbuf[i];
    }
}

// ---------------- K4: exact top-300 per (b,level) + decode ----------------
__global__ __launch_bounds__(THREADS) void k_select(
        const Cand* __restrict__ candAll, const unsigned* __restrict__ cntAll,
        const float* l0, const float* l1, const float* l2, const float* l3, const float* l4,
        const float* b0, const float* b1, const float* b2, const float* b3, const float* b4,
        float* __restrict__ cbox, float* __restrict__ csc, int* __restrict__ clb) {
    __shared__ float ss[CAP];
    __shared__ int si[CAP];
    int pid = blockIdx.x;
    int li = pid / NB, b = pid - li * NB;
    int n = (int)min(cntAll[pid], (unsigned)CAP);
    const Cand* cd = candAll + (size_t)pid * CAP;
    int N = 2; while (N < n) N <<= 1;
    for (int k = threadIdx.x; k < N; k += THREADS) {
        if (k < n) { ss[k] = cd[k].s; si[k] = cd[k].i; }
        else       { ss[k] = -INFINITY; si[k] = 0x40000000 + k; }
    }
    __syncthreads();
    bitonicShared(ss, si, N);

    const float* locp; const float* boxp; int HW;
    switch (li) {
        case 0: locp = l0; boxp = b0; HW = HW0; break;
        case 1: locp = l1; boxp = b1; HW = HW1; break;
        case 2: locp = l2; boxp = b2; HW = HW2; break;
        case 3: locp = l3; boxp = b3; HW = HW3; break;
        default: locp = l4; boxp = b4; HW = HW4; break;
    }
    for (int j = threadIdx.x; j < TOPN; j += THREADS) {
        int cidx = b * KC + li * TOPN + j;
        bool ok = (j < n);
        float s = ok ? ss[j] : -INFINITY;
        ok = ok && (s > 0.0f);
        if (ok) {
            int idx = si[j];
            int hw = idx / NC, c = idx - hw * NC;
            float lx = locp[hw * 2 + 0], ly = locp[hw * 2 + 1];
            const float* bp = boxp + (size_t)b * 4 * HW + hw;
            float bl = bp[0], bt = bp[HW], br = bp[2 * HW], bb = bp[3 * HW];
            float x1 = fminf(fmaxf(__fsub_rn(lx, bl), 0.0f), 1023.0f);
            float y1 = fminf(fmaxf(__fsub_rn(ly, bt), 0.0f),  799.0f);
            float x2 = fminf(fmaxf(__fadd_rn(lx, br), 0.0f), 1023.0f);
            float y2 = fminf(fmaxf(__fadd_rn(ly, bb), 0.0f),  799.0f);
            cbox[cidx * 4 + 0] = x1; cbox[cidx * 4 + 1] = y1;
            cbox[cidx * 4 + 2] = x2; cbox[cidx * 4 + 3] = y2;
            csc[cidx] = sqrtf(fmaxf(s, 1e-12f));
            clb[cidx] = c + 1;
        } else {
            cbox[cidx * 4 + 0] = 0.0f; cbox[cidx * 4 + 1] = 0.0f;
            cbox[cidx * 4 + 2] = 0.0f; cbox[cidx * 4 + 3] = 0.0f;
            csc[cidx] = -INFINITY;
            clb[cidx] = 0;
        }
    }
}

// ---------------- K5a: per-image sort by score desc (1024 threads) ----------------
__global__ __launch_bounds__(SORTT) void k_sortimg(
        const float* __restrict__ csc, const int* __restrict__ clb, const float* __restrict__ cbox,
        float* __restrict__ ssc, int* __restrict__ slb, float* __restrict__ sbox, float* __restrict__ obox) {
    int b = blockIdx.x;
    __shared__ float ss[2048];
    __shared__ int si[2048];
    for (int k = threadIdx.x; k < 2048; k += SORTT) {
        if (k < KC) { ss[k] = csc[b * KC + k]; si[k] = k; }
        else        { ss[k] = -INFINITY; si[k] = 0x40000000 + k; }
    }
    __syncthreads();
    bitonicShared(ss, si, 2048);
    for (int k = threadIdx.x; k < KC; k += SORTT) {
        int sl = si[k];                 // all 1500 real entries sort before pads
        int src = b * KC + sl;
        int dst = b * KC + k;
        float sc = ss[k];
        int lab = clb[src];
        ssc[dst] = sc; slb[dst] = lab;
        float off = __fmul_rn((float)lab, 1025.0f);   // offset = max(800,1024)+1
        #pragma unroll
        for (int q = 0; q < 4; ++q) {
            float v = cbox[src * 4 + q];
            sbox[dst * 4 + q] = v;
            obox[dst * 4 + q] = __fadd_rn(v, off);
        }
    }
}

// ---------------- K5b: suppression bitmask (iou > 0.6 && j > i) ----------------
__global__ __launch_bounds__(THREADS) void k_iou(const float* __restrict__ obox,
                                                 unsigned long long* __restrict__ M) {
    int b = blockIdx.y, tile = blockIdx.x;
    __shared__ float4 cb[KC];
    __shared__ float car[KC];
    const float4* op = (const float4*)obox + (size_t)b * KC;
    for (int j = threadIdx.x; j < KC; j += THREADS) {
        float4 v = op[j];
        cb[j] = v;
        car[j] = __fmul_rn(__fsub_rn(v.z, v.x), __fsub_rn(v.w, v.y));
    }
    __syncthreads();
    for (int task = threadIdx.x; task < 64 * WORDS; task += THREADS) {
        int r = task / WORDS, w = task - (task / WORDS) * WORDS;
        int i = tile * 64 + r;
        unsigned long long bits = 0;
        if (i < KC) {
            float4 bi = cb[i]; float ai = car[i];
            int j0 = w * 64;
            if (j0 + 63 > i) {
                int j1 = min(j0 + 64, KC);
                for (int j = max(j0, i + 1); j < j1; ++j) {
                    float4 bj = cb[j];
                    float xx1 = fmaxf(bi.x, bj.x), yy1 = fmaxf(bi.y, bj.y);
                    float xx2 = fminf(bi.z, bj.z), yy2 = fminf(bi.w, bj.w);
                    float ww = fmaxf(__fsub_rn(xx2, xx1), 0.0f);
                    float hh = fmaxf(__fsub_rn(yy2, yy1), 0.0f);
                    float inter = __fmul_rn(ww, hh);
                    float uni = __fsub_rn(__fadd_rn(ai, car[j]), inter);
                    float iou = __fdiv_rn(inter, fmaxf(uni, 1e-9f));
                    if (iou > 0.6f) bits |= (1ull << (j - j0));
                }
            }
        }
        M[((size_t)b * KROWS + i) * WORDS + w] = bits;
    }
}

// ---------------- K5c: tile-parallel greedy scan (1 wave/image) + emit ----------------
__global__ __launch_bounds__(64) void k_nms(
        const unsigned long long* __restrict__ M, const float* __restrict__ ssc,
        const int* __restrict__ slb, const float* __restrict__ sbox, float* __restrict__ out) {
    int b = blockIdx.x, lane = threadIdx.x;
    // zero-fill this image's output slices (d_out is poisoned before every launch)
    for (int k = lane; k < POSTN * 5; k += 64) out[(size_t)b * POSTN * 5 + k] = 0.0f;
    for (int k = lane; k < POSTN; k += 64) {
        out[(size_t)NB * POSTN * 5 + b * POSTN + k] = 0.0f;                 // labels
        out[(size_t)NB * POSTN * 5 + NB * POSTN + b * POSTN + k] = 0.0f;    // valid
    }
    // removed-bitmask: lane w (w<WORDS) owns candidates [64w, 64w+64); invalid start removed
    const float* sp = ssc + b * KC;
    unsigned long long removed = ~0ull;
    for (int c = 0; c < WORDS; ++c) {
        int i = c * 64 + lane;
        bool f = (i < KC) && (sp[i] > 0.0f);
        unsigned long long m = __ballot(f);
        if (lane == c) removed = ~m;
    }
    unsigned long long keepW = 0;
    const unsigned long long* Mb = M + (size_t)b * KROWS * WORDS;
    int mylane = (lane < WORDS) ? lane : 0;   // clamp for safe (unused) loads on idle lanes

    // prefetch tile 0 diagonal word: row 64*0+lane, word 0
    unsigned long long D = Mb[(size_t)lane * WORDS + 0];

    for (int t = 0; t < WORDS; ++t) {
        // prefetch next tile's diagonal word
        unsigned long long Dnext = 0;
        if (t + 1 < WORDS) Dnext = Mb[(size_t)((t + 1) * 64 + lane) * WORDS + (t + 1)];

        // --- Phase A: intra-tile greedy over kept rows only (register/shfl only) ---
        unsigned long long rem = __shfl(removed, t);
        unsigned long long kept = 0;
        unsigned long long todo = ~rem;
        while (todo) {
            int r = __builtin_ctzll(todo);
            kept |= 1ull << r;
            unsigned long long Dr = __shfl(D, r);   // row r's intra-tile suppression bits (j>r only)
            rem |= Dr;
            todo &= ~(rem | (1ull << r));
        }
        if (lane == t) { removed = rem; keepW = kept; }

        // --- Phase B: OR kept rows' masks into all later words (parallel over lanes) ---
        unsigned long long acc = 0;
        const unsigned long long* rp = Mb + (size_t)(t * 64) * WORDS + mylane;
        #pragma unroll
        for (int g = 0; g < 2; ++g) {
            unsigned gm = (unsigned)(kept >> (g * 32));
            if (gm) {
                unsigned long long v[32];
                #pragma unroll
                for (int q = 0; q < 32; ++q) v[q] = rp[(size_t)(g * 32 + q) * WORDS];
                #pragma unroll
                for (int q = 0; q < 32; ++q) acc |= ((gm >> q) & 1u) ? v[q] : 0ull;
            }
        }
        removed |= acc;
        D = Dnext;
    }

    // emit first 100 kept in score order
    int base = 0;
    for (int c = 0; c < WORDS && base < POSTN; ++c) {
        unsigned long long kw = __shfl(keepW, c);
        bool f = (kw >> lane) & 1ull;
        int rank = base + __popcll(kw & ((1ull << lane) - 1ull));
        if (f && rank < POSTN) {
            int i = c * 64 + lane;
            int src = b * KC + i;
            float* o5 = out + ((size_t)b * POSTN + rank) * 5;
            o5[0] = sbox[src * 4 + 0]; o5[1] = sbox[src * 4 + 1];
            o5[2] = sbox[src * 4 + 2]; o5[3] = sbox[src * 4 + 3];
            o5[4] = ssc[src];
            out[(size_t)NB * POSTN * 5 + b * POSTN + rank] = (float)slb[src];
            out[(size_t)NB * POSTN * 5 + NB * POSTN + b * POSTN + rank] = 1.0f;
        }
        base += __popcll(kw);
    }
}

// ---------------- launch ----------------
extern "C" void kernel_launch(void* const* d_in, const int* in_sizes, int n_in,
                              void* d_out, int out_size, void* d_ws, size_t ws_size,
                              hipStream_t stream) {
    // setup_inputs dict order: per level: location, cls, box, ctr; then img_h, img_w
    const float *loc[5], *cls[5], *box[5], *ctr[5];
    for (int l = 0; l < 5; ++l) {
        loc[l] = (const float*)d_in[l * 4 + 0];
        cls[l] = (const float*)d_in[l * 4 + 1];
        box[l] = (const float*)d_in[l * 4 + 2];
        ctr[l] = (const float*)d_in[l * 4 + 3];
    }
    char* ws = (char*)d_ws;
    unsigned* hist = (unsigned*)(ws + OFF_HIST);
    unsigned* T    = (unsigned*)(ws + OFF_T);
    unsigned* cnt  = (unsigned*)(ws + OFF_CNT);
    Cand* cand     = (Cand*)(ws + OFF_CAND);
    float* cbox    = (float*)(ws + OFF_CBOX);
    float* csc     = (float*)(ws + OFF_CSC);
    int*   clb     = (int*)(ws + OFF_CLB);
    float* ssc     = (float*)(ws + OFF_SSC);
    int*   slb     = (int*)(ws + OFF_SLB);
    float* sbox    = (float*)(ws + OFF_SBOX);
    float* obox    = (float*)(ws + OFF_OBOX);
    unsigned long long* M = (unsigned long long*)(ws + OFF_M);
    float* out = (float*)d_out;

    int zn = (int)(OFF_CAND / 4);
    k_zero<<<(zn + THREADS - 1) / THREADS, THREADS, 0, stream>>>((unsigned*)ws, zn);
    k_hist<<<dim3(CHUNKS, NB), THREADS, 0, stream>>>(
        cls[0], cls[1], cls[2], cls[3], cls[4],
        ctr[0], ctr[1], ctr[2], ctr[3], ctr[4], hist);
    k_thresh<<<NPAIR, THREADS, 0, stream>>>(hist, T);
    k_collect<<<dim3(CHUNKS, NB), THREADS, 0, stream>>>(
        cls[0], cls[1], cls[2], cls[3], cls[4],
        ctr[0], ctr[1], ctr[2], ctr[3], ctr[4], T, cand, cnt);
    k_select<<<NPAIR, THREADS, 0, stream>>>(
        cand, cnt,
        loc[0], loc[1], loc[2], loc[3], loc[4],
        box[0], box[1], box[2], box[3], box[4],
        cbox, csc, clb);
    k_sortimg<<<NB, SORTT, 0, stream>>>(csc, clb, cbox, ssc, slb, sbox, obox);
    k_iou<<<dim3(WORDS, NB), THREADS, 0, stream>>>(obox, M);
    k_nms<<<NB, 64, 0, stream>>>(M, ssc, slb, sbox, out);
}

// Round 3
// 485.717 us; speedup vs baseline: 1.4025x; 1.2499x over previous
//
#include <hip/hip_runtime.h>
#include <math.h>

#define THREADS 256
#define SORTT 1024

// ---------------- problem constants (fixed by reference setup) ----------------
constexpr int NLEV  = 5;
constexpr int NB    = 16;     // batch
constexpr int NC    = 80;     // classes (label = c+1)
constexpr int TOPN  = 300;
constexpr int KC    = NLEV * TOPN;   // 1500 candidates per image
constexpr int KROWS = 1536;          // padded rows for NMS bitmask
constexpr int WORDS = 24;            // 1536 / 64
constexpr int POSTN = 100;
constexpr int CAP   = 4096;          // per-(b,level) candidate pool
constexpr int NBINS = 2048;          // score-histogram bins over [0.25, 1.0)
constexpr int NPAIR = NLEV * NB;     // 80

constexpr int HW0 = 12800, HW1 = 3200, HW2 = 800, HW3 = 208, HW4 = 56;
constexpr int CH0 = 63, CH1 = 16, CH2 = 4, CH3 = 2, CH4 = 1;  // 16384-elem chunks per (b,level)
constexpr int CHUNKS = CH0 + CH1 + CH2 + CH3 + CH4;           // 86
constexpr int CHUNK_ELEMS = 16384;

// ---------------- workspace layout ----------------
constexpr size_t align256(size_t x) { return (x + 255) & ~(size_t)255; }
constexpr size_t OFF_HIST = 0;
constexpr size_t OFF_T    = OFF_HIST + (size_t)NPAIR * NBINS * 4;
constexpr size_t OFF_CNT  = OFF_T + (size_t)NPAIR * 4;
constexpr size_t OFF_CAND = align256(OFF_CNT + (size_t)NPAIR * 4);
constexpr size_t OFF_CBOX = align256(OFF_CAND + (size_t)NPAIR * CAP * 8);
constexpr size_t OFF_CSC  = align256(OFF_CBOX + (size_t)NB * KC * 4 * 4);
constexpr size_t OFF_CLB  = align256(OFF_CSC  + (size_t)NB * KC * 4);
constexpr size_t OFF_SSC  = align256(OFF_CLB  + (size_t)NB * KC * 4);
constexpr size_t OFF_SLB  = align256(OFF_SSC  + (size_t)NB * KC * 4);
constexpr size_t OFF_SBOX = align256(OFF_SLB  + (size_t)NB * KC * 4);
constexpr size_t OFF_OBOX = align256(OFF_SBOX + (size_t)NB * KC * 4 * 4);
constexpr size_t OFF_M    = align256(OFF_OBOX + (size_t)NB * KC * 4 * 4);
// total ~9.6 MB

struct Cand { float s; int i; };

// ---------------- helpers ----------------
__device__ __forceinline__ float sigm(float x) { return 1.0f / (1.0f + expf(-x)); }

// monotone key over score in (0,1): 2048 bins over [0.25,1.0), everything below -> bin 0
__device__ __forceinline__ unsigned scoreKey(float s) {
    unsigned b = __float_as_uint(s);
    unsigned k = (b < 0x3E800000u) ? 0u : ((b - 0x3E800000u) >> 13);
    return (k > 2047u) ? 2047u : k;
}

__device__ __forceinline__ unsigned long long readlane64(unsigned long long v, int l) {
    unsigned lo = (unsigned)__builtin_amdgcn_readlane((int)(unsigned)(v & 0xffffffffull), l);
    unsigned hi = (unsigned)__builtin_amdgcn_readlane((int)(unsigned)(v >> 32), l);
    return ((unsigned long long)hi << 32) | lo;
}

__device__ void bitonicShared(float* ss, int* si, int N) {
    for (int k = 2; k <= N; k <<= 1) {
        for (int j = k >> 1; j > 0; j >>= 1) {
            __syncthreads();
            for (int i = threadIdx.x; i < N; i += blockDim.x) {
                int ixj = i ^ j;
                if (ixj > i) {
                    float s1 = ss[i], s2 = ss[ixj];
                    int a1 = si[i], a2 = si[ixj];
                    bool bef = (s1 > s2) || (s1 == s2 && a1 < a2);   // desc, idx asc
                    bool up = ((i & k) == 0);
                    if (up ? !bef : bef) { ss[i] = s2; ss[ixj] = s1; si[i] = a2; si[ixj] = a1; }
                }
            }
        }
    }
    __syncthreads();
}

// ---------------- K0: zero hist + counters ----------------
__global__ void k_zero(unsigned* p, int n) {
    int i = blockIdx.x * THREADS + threadIdx.x;
    if (i < n) p[i] = 0;
}

// ---------------- K1: histogram ----------------
template<int HW>
__device__ __forceinline__ void histChunk(int chunkLocal, int b,
        const float* __restrict__ cls, const float* __restrict__ ctr, unsigned* __restrict__ h) {
    constexpr int NE = HW * NC;
    int base = chunkLocal * CHUNK_ELEMS;
    int eend = min(base + CHUNK_ELEMS, NE);
    const float* cp = cls + (size_t)b * NE;
    const float* tp = ctr + (size_t)b * HW;
    for (int e = base + threadIdx.x; e < eend; e += THREADS) {
        int c = e / HW; int hw = e - c * HW;
        float scls = sigm(cp[e]);
        if (scls > 0.05f) {
            float s = __fmul_rn(scls, sigm(tp[hw]));
            unsigned key = scoreKey(s);
            if (key) atomicAdd(&h[key], 1u);   // skip hot bin0 (never reaches threshold)
        }
    }
}

__global__ __launch_bounds__(THREADS) void k_hist(
        const float* c0, const float* c1, const float* c2, const float* c3, const float* c4,
        const float* t0, const float* t1, const float* t2, const float* t3, const float* t4,
        unsigned* ghist) {
    __shared__ unsigned h[NBINS];
    for (int k = threadIdx.x; k < NBINS; k += THREADS) h[k] = 0;
    __syncthreads();
    int cx = blockIdx.x, b = blockIdx.y;
    int li;
    if (cx < CH0)                 { histChunk<HW0>(cx, b, c0, t0, h); li = 0; }
    else if (cx < CH0+CH1)        { histChunk<HW1>(cx-CH0, b, c1, t1, h); li = 1; }
    else if (cx < CH0+CH1+CH2)    { histChunk<HW2>(cx-CH0-CH1, b, c2, t2, h); li = 2; }
    else if (cx < CH0+CH1+CH2+CH3){ histChunk<HW3>(cx-CH0-CH1-CH2, b, c3, t3, h); li = 3; }
    else                          { histChunk<HW4>(cx-CH0-CH1-CH2-CH3, b, c4, t4, h); li = 4; }
    __syncthreads();
    unsigned* gp = ghist + (size_t)(li * NB + b) * NBINS;
    for (int k = threadIdx.x; k < NBINS; k += THREADS) {
        unsigned v = h[k];
        if (v) atomicAdd(&gp[k], v);
    }
}

// ---------------- K2: find per-(b,level) key threshold ----------------
__global__ __launch_bounds__(THREADS) void k_thresh(const unsigned* __restrict__ ghist, unsigned* __restrict__ T) {
    int pid = blockIdx.x;
    const unsigned* h = ghist + (size_t)pid * NBINS;
    __shared__ unsigned seg[THREADS];
    constexpr int SB = NBINS / THREADS;   // 8
    unsigned s = 0;
    for (int k = 0; k < SB; ++k) s += h[threadIdx.x * SB + k];
    seg[threadIdx.x] = s;
    __syncthreads();
    if (threadIdx.x == 0) {
        unsigned acc = 0; unsigned Tv = 0;
        int t = THREADS - 1;
        for (; t >= 0; --t) {
            if (acc + seg[t] >= (unsigned)TOPN) break;
            acc += seg[t];
        }
        if (t >= 0) {
            int lo = t * SB;
            int bin = lo + SB - 1;
            for (; bin >= lo; --bin) { acc += h[bin]; if (acc >= (unsigned)TOPN) break; }
            Tv = (unsigned)max(bin, lo);
        }
        T[pid] = Tv;   // 0 => collect everything (degenerate, <300 passing)
    }
}

// ---------------- K3: compact candidates >= threshold (LDS-staged) ----------------
constexpr int LBUF = 1024;

template<int HW>
__device__ __forceinline__ void collectChunk(int chunkLocal, int b, int li,
        const float* __restrict__ cls, const float* __restrict__ ctr,
        const unsigned* __restrict__ T, Cand* __restrict__ candAll, unsigned* __restrict__ cnt,
        Cand* __restrict__ lbuf, unsigned* __restrict__ lcnt) {
    constexpr int NE = HW * NC;
    int pid = li * NB + b;
    unsigned Tv = T[pid];
    Cand* cd = candAll + (size_t)pid * CAP;
    int base = chunkLocal * CHUNK_ELEMS;
    int eend = min(base + CHUNK_ELEMS, NE);
    const float* cp = cls + (size_t)b * NE;
    const float* tp = ctr + (size_t)b * HW;
    for (int e = base + threadIdx.x; e < eend; e += THREADS) {
        int c = e / HW; int hw = e - c * HW;
        float scls = sigm(cp[e]);
        if (scls > 0.05f) {
            float s = __fmul_rn(scls, sigm(tp[hw]));
            unsigned key = scoreKey(s);
            if (key >= Tv) {
                unsigned slot = atomicAdd(lcnt, 1u);
                if (slot < (unsigned)LBUF) { lbuf[slot].s = s; lbuf[slot].i = hw * NC + c; }
                else {
                    unsigned gs = atomicAdd(&cnt[pid], 1u);   // rare fallback
                    if (gs < (unsigned)CAP) { cd[gs].s = s; cd[gs].i = hw * NC + c; }
                }
            }
        }
    }
}

__global__ __launch_bounds__(THREADS) void k_collect(
        const float* c0, const float* c1, const float* c2, const float* c3, const float* c4,
        const float* t0, const float* t1, const float* t2, const float* t3, const float* t4,
        const unsigned* T, Cand* cand, unsigned* cnt) {
    __shared__ Cand lbuf[LBUF];
    __shared__ unsigned lcnt, gbase;
    if (threadIdx.x == 0) lcnt = 0;
    __syncthreads();
    int cx = blockIdx.x, b = blockIdx.y;
    int li;
    if (cx < CH0)                 { collectChunk<HW0>(cx, b, 0, c0, t0, T, cand, cnt, lbuf, &lcnt); li = 0; }
    else if (cx < CH0+CH1)        { collectChunk<HW1>(cx-CH0, b, 1, c1, t1, T, cand, cnt, lbuf, &lcnt); li = 1; }
    else if (cx < CH0+CH1+CH2)    { collectChunk<HW2>(cx-CH0-CH1, b, 2, c2, t2, T, cand, cnt, lbuf, &lcnt); li = 2; }
    else if (cx < CH0+CH1+CH2+CH3){ collectChunk<HW3>(cx-CH0-CH1-CH2, b, 3, c3, t3, T, cand, cnt, lbuf, &lcnt); li = 3; }
    else                          { collectChunk<HW4>(cx-CH0-CH1-CH2-CH3, b, 4, c4, t4, T, cand, cnt, lbuf, &lcnt); li = 4; }
    __syncthreads();
    int pid = li * NB + b;
    unsigned n = lcnt; if (n > (unsigned)LBUF) n = LBUF;
    if (threadIdx.x == 0) gbase = n ? atomicAdd(&cnt[pid], n) : 0u;
    __syncthreads();
    Cand* cd = cand + (size_t)pid * CAP;
    for (unsigned i = threadIdx.x; i < n; i += THREADS) {
        unsigned s = gbase + i;
        if (s < (unsigned)CAP) cd[s] = lbuf[i];
    }
}

// ---------------- K4: exact top-300 per (b,level) + decode ----------------
__global__ __launch_bounds__(THREADS) void k_select(
        const Cand* __restrict__ candAll, const unsigned* __restrict__ cntAll,
        const float* l0, const float* l1, const float* l2, const float* l3, const float* l4,
        const float* b0, const float* b1, const float* b2, const float* b3, const float* b4,
        float* __restrict__ cbox, float* __restrict__ csc, int* __restrict__ clb) {
    __shared__ float ss[CAP];
    __shared__ int si[CAP];
    int pid = blockIdx.x;
    int li = pid / NB, b = pid - li * NB;
    int n = (int)min(cntAll[pid], (unsigned)CAP);
    const Cand* cd = candAll + (size_t)pid * CAP;
    int N = 2; while (N < n) N <<= 1;
    for (int k = threadIdx.x; k < N; k += THREADS) {
        if (k < n) { ss[k] = cd[k].s; si[k] = cd[k].i; }
        else       { ss[k] = -INFINITY; si[k] = 0x40000000 + k; }
    }
    __syncthreads();
    bitonicShared(ss, si, N);

    const float* locp; const float* boxp; int HW;
    switch (li) {
        case 0: locp = l0; boxp = b0; HW = HW0; break;
        case 1: locp = l1; boxp = b1; HW = HW1; break;
        case 2: locp = l2; boxp = b2; HW = HW2; break;
        case 3: locp = l3; boxp = b3; HW = HW3; break;
        default: locp = l4; boxp = b4; HW = HW4; break;
    }
    for (int j = threadIdx.x; j < TOPN; j += THREADS) {
        int cidx = b * KC + li * TOPN + j;
        bool ok = (j < n);
        float s = ok ? ss[j] : -INFINITY;
        ok = ok && (s > 0.0f);
        if (ok) {
            int idx = si[j];
            int hw = idx / NC, c = idx - hw * NC;
            float lx = locp[hw * 2 + 0], ly = locp[hw * 2 + 1];
            const float* bp = boxp + (size_t)b * 4 * HW + hw;
            float bl = bp[0], bt = bp[HW], br = bp[2 * HW], bb = bp[3 * HW];
            float x1 = fminf(fmaxf(__fsub_rn(lx, bl), 0.0f), 1023.0f);
            float y1 = fminf(fmaxf(__fsub_rn(ly, bt), 0.0f),  799.0f);
            float x2 = fminf(fmaxf(__fadd_rn(lx, br), 0.0f), 1023.0f);
            float y2 = fminf(fmaxf(__fadd_rn(ly, bb), 0.0f),  799.0f);
            cbox[cidx * 4 + 0] = x1; cbox[cidx * 4 + 1] = y1;
            cbox[cidx * 4 + 2] = x2; cbox[cidx * 4 + 3] = y2;
            csc[cidx] = sqrtf(fmaxf(s, 1e-12f));
            clb[cidx] = c + 1;
        } else {
            cbox[cidx * 4 + 0] = 0.0f; cbox[cidx * 4 + 1] = 0.0f;
            cbox[cidx * 4 + 2] = 0.0f; cbox[cidx * 4 + 3] = 0.0f;
            csc[cidx] = -INFINITY;
            clb[cidx] = 0;
        }
    }
}

// ---------------- K5a: per-image sort by score desc (1024 threads) ----------------
__global__ __launch_bounds__(SORTT) void k_sortimg(
        const float* __restrict__ csc, const int* __restrict__ clb, const float* __restrict__ cbox,
        float* __restrict__ ssc, int* __restrict__ slb, float* __restrict__ sbox, float* __restrict__ obox) {
    int b = blockIdx.x;
    __shared__ float ss[2048];
    __shared__ int si[2048];
    for (int k = threadIdx.x; k < 2048; k += SORTT) {
        if (k < KC) { ss[k] = csc[b * KC + k]; si[k] = k; }
        else        { ss[k] = -INFINITY; si[k] = 0x40000000 + k; }
    }
    __syncthreads();
    bitonicShared(ss, si, 2048);
    for (int k = threadIdx.x; k < KC; k += SORTT) {
        int sl = si[k];                 // all 1500 real entries sort before pads
        int src = b * KC + sl;
        int dst = b * KC + k;
        float sc = ss[k];
        int lab = clb[src];
        ssc[dst] = sc; slb[dst] = lab;
        float off = __fmul_rn((float)lab, 1025.0f);   // offset = max(800,1024)+1
        #pragma unroll
        for (int q = 0; q < 4; ++q) {
            float v = cbox[src * 4 + q];
            sbox[dst * 4 + q] = v;
            obox[dst * 4 + q] = __fadd_rn(v, off);
        }
    }
}

// ---------------- K5b: suppression bitmask (iou > 0.6 && j > i) ----------------
__global__ __launch_bounds__(THREADS) void k_iou(const float* __restrict__ obox,
                                                 unsigned long long* __restrict__ M) {
    int b = blockIdx.y, tile = blockIdx.x;
    __shared__ float4 cb[KC];
    __shared__ float car[KC];
    const float4* op = (const float4*)obox + (size_t)b * KC;
    for (int j = threadIdx.x; j < KC; j += THREADS) {
        float4 v = op[j];
        cb[j] = v;
        car[j] = __fmul_rn(__fsub_rn(v.z, v.x), __fsub_rn(v.w, v.y));
    }
    __syncthreads();
    for (int task = threadIdx.x; task < 64 * WORDS; task += THREADS) {
        int r = task / WORDS, w = task - (task / WORDS) * WORDS;
        int i = tile * 64 + r;
        unsigned long long bits = 0;
        if (i < KC) {
            float4 bi = cb[i]; float ai = car[i];
            int j0 = w * 64;
            if (j0 + 63 > i) {
                int j1 = min(j0 + 64, KC);
                for (int j = max(j0, i + 1); j < j1; ++j) {
                    float4 bj = cb[j];
                    float xx1 = fmaxf(bi.x, bj.x), yy1 = fmaxf(bi.y, bj.y);
                    float xx2 = fminf(bi.z, bj.z), yy2 = fminf(bi.w, bj.w);
                    float ww = fmaxf(__fsub_rn(xx2, xx1), 0.0f);
                    float hh = fmaxf(__fsub_rn(yy2, yy1), 0.0f);
                    float inter = __fmul_rn(ww, hh);
                    float uni = __fsub_rn(__fadd_rn(ai, car[j]), inter);
                    float iou = __fdiv_rn(inter, fmaxf(uni, 1e-9f));
                    if (iou > 0.6f) bits |= (1ull << (j - j0));
                }
            }
        }
        M[((size_t)b * KROWS + i) * WORDS + w] = bits;
    }
}

// ---------------- K5c: pull-style greedy scan (1 wave/image) + emit ----------------
// Per tile t: (1) lane l batch-loads M[c*64+l][t] for c<t (independent, one latency),
// masks by previous tiles' kept (keptV, via readlane), (2) OR-butterfly -> uniform
// removed word, (3) suppressor-sparse scalar greedy over rows with D!=0 (readlane).
__global__ __launch_bounds__(64) void k_nms(
        const unsigned long long* __restrict__ M, const float* __restrict__ ssc,
        const int* __restrict__ slb, const float* __restrict__ sbox, float* __restrict__ out) {
    int b = blockIdx.x, lane = threadIdx.x;
    // zero-fill this image's output slices (d_out is poisoned before every launch)
    for (int k = lane; k < POSTN * 5; k += 64) out[(size_t)b * POSTN * 5 + k] = 0.0f;
    for (int k = lane; k < POSTN; k += 64) {
        out[(size_t)NB * POSTN * 5 + b * POSTN + k] = 0.0f;                 // labels
        out[(size_t)NB * POSTN * 5 + NB * POSTN + b * POSTN + k] = 0.0f;    // valid
    }
    // validV: lane c holds tile c's valid mask
    const float* sp = ssc + b * KC;
    unsigned long long validV = 0;
    for (int c = 0; c < WORDS; ++c) {
        int i = c * 64 + lane;
        bool f = (i < KC) && (sp[i] > 0.0f);
        unsigned long long m = __ballot(f);
        validV = (lane == c) ? m : validV;
    }
    unsigned long long mybit = 1ull << lane;
    unsigned long long keptV = 0;   // lane c holds tile c's kept mask
    const unsigned long long* Mb = M + (size_t)b * KROWS * WORDS;

    for (int t = 0; t < WORDS; ++t) {
        // batch-issue independent loads: diagonal + all previous chunks' word-t rows
        unsigned long long D = Mb[(size_t)(t * 64 + lane) * WORDS + t];
        unsigned long long v[WORDS - 1];
        #pragma unroll
        for (int c = 0; c < WORDS - 1; ++c) {
            int cc = (c < t) ? c : 0;                      // uniform clamp: no branches around loads
            v[c] = Mb[(size_t)(cc * 64 + lane) * WORDS + t];
        }
        // mask by kept rows of previous tiles
        unsigned long long acc = 0;
        #pragma unroll
        for (int c = 0; c < WORDS - 1; ++c) {
            if (c < t) {
                unsigned long long kc = readlane64(keptV, c);   // uniform
                if (kc & mybit) acc |= v[c];
            }
        }
        // OR-butterfly: every lane ends with the full removed word (uniform)
        #pragma unroll
        for (int s = 1; s < 64; s <<= 1) acc |= __shfl_xor(acc, s, 64);

        unsigned long long validT = readlane64(validV, t);
        unsigned long long rem = acc;
        // suppressor-sparse greedy: only rows with intra-tile bits matter for rem
        unsigned long long sup = __ballot(D != 0ull) & validT;
        unsigned long long todoS = sup;
        while (todoS) {
            int r = __builtin_ctzll(todoS);
            todoS &= todoS - 1;
            if (!((rem >> r) & 1ull)) {
                unsigned long long Dr = readlane64(D, r);
                rem |= Dr;
                todoS &= ~Dr;
            }
        }
        unsigned long long kept = validT & ~rem;   // uniform
        keptV = (lane == t) ? kept : keptV;
    }

    // emit first 100 kept in score order
    int base = 0;
    for (int c = 0; c < WORDS && base < POSTN; ++c) {
        unsigned long long kw = readlane64(keptV, c);
        bool f = (kw & mybit) != 0ull;
        int rank = base + __popcll(kw & (mybit - 1ull));
        if (f && rank < POSTN) {
            int i = c * 64 + lane;
            int src = b * KC + i;
            float* o5 = out + ((size_t)b * POSTN + rank) * 5;
            o5[0] = sbox[src * 4 + 0]; o5[1] = sbox[src * 4 + 1];
            o5[2] = sbox[src * 4 + 2]; o5[3] = sbox[src * 4 + 3];
            o5[4] = ssc[src];
            out[(size_t)NB * POSTN * 5 + b * POSTN + rank] = (float)slb[src];
            out[(size_t)NB * POSTN * 5 + NB * POSTN + b * POSTN + rank] = 1.0f;
        }
        base += __popcll(kw);
    }
}

// ---------------- launch ----------------
extern "C" void kernel_launch(void* const* d_in, const int* in_sizes, int n_in,
                              void* d_out, int out_size, void* d_ws, size_t ws_size,
                              hipStream_t stream) {
    // setup_inputs dict order: per level: location, cls, box, ctr; then img_h, img_w
    const float *loc[5], *cls[5], *box[5], *ctr[5];
    for (int l = 0; l < 5; ++l) {
        loc[l] = (const float*)d_in[l * 4 + 0];
        cls[l] = (const float*)d_in[l * 4 + 1];
        box[l] = (const float*)d_in[l * 4 + 2];
        ctr[l] = (const float*)d_in[l * 4 + 3];
    }
    char* ws = (char*)d_ws;
    unsigned* hist = (unsigned*)(ws + OFF_HIST);
    unsigned* T    = (unsigned*)(ws + OFF_T);
    unsigned* cnt  = (unsigned*)(ws + OFF_CNT);
    Cand* cand     = (Cand*)(ws + OFF_CAND);
    float* cbox    = (float*)(ws + OFF_CBOX);
    float* csc     = (float*)(ws + OFF_CSC);
    int*   clb     = (int*)(ws + OFF_CLB);
    float* ssc     = (float*)(ws + OFF_SSC);
    int*   slb     = (int*)(ws + OFF_SLB);
    float* sbox    = (float*)(ws + OFF_SBOX);
    float* obox    = (float*)(ws + OFF_OBOX);
    unsigned long long* M = (unsigned long long*)(ws + OFF_M);
    float* out = (float*)d_out;

    int zn = (int)(OFF_CAND / 4);
    k_zero<<<(zn + THREADS - 1) / THREADS, THREADS, 0, stream>>>((unsigned*)ws, zn);
    k_hist<<<dim3(CHUNKS, NB), THREADS, 0, stream>>>(
        cls[0], cls[1], cls[2], cls[3], cls[4],
        ctr[0], ctr[1], ctr[2], ctr[3], ctr[4], hist);
    k_thresh<<<NPAIR, THREADS, 0, stream>>>(hist, T);
    k_collect<<<dim3(CHUNKS, NB), THREADS, 0, stream>>>(
        cls[0], cls[1], cls[2], cls[3], cls[4],
        ctr[0], ctr[1], ctr[2], ctr[3], ctr[4], T, cand, cnt);
    k_select<<<NPAIR, THREADS, 0, stream>>>(
        cand, cnt,
        loc[0], loc[1], loc[2], loc[3], loc[4],
        box[0], box[1], box[2], box[3], box[4],
        cbox, csc, clb);
    k_sortimg<<<NB, SORTT, 0, stream>>>(csc, clb, cbox, ssc, slb, sbox, obox);
    k_iou<<<dim3(WORDS, NB), THREADS, 0, stream>>>(obox, M);
    k_nms<<<NB, 64, 0, stream>>>(M, ssc, slb, sbox, out);
}

// Round 4
// 418.119 us; speedup vs baseline: 1.6292x; 1.1617x over previous
//
#include <hip/hip_runtime.h>
#include <math.h>

#define THREADS 256
#define SORTT 1024

// ---------------- problem constants (fixed by reference setup) ----------------
constexpr int NLEV  = 5;
constexpr int NB    = 16;     // batch
constexpr int NC    = 80;     // classes (label = c+1)
constexpr int TOPN  = 300;
constexpr int KC    = NLEV * TOPN;   // 1500 candidates per image
constexpr int KROWS = 1536;          // padded rows for NMS bitmask
constexpr int WORDS = 24;            // 1536 / 64
constexpr int POSTN = 100;
constexpr int CAP   = 4096;          // per-(b,level) candidate pool
constexpr int NBINS = 2048;          // score-histogram bins over [0.25, 1.0)
constexpr int NPAIR = NLEV * NB;     // 80

constexpr int HW0 = 12800, HW1 = 3200, HW2 = 800, HW3 = 208, HW4 = 56;
constexpr int CH0 = 63, CH1 = 16, CH2 = 4, CH3 = 2, CH4 = 1;  // 16384-elem chunks per (b,level)
constexpr int CHUNKS = CH0 + CH1 + CH2 + CH3 + CH4;           // 86
constexpr int CHUNK_ELEMS = 16384;

// ---------------- workspace layout ----------------
constexpr size_t align256(size_t x) { return (x + 255) & ~(size_t)255; }
constexpr size_t OFF_HIST = 0;
constexpr size_t OFF_T    = OFF_HIST + (size_t)NPAIR * NBINS * 4;
constexpr size_t OFF_CNT  = OFF_T + (size_t)NPAIR * 4;
constexpr size_t OFF_CAND = align256(OFF_CNT + (size_t)NPAIR * 4);
constexpr size_t OFF_CBOX = align256(OFF_CAND + (size_t)NPAIR * CAP * 8);
constexpr size_t OFF_CSC  = align256(OFF_CBOX + (size_t)NB * KC * 4 * 4);
constexpr size_t OFF_CLB  = align256(OFF_CSC  + (size_t)NB * KC * 4);
constexpr size_t OFF_SSC  = align256(OFF_CLB  + (size_t)NB * KC * 4);
constexpr size_t OFF_SLB  = align256(OFF_SSC  + (size_t)NB * KC * 4);
constexpr size_t OFF_SBOX = align256(OFF_SLB  + (size_t)NB * KC * 4);
constexpr size_t OFF_OBOX = align256(OFF_SBOX + (size_t)NB * KC * 4 * 4);
constexpr size_t OFF_M    = align256(OFF_OBOX + (size_t)NB * KC * 4 * 4);
// total ~9.6 MB

struct Cand { float s; int i; };

// ---------------- helpers ----------------
__device__ __forceinline__ float sigm(float x) { return 1.0f / (1.0f + expf(-x)); }

// monotone key over score in (0,1): 2048 bins over [0.25,1.0), everything below -> bin 0
__device__ __forceinline__ unsigned scoreKey(float s) {
    unsigned b = __float_as_uint(s);
    unsigned k = (b < 0x3E800000u) ? 0u : ((b - 0x3E800000u) >> 13);
    return (k > 2047u) ? 2047u : k;
}

__device__ __forceinline__ unsigned long long readlane64(unsigned long long v, int l) {
    unsigned lo = (unsigned)__builtin_amdgcn_readlane((int)(unsigned)(v & 0xffffffffull), l);
    unsigned hi = (unsigned)__builtin_amdgcn_readlane((int)(unsigned)(v >> 32), l);
    return ((unsigned long long)hi << 32) | lo;
}

__device__ void bitonicShared(float* ss, int* si, int N) {
    for (int k = 2; k <= N; k <<= 1) {
        for (int j = k >> 1; j > 0; j >>= 1) {
            __syncthreads();
            for (int i = threadIdx.x; i < N; i += blockDim.x) {
                int ixj = i ^ j;
                if (ixj > i) {
                    float s1 = ss[i], s2 = ss[ixj];
                    int a1 = si[i], a2 = si[ixj];
                    bool bef = (s1 > s2) || (s1 == s2 && a1 < a2);   // desc, idx asc
                    bool up = ((i & k) == 0);
                    if (up ? !bef : bef) { ss[i] = s2; ss[ixj] = s1; si[i] = a2; si[ixj] = a1; }
                }
            }
        }
    }
    __syncthreads();
}

// ---------------- K0: zero hist + counters ----------------
__global__ void k_zero(unsigned* p, int n) {
    int i = blockIdx.x * THREADS + threadIdx.x;
    if (i < n) p[i] = 0;
}

// ---------------- K1: histogram ----------------
template<int HW>
__device__ __forceinline__ void histChunk(int chunkLocal, int b,
        const float* __restrict__ cls, const float* __restrict__ ctr, unsigned* __restrict__ h) {
    constexpr int NE = HW * NC;
    int base = chunkLocal * CHUNK_ELEMS;
    int eend = min(base + CHUNK_ELEMS, NE);
    const float* cp = cls + (size_t)b * NE;
    const float* tp = ctr + (size_t)b * HW;
    for (int e = base + threadIdx.x; e < eend; e += THREADS) {
        int c = e / HW; int hw = e - c * HW;
        float scls = sigm(cp[e]);
        if (scls > 0.05f) {
            float s = __fmul_rn(scls, sigm(tp[hw]));
            unsigned key = scoreKey(s);
            if (key) atomicAdd(&h[key], 1u);   // skip hot bin0 (never reaches threshold)
        }
    }
}

__global__ __launch_bounds__(THREADS) void k_hist(
        const float* c0, const float* c1, const float* c2, const float* c3, const float* c4,
        const float* t0, const float* t1, const float* t2, const float* t3, const float* t4,
        unsigned* ghist) {
    __shared__ unsigned h[NBINS];
    for (int k = threadIdx.x; k < NBINS; k += THREADS) h[k] = 0;
    __syncthreads();
    int cx = blockIdx.x, b = blockIdx.y;
    int li;
    if (cx < CH0)                 { histChunk<HW0>(cx, b, c0, t0, h); li = 0; }
    else if (cx < CH0+CH1)        { histChunk<HW1>(cx-CH0, b, c1, t1, h); li = 1; }
    else if (cx < CH0+CH1+CH2)    { histChunk<HW2>(cx-CH0-CH1, b, c2, t2, h); li = 2; }
    else if (cx < CH0+CH1+CH2+CH3){ histChunk<HW3>(cx-CH0-CH1-CH2, b, c3, t3, h); li = 3; }
    else                          { histChunk<HW4>(cx-CH0-CH1-CH2-CH3, b, c4, t4, h); li = 4; }
    __syncthreads();
    unsigned* gp = ghist + (size_t)(li * NB + b) * NBINS;
    for (int k = threadIdx.x; k < NBINS; k += THREADS) {
        unsigned v = h[k];
        if (v) atomicAdd(&gp[k], v);
    }
}

// ---------------- K2: find per-(b,level) key threshold ----------------
__global__ __launch_bounds__(THREADS) void k_thresh(const unsigned* __restrict__ ghist, unsigned* __restrict__ T) {
    int pid = blockIdx.x;
    const unsigned* h = ghist + (size_t)pid * NBINS;
    __shared__ unsigned seg[THREADS];
    constexpr int SB = NBINS / THREADS;   // 8
    unsigned s = 0;
    for (int k = 0; k < SB; ++k) s += h[threadIdx.x * SB + k];
    seg[threadIdx.x] = s;
    __syncthreads();
    if (threadIdx.x == 0) {
        unsigned acc = 0; unsigned Tv = 0;
        int t = THREADS - 1;
        for (; t >= 0; --t) {
            if (acc + seg[t] >= (unsigned)TOPN) break;
            acc += seg[t];
        }
        if (t >= 0) {
            int lo = t * SB;
            int bin = lo + SB - 1;
            for (; bin >= lo; --bin) { acc += h[bin]; if (acc >= (unsigned)TOPN) break; }
            Tv = (unsigned)max(bin, lo);
        }
        T[pid] = Tv;   // 0 => collect everything (degenerate, <300 passing)
    }
}

// ---------------- K3: compact candidates >= threshold (LDS-staged) ----------------
constexpr int LBUF = 1024;

template<int HW>
__device__ __forceinline__ void collectChunk(int chunkLocal, int b, int li,
        const float* __restrict__ cls, const float* __restrict__ ctr,
        const unsigned* __restrict__ T, Cand* __restrict__ candAll, unsigned* __restrict__ cnt,
        Cand* __restrict__ lbuf, unsigned* __restrict__ lcnt) {
    constexpr int NE = HW * NC;
    int pid = li * NB + b;
    unsigned Tv = T[pid];
    Cand* cd = candAll + (size_t)pid * CAP;
    int base = chunkLocal * CHUNK_ELEMS;
    int eend = min(base + CHUNK_ELEMS, NE);
    const float* cp = cls + (size_t)b * NE;
    const float* tp = ctr + (size_t)b * HW;
    for (int e = base + threadIdx.x; e < eend; e += THREADS) {
        int c = e / HW; int hw = e - c * HW;
        float scls = sigm(cp[e]);
        if (scls > 0.05f) {
            float s = __fmul_rn(scls, sigm(tp[hw]));
            unsigned key = scoreKey(s);
            if (key >= Tv) {
                unsigned slot = atomicAdd(lcnt, 1u);
                if (slot < (unsigned)LBUF) { lbuf[slot].s = s; lbuf[slot].i = hw * NC + c; }
                else {
                    unsigned gs = atomicAdd(&cnt[pid], 1u);   // rare fallback
                    if (gs < (unsigned)CAP) { cd[gs].s = s; cd[gs].i = hw * NC + c; }
                }
            }
        }
    }
}

__global__ __launch_bounds__(THREADS) void k_collect(
        const float* c0, const float* c1, const float* c2, const float* c3, const float* c4,
        const float* t0, const float* t1, const float* t2, const float* t3, const float* t4,
        const unsigned* T, Cand* cand, unsigned* cnt) {
    __shared__ Cand lbuf[LBUF];
    __shared__ unsigned lcnt, gbase;
    if (threadIdx.x == 0) lcnt = 0;
    __syncthreads();
    int cx = blockIdx.x, b = blockIdx.y;
    int li;
    if (cx < CH0)                 { collectChunk<HW0>(cx, b, 0, c0, t0, T, cand, cnt, lbuf, &lcnt); li = 0; }
    else if (cx < CH0+CH1)        { collectChunk<HW1>(cx-CH0, b, 1, c1, t1, T, cand, cnt, lbuf, &lcnt); li = 1; }
    else if (cx < CH0+CH1+CH2)    { collectChunk<HW2>(cx-CH0-CH1, b, 2, c2, t2, T, cand, cnt, lbuf, &lcnt); li = 2; }
    else if (cx < CH0+CH1+CH2+CH3){ collectChunk<HW3>(cx-CH0-CH1-CH2, b, 3, c3, t3, T, cand, cnt, lbuf, &lcnt); li = 3; }
    else                          { collectChunk<HW4>(cx-CH0-CH1-CH2-CH3, b, 4, c4, t4, T, cand, cnt, lbuf, &lcnt); li = 4; }
    __syncthreads();
    int pid = li * NB + b;
    unsigned n = lcnt; if (n > (unsigned)LBUF) n = LBUF;
    if (threadIdx.x == 0) gbase = n ? atomicAdd(&cnt[pid], n) : 0u;
    __syncthreads();
    Cand* cd = cand + (size_t)pid * CAP;
    for (unsigned i = threadIdx.x; i < n; i += THREADS) {
        unsigned s = gbase + i;
        if (s < (unsigned)CAP) cd[s] = lbuf[i];
    }
}

// ---------------- K4: exact top-300 per (b,level) + decode ----------------
__global__ __launch_bounds__(THREADS) void k_select(
        const Cand* __restrict__ candAll, const unsigned* __restrict__ cntAll,
        const float* l0, const float* l1, const float* l2, const float* l3, const float* l4,
        const float* b0, const float* b1, const float* b2, const float* b3, const float* b4,
        float* __restrict__ cbox, float* __restrict__ csc, int* __restrict__ clb) {
    __shared__ float ss[CAP];
    __shared__ int si[CAP];
    int pid = blockIdx.x;
    int li = pid / NB, b = pid - li * NB;
    int n = (int)min(cntAll[pid], (unsigned)CAP);
    const Cand* cd = candAll + (size_t)pid * CAP;
    int N = 2; while (N < n) N <<= 1;
    for (int k = threadIdx.x; k < N; k += THREADS) {
        if (k < n) { ss[k] = cd[k].s; si[k] = cd[k].i; }
        else       { ss[k] = -INFINITY; si[k] = 0x40000000 + k; }
    }
    __syncthreads();
    bitonicShared(ss, si, N);

    const float* locp; const float* boxp; int HW;
    switch (li) {
        case 0: locp = l0; boxp = b0; HW = HW0; break;
        case 1: locp = l1; boxp = b1; HW = HW1; break;
        case 2: locp = l2; boxp = b2; HW = HW2; break;
        case 3: locp = l3; boxp = b3; HW = HW3; break;
        default: locp = l4; boxp = b4; HW = HW4; break;
    }
    for (int j = threadIdx.x; j < TOPN; j += THREADS) {
        int cidx = b * KC + li * TOPN + j;
        bool ok = (j < n);
        float s = ok ? ss[j] : -INFINITY;
        ok = ok && (s > 0.0f);
        if (ok) {
            int idx = si[j];
            int hw = idx / NC, c = idx - hw * NC;
            float lx = locp[hw * 2 + 0], ly = locp[hw * 2 + 1];
            const float* bp = boxp + (size_t)b * 4 * HW + hw;
            float bl = bp[0], bt = bp[HW], br = bp[2 * HW], bb = bp[3 * HW];
            float x1 = fminf(fmaxf(__fsub_rn(lx, bl), 0.0f), 1023.0f);
            float y1 = fminf(fmaxf(__fsub_rn(ly, bt), 0.0f),  799.0f);
            float x2 = fminf(fmaxf(__fadd_rn(lx, br), 0.0f), 1023.0f);
            float y2 = fminf(fmaxf(__fadd_rn(ly, bb), 0.0f),  799.0f);
            cbox[cidx * 4 + 0] = x1; cbox[cidx * 4 + 1] = y1;
            cbox[cidx * 4 + 2] = x2; cbox[cidx * 4 + 3] = y2;
            csc[cidx] = sqrtf(fmaxf(s, 1e-12f));
            clb[cidx] = c + 1;
        } else {
            cbox[cidx * 4 + 0] = 0.0f; cbox[cidx * 4 + 1] = 0.0f;
            cbox[cidx * 4 + 2] = 0.0f; cbox[cidx * 4 + 3] = 0.0f;
            csc[cidx] = -INFINITY;
            clb[cidx] = 0;
        }
    }
}

// ---------------- K5a: per-image sort by score desc (1024 threads) ----------------
__global__ __launch_bounds__(SORTT) void k_sortimg(
        const float* __restrict__ csc, const int* __restrict__ clb, const float* __restrict__ cbox,
        float* __restrict__ ssc, int* __restrict__ slb, float* __restrict__ sbox, float* __restrict__ obox) {
    int b = blockIdx.x;
    __shared__ float ss[2048];
    __shared__ int si[2048];
    for (int k = threadIdx.x; k < 2048; k += SORTT) {
        if (k < KC) { ss[k] = csc[b * KC + k]; si[k] = k; }
        else        { ss[k] = -INFINITY; si[k] = 0x40000000 + k; }
    }
    __syncthreads();
    bitonicShared(ss, si, 2048);
    for (int k = threadIdx.x; k < KC; k += SORTT) {
        int sl = si[k];                 // all 1500 real entries sort before pads
        int src = b * KC + sl;
        int dst = b * KC + k;
        float sc = ss[k];
        int lab = clb[src];
        ssc[dst] = sc; slb[dst] = lab;
        float off = __fmul_rn((float)lab, 1025.0f);   // offset = max(800,1024)+1
        #pragma unroll
        for (int q = 0; q < 4; ++q) {
            float v = cbox[src * 4 + q];
            sbox[dst * 4 + q] = v;
            obox[dst * 4 + q] = __fadd_rn(v, off);
        }
    }
}

// ---------------- K5b: suppression bitmask (iou > 0.6 && j > i) ----------------
// One wave per (col-word w, row-tile, image), upper triangle only (w >= tile).
// Inner loop reads column box wave-uniformly from LDS -> broadcast, conflict-free.
// k_nms only ever reads words w >= row-chunk, so lower-triangle words stay unwritten.
__global__ __launch_bounds__(64) void k_iou(const float* __restrict__ obox,
                                            unsigned long long* __restrict__ M) {
    int w = blockIdx.x, tile = blockIdx.y, b = blockIdx.z;
    if (w < tile) return;
    int lane = threadIdx.x;
    __shared__ float4 sj[64];
    __shared__ float aj[64];
    const float4* op = (const float4*)obox + (size_t)b * KC;
    int j0 = w * 64;
    int jl = j0 + lane;
    float4 vj = op[(jl < KC) ? jl : (KC - 1)];
    sj[lane] = vj;
    aj[lane] = __fmul_rn(__fsub_rn(vj.z, vj.x), __fsub_rn(vj.w, vj.y));
    int i = tile * 64 + lane;
    float4 bi = op[(i < KC) ? i : (KC - 1)];
    float ai = __fmul_rn(__fsub_rn(bi.z, bi.x), __fsub_rn(bi.w, bi.y));
    __syncthreads();
    unsigned long long bits = 0;
    int jmax = min(64, KC - j0);       // uniform: only word 23 is partial
    for (int jj = 0; jj < jmax; ++jj) {
        float4 bj = sj[jj];            // wave-uniform -> LDS broadcast
        float xx1 = fmaxf(bi.x, bj.x), yy1 = fmaxf(bi.y, bj.y);
        float xx2 = fminf(bi.z, bj.z), yy2 = fminf(bi.w, bj.w);
        float ww = fmaxf(__fsub_rn(xx2, xx1), 0.0f);
        float hh = fmaxf(__fsub_rn(yy2, yy1), 0.0f);
        float inter = __fmul_rn(ww, hh);
        float uni = __fsub_rn(__fadd_rn(ai, aj[jj]), inter);
        float iou = __fdiv_rn(inter, fmaxf(uni, 1e-9f));
        bool kp = ((j0 + jj) > i) && (iou > 0.6f);
        bits |= kp ? (1ull << jj) : 0ull;
    }
    if (i >= KC) bits = 0;             // padded rows
    M[((size_t)b * KROWS + i) * WORDS + w] = bits;
}

// ---------------- K5c: pull-style greedy scan (1 wave/image) + emit ----------------
__global__ __launch_bounds__(64) void k_nms(
        const unsigned long long* __restrict__ M, const float* __restrict__ ssc,
        const int* __restrict__ slb, const float* __restrict__ sbox, float* __restrict__ out) {
    int b = blockIdx.x, lane = threadIdx.x;
    // zero-fill this image's output slices (d_out is poisoned before every launch)
    for (int k = lane; k < POSTN * 5; k += 64) out[(size_t)b * POSTN * 5 + k] = 0.0f;
    for (int k = lane; k < POSTN; k += 64) {
        out[(size_t)NB * POSTN * 5 + b * POSTN + k] = 0.0f;                 // labels
        out[(size_t)NB * POSTN * 5 + NB * POSTN + b * POSTN + k] = 0.0f;    // valid
    }
    // validV: lane c holds tile c's valid mask
    const float* sp = ssc + b * KC;
    unsigned long long validV = 0;
    for (int c = 0; c < WORDS; ++c) {
        int i = c * 64 + lane;
        bool f = (i < KC) && (sp[i] > 0.0f);
        unsigned long long m = __ballot(f);
        validV = (lane == c) ? m : validV;
    }
    unsigned long long mybit = 1ull << lane;
    unsigned long long keptV = 0;   // lane c holds tile c's kept mask
    const unsigned long long* Mb = M + (size_t)b * KROWS * WORDS;

    for (int t = 0; t < WORDS; ++t) {
        // batch-issue independent loads: diagonal + all previous chunks' word-t rows
        unsigned long long D = Mb[(size_t)(t * 64 + lane) * WORDS + t];
        unsigned long long v[WORDS - 1];
        #pragma unroll
        for (int c = 0; c < WORDS - 1; ++c) {
            int cc = (c < t) ? c : 0;                      // uniform clamp: no branches around loads
            v[c] = Mb[(size_t)(cc * 64 + lane) * WORDS + t];
        }
        // mask by kept rows of previous tiles
        unsigned long long acc = 0;
        #pragma unroll
        for (int c = 0; c < WORDS - 1; ++c) {
            if (c < t) {
                unsigned long long kc = readlane64(keptV, c);   // uniform
                if (kc & mybit) acc |= v[c];
            }
        }
        // OR-butterfly: every lane ends with the full removed word (uniform)
        #pragma unroll
        for (int s = 1; s < 64; s <<= 1) acc |= __shfl_xor(acc, s, 64);

        unsigned long long validT = readlane64(validV, t);
        unsigned long long rem = acc;
        // suppressor-sparse greedy: only rows with intra-tile bits matter for rem
        unsigned long long sup = __ballot(D != 0ull) & validT;
        unsigned long long todoS = sup;
        while (todoS) {
            int r = __builtin_ctzll(todoS);
            todoS &= todoS - 1;
            if (!((rem >> r) & 1ull)) {
                unsigned long long Dr = readlane64(D, r);
                rem |= Dr;
                todoS &= ~Dr;
            }
        }
        unsigned long long kept = validT & ~rem;   // uniform
        keptV = (lane == t) ? kept : keptV;
    }

    // emit first 100 kept in score order
    int base = 0;
    for (int c = 0; c < WORDS && base < POSTN; ++c) {
        unsigned long long kw = readlane64(keptV, c);
        bool f = (kw & mybit) != 0ull;
        int rank = base + __popcll(kw & (mybit - 1ull));
        if (f && rank < POSTN) {
            int i = c * 64 + lane;
            int src = b * KC + i;
            float* o5 = out + ((size_t)b * POSTN + rank) * 5;
            o5[0] = sbox[src * 4 + 0]; o5[1] = sbox[src * 4 + 1];
            o5[2] = sbox[src * 4 + 2]; o5[3] = sbox[src * 4 + 3];
            o5[4] = ssc[src];
            out[(size_t)NB * POSTN * 5 + b * POSTN + rank] = (float)slb[src];
            out[(size_t)NB * POSTN * 5 + NB * POSTN + b * POSTN + rank] = 1.0f;
        }
        base += __popcll(kw);
    }
}

// ---------------- launch ----------------
extern "C" void kernel_launch(void* const* d_in, const int* in_sizes, int n_in,
                              void* d_out, int out_size, void* d_ws, size_t ws_size,
                              hipStream_t stream) {
    // setup_inputs dict order: per level: location, cls, box, ctr; then img_h, img_w
    const float *loc[5], *cls[5], *box[5], *ctr[5];
    for (int l = 0; l < 5; ++l) {
        loc[l] = (const float*)d_in[l * 4 + 0];
        cls[l] = (const float*)d_in[l * 4 + 1];
        box[l] = (const float*)d_in[l * 4 + 2];
        ctr[l] = (const float*)d_in[l * 4 + 3];
    }
    char* ws = (char*)d_ws;
    unsigned* hist = (unsigned*)(ws + OFF_HIST);
    unsigned* T    = (unsigned*)(ws + OFF_T);
    unsigned* cnt  = (unsigned*)(ws + OFF_CNT);
    Cand* cand     = (Cand*)(ws + OFF_CAND);
    float* cbox    = (float*)(ws + OFF_CBOX);
    float* csc     = (float*)(ws + OFF_CSC);
    int*   clb     = (int*)(ws + OFF_CLB);
    float* ssc     = (float*)(ws + OFF_SSC);
    int*   slb     = (int*)(ws + OFF_SLB);
    float* sbox    = (float*)(ws + OFF_SBOX);
    float* obox    = (float*)(ws + OFF_OBOX);
    unsigned long long* M = (unsigned long long*)(ws + OFF_M);
    float* out = (float*)d_out;

    int zn = (int)(OFF_CAND / 4);
    k_zero<<<(zn + THREADS - 1) / THREADS, THREADS, 0, stream>>>((unsigned*)ws, zn);
    k_hist<<<dim3(CHUNKS, NB), THREADS, 0, stream>>>(
        cls[0], cls[1], cls[2], cls[3], cls[4],
        ctr[0], ctr[1], ctr[2], ctr[3], ctr[4], hist);
    k_thresh<<<NPAIR, THREADS, 0, stream>>>(hist, T);
    k_collect<<<dim3(CHUNKS, NB), THREADS, 0, stream>>>(
        cls[0], cls[1], cls[2], cls[3], cls[4],
        ctr[0], ctr[1], ctr[2], ctr[3], ctr[4], T, cand, cnt);
    k_select<<<NPAIR, THREADS, 0, stream>>>(
        cand, cnt,
        loc[0], loc[1], loc[2], loc[3], loc[4],
        box[0], box[1], box[2], box[3], box[4],
        cbox, csc, clb);
    k_sortimg<<<NB, SORTT, 0, stream>>>(csc, clb, cbox, ssc, slb, sbox, obox);
    k_iou<<<dim3(WORDS, WORDS, NB), 64, 0, stream>>>(obox, M);
    k_nms<<<NB, 64, 0, stream>>>(M, ssc, slb, sbox, out);
}

// Round 5
// 348.190 us; speedup vs baseline: 1.9564x; 1.2008x over previous
//
#include <hip/hip_runtime.h>
#include <math.h>

#define THREADS 256
#define SORTT 1024

// ---------------- problem constants (fixed by reference setup) ----------------
constexpr int NLEV  = 5;
constexpr int NB    = 16;     // batch
constexpr int NC    = 80;     // classes (label = c+1)
constexpr int TOPN  = 300;
constexpr int KC    = NLEV * TOPN;   // 1500 candidates per image
constexpr int KROWS = 1536;          // padded rows for NMS bitmask
constexpr int WORDS = 24;            // 1536 / 64
constexpr int POSTN = 100;
constexpr int CAP   = 4096;          // per-(b,level) candidate pool
constexpr int NBINS = 2048;          // score-histogram bins over [0.25, 1.0)
constexpr int NPAIR = NLEV * NB;     // 80

constexpr int HW0 = 12800, HW1 = 3200, HW2 = 800, HW3 = 208, HW4 = 56;
constexpr int CH0 = 63, CH1 = 16, CH2 = 4, CH3 = 2, CH4 = 1;  // 16384-elem chunks per (b,level)
constexpr int CHUNKS = CH0 + CH1 + CH2 + CH3 + CH4;           // 86
constexpr int CHUNK_ELEMS = 16384;

// sigmoid(ctr) precompute: per-level bases into sct[] (floats), layout [li][b][hw]
constexpr int SCTB0 = 0;                      // 16*12800 = 204800
constexpr int SCTB1 = 204800;                 // 16*3200  = 51200
constexpr int SCTB2 = 256000;                 // 16*800   = 12800
constexpr int SCTB3 = 268800;                 // 16*208   = 3328
constexpr int SCTB4 = 272128;                 // 16*56    = 896
constexpr int SCTN  = 273024;

// group-max skip list: 256-element groups, layout [li][b][g] (u16)
constexpr int GPL0 = 4000, GPL1 = 1000, GPL2 = 250, GPL3 = 65, GPL4 = 18;
constexpr int GMXB0 = 0;
constexpr int GMXB1 = GMXB0 + NB * GPL0;      // 64000
constexpr int GMXB2 = GMXB1 + NB * GPL1;      // 80000
constexpr int GMXB3 = GMXB2 + NB * GPL2;      // 84000
constexpr int GMXB4 = GMXB3 + NB * GPL3;      // 85040
constexpr int GMXN  = GMXB4 + NB * GPL4;      // 85328

// ---------------- workspace layout ----------------
constexpr size_t align256(size_t x) { return (x + 255) & ~(size_t)255; }
constexpr size_t OFF_HIST = 0;
constexpr size_t OFF_T    = OFF_HIST + (size_t)NPAIR * NBINS * 4;
constexpr size_t OFF_CNT  = OFF_T + (size_t)NPAIR * 4;
constexpr size_t OFF_CAND = align256(OFF_CNT + (size_t)NPAIR * 4);
constexpr size_t OFF_CBOX = align256(OFF_CAND + (size_t)NPAIR * CAP * 8);
constexpr size_t OFF_CSC  = align256(OFF_CBOX + (size_t)NB * KC * 4 * 4);
constexpr size_t OFF_CLB  = align256(OFF_CSC  + (size_t)NB * KC * 4);
constexpr size_t OFF_SSC  = align256(OFF_CLB  + (size_t)NB * KC * 4);
constexpr size_t OFF_SLB  = align256(OFF_SSC  + (size_t)NB * KC * 4);
constexpr size_t OFF_SBOX = align256(OFF_SLB  + (size_t)NB * KC * 4);
constexpr size_t OFF_OBOX = align256(OFF_SBOX + (size_t)NB * KC * 4 * 4);
constexpr size_t OFF_M    = align256(OFF_OBOX + (size_t)NB * KC * 4 * 4);
constexpr size_t OFF_SCT  = align256(OFF_M + (size_t)NB * KROWS * WORDS * 8);
constexpr size_t OFF_GMX  = align256(OFF_SCT + (size_t)SCTN * 4);
// total ~15.8 MB

struct Cand { float s; int i; };

// ---------------- helpers ----------------
__device__ __forceinline__ float sigm(float x) { return 1.0f / (1.0f + expf(-x)); }

// monotone key over score in (0,1): 2048 bins over [0.25,1.0), everything below -> bin 0
__device__ __forceinline__ unsigned scoreKey(float s) {
    unsigned b = __float_as_uint(s);
    unsigned k = (b < 0x3E800000u) ? 0u : ((b - 0x3E800000u) >> 13);
    return (k > 2047u) ? 2047u : k;
}

__device__ __forceinline__ unsigned long long readlane64(unsigned long long v, int l) {
    unsigned lo = (unsigned)__builtin_amdgcn_readlane((int)(unsigned)(v & 0xffffffffull), l);
    unsigned hi = (unsigned)__builtin_amdgcn_readlane((int)(unsigned)(v >> 32), l);
    return ((unsigned long long)hi << 32) | lo;
}

__device__ void bitonicShared(float* ss, int* si, int N) {
    for (int k = 2; k <= N; k <<= 1) {
        for (int j = k >> 1; j > 0; j >>= 1) {
            __syncthreads();
            for (int i = threadIdx.x; i < N; i += blockDim.x) {
                int ixj = i ^ j;
                if (ixj > i) {
                    float s1 = ss[i], s2 = ss[ixj];
                    int a1 = si[i], a2 = si[ixj];
                    bool bef = (s1 > s2) || (s1 == s2 && a1 < a2);   // desc, idx asc
                    bool up = ((i & k) == 0);
                    if (up ? !bef : bef) { ss[i] = s2; ss[ixj] = s1; si[i] = a2; si[ixj] = a1; }
                }
            }
        }
    }
    __syncthreads();
}

// ---------------- K0: zero hist + counters ----------------
__global__ void k_zero(unsigned* p, int n) {
    int i = blockIdx.x * THREADS + threadIdx.x;
    if (i < n) p[i] = 0;
}

// ---------------- K0b: precompute sigmoid(ctr) ----------------
__global__ __launch_bounds__(THREADS) void k_prep(
        const float* t0, const float* t1, const float* t2, const float* t3, const float* t4,
        float* __restrict__ sct) {
    int i = blockIdx.x * THREADS + threadIdx.x;
    if (i >= SCTN) return;
    float x;
    if (i < SCTB1)      x = t0[i - SCTB0];
    else if (i < SCTB2) x = t1[i - SCTB1];
    else if (i < SCTB3) x = t2[i - SCTB2];
    else if (i < SCTB4) x = t3[i - SCTB3];
    else                x = t4[i - SCTB4];
    sct[i] = sigm(x);   // exact: same formula as reference sigmoid usage
}

// ---------------- K1: histogram + per-256-group max key ----------------
template<int HW, int SCTB, int GPL, int GMXB>
__device__ __forceinline__ void histChunkV(int chunkLocal, int b,
        const float* __restrict__ cls, const float* __restrict__ sct,
        unsigned short* __restrict__ gmx, unsigned* __restrict__ h) {
    constexpr int NE = HW * NC;
    const float* cp = cls + (size_t)b * NE;
    const float* tb = sct + SCTB + b * HW;
    unsigned short* gp = gmx + GMXB + (size_t)b * GPL;
    int w = threadIdx.x >> 6, lane = threadIdx.x & 63;
    for (int gi = w; gi < 64; gi += 4) {
        int g = chunkLocal * 64 + gi;
        int ebase = g * 256;
        if (ebase >= NE) break;
        int e = ebase + lane * 4;
        int kmax = 0;
        if (e < NE) {
            int c = e / HW; int hwb = e - c * HW;        // 4 elems stay in one row (HW%4==0)
            float4 x4 = *(const float4*)(cp + e);
            float4 t4 = *(const float4*)(tb + hwb);
            #pragma unroll
            for (int q = 0; q < 4; ++q) {
                float x = (q == 0) ? x4.x : (q == 1) ? x4.y : (q == 2) ? x4.z : x4.w;
                float t = (q == 0) ? t4.x : (q == 1) ? t4.y : (q == 2) ? t4.z : t4.w;
                float scls = sigm(x);
                float s = __fmul_rn(scls, t);
                unsigned key = scoreKey(s);
                if (key) atomicAdd(&h[key], 1u);
                kmax = max(kmax, (int)key);
            }
        }
        #pragma unroll
        for (int sh = 1; sh < 64; sh <<= 1) kmax = max(kmax, __shfl_xor(kmax, sh, 64));
        if (lane == 0) gp[g] = (unsigned short)kmax;
    }
}

__global__ __launch_bounds__(THREADS) void k_hist(
        const float* c0, const float* c1, const float* c2, const float* c3, const float* c4,
        const float* __restrict__ sct, unsigned short* __restrict__ gmx, unsigned* ghist) {
    __shared__ unsigned h[NBINS];
    for (int k = threadIdx.x; k < NBINS; k += THREADS) h[k] = 0;
    __syncthreads();
    int cx = blockIdx.x, b = blockIdx.y;
    int li;
    if (cx < CH0)                 { histChunkV<HW0,SCTB0,GPL0,GMXB0>(cx, b, c0, sct, gmx, h); li = 0; }
    else if (cx < CH0+CH1)        { histChunkV<HW1,SCTB1,GPL1,GMXB1>(cx-CH0, b, c1, sct, gmx, h); li = 1; }
    else if (cx < CH0+CH1+CH2)    { histChunkV<HW2,SCTB2,GPL2,GMXB2>(cx-CH0-CH1, b, c2, sct, gmx, h); li = 2; }
    else if (cx < CH0+CH1+CH2+CH3){ histChunkV<HW3,SCTB3,GPL3,GMXB3>(cx-CH0-CH1-CH2, b, c3, sct, gmx, h); li = 3; }
    else                          { histChunkV<HW4,SCTB4,GPL4,GMXB4>(cx-CH0-CH1-CH2-CH3, b, c4, sct, gmx, h); li = 4; }
    __syncthreads();
    unsigned* gp = ghist + (size_t)(li * NB + b) * NBINS;
    for (int k = threadIdx.x; k < NBINS; k += THREADS) {
        unsigned v = h[k];
        if (v) atomicAdd(&gp[k], v);
    }
}

// ---------------- K2: find per-(b,level) key threshold ----------------
__global__ __launch_bounds__(THREADS) void k_thresh(const unsigned* __restrict__ ghist, unsigned* __restrict__ T) {
    int pid = blockIdx.x;
    const unsigned* h = ghist + (size_t)pid * NBINS;
    __shared__ unsigned seg[THREADS];
    constexpr int SB = NBINS / THREADS;   // 8
    unsigned s = 0;
    for (int k = 0; k < SB; ++k) s += h[threadIdx.x * SB + k];
    seg[threadIdx.x] = s;
    __syncthreads();
    if (threadIdx.x == 0) {
        unsigned acc = 0; unsigned Tv = 0;
        int t = THREADS - 1;
        for (; t >= 0; --t) {
            if (acc + seg[t] >= (unsigned)TOPN) break;
            acc += seg[t];
        }
        if (t >= 0) {
            int lo = t * SB;
            int bin = lo + SB - 1;
            for (; bin >= lo; --bin) { acc += h[bin]; if (acc >= (unsigned)TOPN) break; }
            Tv = (unsigned)max(bin, lo);
        }
        T[pid] = Tv;   // 0 => collect everything (degenerate, <300 passing)
    }
}

// ---------------- K3: skip-list-driven compaction ----------------
constexpr int LBUF = 1024;

template<int HW, int SCTB, int GPL, int GMXB>
__device__ __forceinline__ void collectChunkV(int chunkLocal, int b, int li,
        const float* __restrict__ cls, const float* __restrict__ sct,
        const unsigned short* __restrict__ gmx,
        const unsigned* __restrict__ T, Cand* __restrict__ candAll, unsigned* __restrict__ cnt,
        Cand* __restrict__ lbuf, unsigned* __restrict__ lcnt, unsigned long long* __restrict__ pmShared) {
    constexpr int NE = HW * NC;
    int pid = li * NB + b;
    unsigned Tv = T[pid];
    Cand* cd = candAll + (size_t)pid * CAP;
    const float* cp = cls + (size_t)b * NE;
    const float* tb = sct + SCTB + b * HW;
    const unsigned short* gp = gmx + GMXB + (size_t)b * GPL;
    if (threadIdx.x < 64) {
        int g = chunkLocal * 64 + threadIdx.x;
        bool ok = ((size_t)g * 256 < (size_t)NE);
        if (ok && Tv) ok = (gp[g] >= (unsigned short)Tv);
        unsigned long long m = __ballot(ok);
        if (threadIdx.x == 0) *pmShared = m;
    }
    __syncthreads();
    unsigned long long pm = *pmShared;
    while (pm) {
        int gi = __builtin_ctzll(pm);
        pm &= pm - 1;
        int e = (chunkLocal * 64 + gi) * 256 + threadIdx.x;
        if (e < NE) {
            float x = cp[e];
            int c = e / HW; int hw = e - c * HW;
            float scls = sigm(x);
            float s = __fmul_rn(scls, tb[hw]);
            unsigned key = scoreKey(s);
            bool take = Tv ? (key >= Tv) : (scls > 0.05f);
            if (take) {
                unsigned slot = atomicAdd(lcnt, 1u);
                if (slot < (unsigned)LBUF) { lbuf[slot].s = s; lbuf[slot].i = hw * NC + c; }
                else {
                    unsigned gs = atomicAdd(&cnt[pid], 1u);   // rare fallback
                    if (gs < (unsigned)CAP) { cd[gs].s = s; cd[gs].i = hw * NC + c; }
                }
            }
        }
    }
}

__global__ __launch_bounds__(THREADS) void k_collect(
        const float* c0, const float* c1, const float* c2, const float* c3, const float* c4,
        const float* __restrict__ sct, const unsigned short* __restrict__ gmx,
        const unsigned* T, Cand* cand, unsigned* cnt) {
    __shared__ Cand lbuf[LBUF];
    __shared__ unsigned lcnt, gbase;
    __shared__ unsigned long long pmShared;
    if (threadIdx.x == 0) lcnt = 0;
    __syncthreads();
    int cx = blockIdx.x, b = blockIdx.y;
    int li;
    if (cx < CH0)                 { collectChunkV<HW0,SCTB0,GPL0,GMXB0>(cx, b, 0, c0, sct, gmx, T, cand, cnt, lbuf, &lcnt, &pmShared); li = 0; }
    else if (cx < CH0+CH1)        { collectChunkV<HW1,SCTB1,GPL1,GMXB1>(cx-CH0, b, 1, c1, sct, gmx, T, cand, cnt, lbuf, &lcnt, &pmShared); li = 1; }
    else if (cx < CH0+CH1+CH2)    { collectChunkV<HW2,SCTB2,GPL2,GMXB2>(cx-CH0-CH1, b, 2, c2, sct, gmx, T, cand, cnt, lbuf, &lcnt, &pmShared); li = 2; }
    else if (cx < CH0+CH1+CH2+CH3){ collectChunkV<HW3,SCTB3,GPL3,GMXB3>(cx-CH0-CH1-CH2, b, 3, c3, sct, gmx, T, cand, cnt, lbuf, &lcnt, &pmShared); li = 3; }
    else                          { collectChunkV<HW4,SCTB4,GPL4,GMXB4>(cx-CH0-CH1-CH2-CH3, b, 4, c4, sct, gmx, T, cand, cnt, lbuf, &lcnt, &pmShared); li = 4; }
    __syncthreads();
    int pid = li * NB + b;
    unsigned n = lcnt; if (n > (unsigned)LBUF) n = LBUF;
    if (threadIdx.x == 0) gbase = n ? atomicAdd(&cnt[pid], n) : 0u;
    __syncthreads();
    Cand* cd = cand + (size_t)pid * CAP;
    for (unsigned i = threadIdx.x; i < n; i += THREADS) {
        unsigned s = gbase + i;
        if (s < (unsigned)CAP) cd[s] = lbuf[i];
    }
}

// ---------------- K4: exact top-300 per (b,level) + decode ----------------
__global__ __launch_bounds__(THREADS) void k_select(
        const Cand* __restrict__ candAll, const unsigned* __restrict__ cntAll,
        const float* l0, const float* l1, const float* l2, const float* l3, const float* l4,
        const float* b0, const float* b1, const float* b2, const float* b3, const float* b4,
        float* __restrict__ cbox, float* __restrict__ csc, int* __restrict__ clb) {
    __shared__ float ss[CAP];
    __shared__ int si[CAP];
    int pid = blockIdx.x;
    int li = pid / NB, b = pid - li * NB;
    int n = (int)min(cntAll[pid], (unsigned)CAP);
    const Cand* cd = candAll + (size_t)pid * CAP;
    int N = 2; while (N < n) N <<= 1;
    for (int k = threadIdx.x; k < N; k += THREADS) {
        if (k < n) { ss[k] = cd[k].s; si[k] = cd[k].i; }
        else       { ss[k] = -INFINITY; si[k] = 0x40000000 + k; }
    }
    __syncthreads();
    bitonicShared(ss, si, N);

    const float* locp; const float* boxp; int HW;
    switch (li) {
        case 0: locp = l0; boxp = b0; HW = HW0; break;
        case 1: locp = l1; boxp = b1; HW = HW1; break;
        case 2: locp = l2; boxp = b2; HW = HW2; break;
        case 3: locp = l3; boxp = b3; HW = HW3; break;
        default: locp = l4; boxp = b4; HW = HW4; break;
    }
    for (int j = threadIdx.x; j < TOPN; j += THREADS) {
        int cidx = b * KC + li * TOPN + j;
        bool ok = (j < n);
        float s = ok ? ss[j] : -INFINITY;
        ok = ok && (s > 0.0f);
        if (ok) {
            int idx = si[j];
            int hw = idx / NC, c = idx - hw * NC;
            float lx = locp[hw * 2 + 0], ly = locp[hw * 2 + 1];
            const float* bp = boxp + (size_t)b * 4 * HW + hw;
            float bl = bp[0], bt = bp[HW], br = bp[2 * HW], bb = bp[3 * HW];
            float x1 = fminf(fmaxf(__fsub_rn(lx, bl), 0.0f), 1023.0f);
            float y1 = fminf(fmaxf(__fsub_rn(ly, bt), 0.0f),  799.0f);
            float x2 = fminf(fmaxf(__fadd_rn(lx, br), 0.0f), 1023.0f);
            float y2 = fminf(fmaxf(__fadd_rn(ly, bb), 0.0f),  799.0f);
            cbox[cidx * 4 + 0] = x1; cbox[cidx * 4 + 1] = y1;
            cbox[cidx * 4 + 2] = x2; cbox[cidx * 4 + 3] = y2;
            csc[cidx] = sqrtf(fmaxf(s, 1e-12f));
            clb[cidx] = c + 1;
        } else {
            cbox[cidx * 4 + 0] = 0.0f; cbox[cidx * 4 + 1] = 0.0f;
            cbox[cidx * 4 + 2] = 0.0f; cbox[cidx * 4 + 3] = 0.0f;
            csc[cidx] = -INFINITY;
            clb[cidx] = 0;
        }
    }
}

// ---------------- K5a: per-image sort by score desc (1024 threads) ----------------
__global__ __launch_bounds__(SORTT) void k_sortimg(
        const float* __restrict__ csc, const int* __restrict__ clb, const float* __restrict__ cbox,
        float* __restrict__ ssc, int* __restrict__ slb, float* __restrict__ sbox, float* __restrict__ obox) {
    int b = blockIdx.x;
    __shared__ float ss[2048];
    __shared__ int si[2048];
    for (int k = threadIdx.x; k < 2048; k += SORTT) {
        if (k < KC) { ss[k] = csc[b * KC + k]; si[k] = k; }
        else        { ss[k] = -INFINITY; si[k] = 0x40000000 + k; }
    }
    __syncthreads();
    bitonicShared(ss, si, 2048);
    for (int k = threadIdx.x; k < KC; k += SORTT) {
        int sl = si[k];                 // all 1500 real entries sort before pads
        int src = b * KC + sl;
        int dst = b * KC + k;
        float sc = ss[k];
        int lab = clb[src];
        ssc[dst] = sc; slb[dst] = lab;
        float off = __fmul_rn((float)lab, 1025.0f);   // offset = max(800,1024)+1
        #pragma unroll
        for (int q = 0; q < 4; ++q) {
            float v = cbox[src * 4 + q];
            sbox[dst * 4 + q] = v;
            obox[dst * 4 + q] = __fadd_rn(v, off);
        }
    }
}

// ---------------- K5b: suppression bitmask (iou > 0.6 && j > i) ----------------
__global__ __launch_bounds__(64) void k_iou(const float* __restrict__ obox,
                                            unsigned long long* __restrict__ M) {
    int w = blockIdx.x, tile = blockIdx.y, b = blockIdx.z;
    if (w < tile) return;
    int lane = threadIdx.x;
    __shared__ float4 sj[64];
    __shared__ float aj[64];
    const float4* op = (const float4*)obox + (size_t)b * KC;
    int j0 = w * 64;
    int jl = j0 + lane;
    float4 vj = op[(jl < KC) ? jl : (KC - 1)];
    sj[lane] = vj;
    aj[lane] = __fmul_rn(__fsub_rn(vj.z, vj.x), __fsub_rn(vj.w, vj.y));
    int i = tile * 64 + lane;
    float4 bi = op[(i < KC) ? i : (KC - 1)];
    float ai = __fmul_rn(__fsub_rn(bi.z, bi.x), __fsub_rn(bi.w, bi.y));
    __syncthreads();
    unsigned long long bits = 0;
    int jmax = min(64, KC - j0);
    for (int jj = 0; jj < jmax; ++jj) {
        float4 bj = sj[jj];            // wave-uniform -> LDS broadcast
        float xx1 = fmaxf(bi.x, bj.x), yy1 = fmaxf(bi.y, bj.y);
        float xx2 = fminf(bi.z, bj.z), yy2 = fminf(bi.w, bj.w);
        float ww = fmaxf(__fsub_rn(xx2, xx1), 0.0f);
        float hh = fmaxf(__fsub_rn(yy2, yy1), 0.0f);
        float inter = __fmul_rn(ww, hh);
        float uni = __fsub_rn(__fadd_rn(ai, aj[jj]), inter);
        float iou = __fdiv_rn(inter, fmaxf(uni, 1e-9f));
        bool kp = ((j0 + jj) > i) && (iou > 0.6f);
        bits |= kp ? (1ull << jj) : 0ull;
    }
    if (i >= KC) bits = 0;
    M[((size_t)b * KROWS + i) * WORDS + w] = bits;
}

// ---------------- K5c: pull-style greedy scan (1 wave/image) + emit ----------------
__global__ __launch_bounds__(64) void k_nms(
        const unsigned long long* __restrict__ M, const float* __restrict__ ssc,
        const int* __restrict__ slb, const float* __restrict__ sbox, float* __restrict__ out) {
    int b = blockIdx.x, lane = threadIdx.x;
    for (int k = lane; k < POSTN * 5; k += 64) out[(size_t)b * POSTN * 5 + k] = 0.0f;
    for (int k = lane; k < POSTN; k += 64) {
        out[(size_t)NB * POSTN * 5 + b * POSTN + k] = 0.0f;                 // labels
        out[(size_t)NB * POSTN * 5 + NB * POSTN + b * POSTN + k] = 0.0f;    // valid
    }
    const float* sp = ssc + b * KC;
    unsigned long long validV = 0;
    for (int c = 0; c < WORDS; ++c) {
        int i = c * 64 + lane;
        bool f = (i < KC) && (sp[i] > 0.0f);
        unsigned long long m = __ballot(f);
        validV = (lane == c) ? m : validV;
    }
    unsigned long long mybit = 1ull << lane;
    unsigned long long keptV = 0;
    const unsigned long long* Mb = M + (size_t)b * KROWS * WORDS;

    for (int t = 0; t < WORDS; ++t) {
        unsigned long long D = Mb[(size_t)(t * 64 + lane) * WORDS + t];
        unsigned long long v[WORDS - 1];
        #pragma unroll
        for (int c = 0; c < WORDS - 1; ++c) {
            int cc = (c < t) ? c : 0;
            v[c] = Mb[(size_t)(cc * 64 + lane) * WORDS + t];
        }
        unsigned long long acc = 0;
        #pragma unroll
        for (int c = 0; c < WORDS - 1; ++c) {
            if (c < t) {
                unsigned long long kc = readlane64(keptV, c);
                if (kc & mybit) acc |= v[c];
            }
        }
        #pragma unroll
        for (int s = 1; s < 64; s <<= 1) acc |= __shfl_xor(acc, s, 64);

        unsigned long long validT = readlane64(validV, t);
        unsigned long long rem = acc;
        unsigned long long sup = __ballot(D != 0ull) & validT;
        unsigned long long todoS = sup;
        while (todoS) {
            int r = __builtin_ctzll(todoS);
            todoS &= todoS - 1;
            if (!((rem >> r) & 1ull)) {
                unsigned long long Dr = readlane64(D, r);
                rem |= Dr;
                todoS &= ~Dr;
            }
        }
        unsigned long long kept = validT & ~rem;
        keptV = (lane == t) ? kept : keptV;
    }

    int base = 0;
    for (int c = 0; c < WORDS && base < POSTN; ++c) {
        unsigned long long kw = readlane64(keptV, c);
        bool f = (kw & mybit) != 0ull;
        int rank = base + __popcll(kw & (mybit - 1ull));
        if (f && rank < POSTN) {
            int i = c * 64 + lane;
            int src = b * KC + i;
            float* o5 = out + ((size_t)b * POSTN + rank) * 5;
            o5[0] = sbox[src * 4 + 0]; o5[1] = sbox[src * 4 + 1];
            o5[2] = sbox[src * 4 + 2]; o5[3] = sbox[src * 4 + 3];
            o5[4] = ssc[src];
            out[(size_t)NB * POSTN * 5 + b * POSTN + rank] = (float)slb[src];
            out[(size_t)NB * POSTN * 5 + NB * POSTN + b * POSTN + rank] = 1.0f;
        }
        base += __popcll(kw);
    }
}

// ---------------- launch ----------------
extern "C" void kernel_launch(void* const* d_in, const int* in_sizes, int n_in,
                              void* d_out, int out_size, void* d_ws, size_t ws_size,
                              hipStream_t stream) {
    const float *loc[5], *cls[5], *box[5], *ctr[5];
    for (int l = 0; l < 5; ++l) {
        loc[l] = (const float*)d_in[l * 4 + 0];
        cls[l] = (const float*)d_in[l * 4 + 1];
        box[l] = (const float*)d_in[l * 4 + 2];
        ctr[l] = (const float*)d_in[l * 4 + 3];
    }
    char* ws = (char*)d_ws;
    unsigned* hist = (unsigned*)(ws + OFF_HIST);
    unsigned* T    = (unsigned*)(ws + OFF_T);
    unsigned* cnt  = (unsigned*)(ws + OFF_CNT);
    Cand* cand     = (Cand*)(ws + OFF_CAND);
    float* cbox    = (float*)(ws + OFF_CBOX);
    float* csc     = (float*)(ws + OFF_CSC);
    int*   clb     = (int*)(ws + OFF_CLB);
    float* ssc     = (float*)(ws + OFF_SSC);
    int*   slb     = (int*)(ws + OFF_SLB);
    float* sbox    = (float*)(ws + OFF_SBOX);
    float* obox    = (float*)(ws + OFF_OBOX);
    unsigned long long* M = (unsigned long long*)(ws + OFF_M);
    float* sct     = (float*)(ws + OFF_SCT);
    unsigned short* gmx = (unsigned short*)(ws + OFF_GMX);
    float* out = (float*)d_out;

    int zn = (int)(OFF_CAND / 4);
    k_zero<<<(zn + THREADS - 1) / THREADS, THREADS, 0, stream>>>((unsigned*)ws, zn);
    k_prep<<<(SCTN + THREADS - 1) / THREADS, THREADS, 0, stream>>>(
        ctr[0], ctr[1], ctr[2], ctr[3], ctr[4], sct);
    k_hist<<<dim3(CHUNKS, NB), THREADS, 0, stream>>>(
        cls[0], cls[1], cls[2], cls[3], cls[4], sct, gmx, hist);
    k_thresh<<<NPAIR, THREADS, 0, stream>>>(hist, T);
    k_collect<<<dim3(CHUNKS, NB), THREADS, 0, stream>>>(
        cls[0], cls[1], cls[2], cls[3], cls[4], sct, gmx, T, cand, cnt);
    k_select<<<NPAIR, THREADS, 0, stream>>>(
        cand, cnt,
        loc[0], loc[1], loc[2], loc[3], loc[4],
        box[0], box[1], box[2], box[3], box[4],
        cbox, csc, clb);
    k_sortimg<<<NB, SORTT, 0, stream>>>(csc, clb, cbox, ssc, slb, sbox, obox);
    k_iou<<<dim3(WORDS, WORDS, NB), 64, 0, stream>>>(obox, M);
    k_nms<<<NB, 64, 0, stream>>>(M, ssc, slb, sbox, out);
}

// Round 6
// 332.761 us; speedup vs baseline: 2.0471x; 1.0464x over previous
//
#include <hip/hip_runtime.h>
#include <math.h>

#define THREADS 256
#define SORTT 1024

// ---------------- problem constants (fixed by reference setup) ----------------
constexpr int NLEV  = 5;
constexpr int NB    = 16;     // batch
constexpr int NC    = 80;     // classes (label = c+1)
constexpr int TOPN  = 300;
constexpr int KC    = NLEV * TOPN;   // 1500 candidates per image
constexpr int KROWS = 1536;          // padded rows for NMS bitmask
constexpr int WORDS = 24;            // 1536 / 64
constexpr int POSTN = 100;
constexpr int CAP   = 4096;          // per-(b,level) candidate pool
constexpr int NBINS = 2048;          // score-histogram bins over [0.25, 1.0)
constexpr int NPAIR = NLEV * NB;     // 80

constexpr int HW0 = 12800, HW1 = 3200, HW2 = 800, HW3 = 208, HW4 = 56;
constexpr int CH0 = 63, CH1 = 16, CH2 = 4, CH3 = 2, CH4 = 1;  // 16384-elem chunks per (b,level)
constexpr int CHUNKS = CH0 + CH1 + CH2 + CH3 + CH4;           // 86
constexpr int CHUNK_ELEMS = 16384;

// sigmoid(ctr) precompute: per-level bases into sct[] (floats), layout [li][b][hw]
constexpr int SCTB0 = 0;
constexpr int SCTB1 = 204800;
constexpr int SCTB2 = 256000;
constexpr int SCTB3 = 268800;
constexpr int SCTB4 = 272128;
constexpr int SCTN  = 273024;

// group-max skip list: 256-element groups, layout [li][b][g] (u16)
constexpr int GPL0 = 4000, GPL1 = 1000, GPL2 = 250, GPL3 = 65, GPL4 = 18;
constexpr int GMXB0 = 0;
constexpr int GMXB1 = GMXB0 + NB * GPL0;
constexpr int GMXB2 = GMXB1 + NB * GPL1;
constexpr int GMXB3 = GMXB2 + NB * GPL2;
constexpr int GMXB4 = GMXB3 + NB * GPL3;
constexpr int GMXN  = GMXB4 + NB * GPL4;

// ---------------- workspace layout ----------------
constexpr size_t align256(size_t x) { return (x + 255) & ~(size_t)255; }
constexpr size_t OFF_HIST = 0;
constexpr size_t OFF_T    = OFF_HIST + (size_t)NPAIR * NBINS * 4;
constexpr size_t OFF_CNT  = OFF_T + (size_t)NPAIR * 4;
constexpr size_t OFF_CAND = align256(OFF_CNT + (size_t)NPAIR * 4);
constexpr size_t OFF_CBOX = align256(OFF_CAND + (size_t)NPAIR * CAP * 8);
constexpr size_t OFF_CSC  = align256(OFF_CBOX + (size_t)NB * KC * 4 * 4);
constexpr size_t OFF_CLB  = align256(OFF_CSC  + (size_t)NB * KC * 4);
constexpr size_t OFF_SSC  = align256(OFF_CLB  + (size_t)NB * KC * 4);
constexpr size_t OFF_SLB  = align256(OFF_SSC  + (size_t)NB * KC * 4);
constexpr size_t OFF_SBOX = align256(OFF_SLB  + (size_t)NB * KC * 4);
constexpr size_t OFF_OBOX = align256(OFF_SBOX + (size_t)NB * KC * 4 * 4);
constexpr size_t OFF_M    = align256(OFF_OBOX + (size_t)NB * KC * 4 * 4);
constexpr size_t OFF_SCT  = align256(OFF_M + (size_t)NB * KROWS * WORDS * 8);
constexpr size_t OFF_GMX  = align256(OFF_SCT + (size_t)SCTN * 4);
// total ~15.8 MB

struct Cand { float s; int i; };

// ---------------- helpers ----------------
__device__ __forceinline__ float sigm(float x) { return 1.0f / (1.0f + expf(-x)); }

// monotone key over score in (0,1): 2048 bins over [0.25,1.0), everything below -> bin 0
__device__ __forceinline__ unsigned scoreKey(float s) {
    unsigned b = __float_as_uint(s);
    unsigned k = (b < 0x3E800000u) ? 0u : ((b - 0x3E800000u) >> 13);
    return (k > 2047u) ? 2047u : k;
}

__device__ __forceinline__ unsigned long long readlane64(unsigned long long v, int l) {
    unsigned lo = (unsigned)__builtin_amdgcn_readlane((int)(unsigned)(v & 0xffffffffull), l);
    unsigned hi = (unsigned)__builtin_amdgcn_readlane((int)(unsigned)(v >> 32), l);
    return ((unsigned long long)hi << 32) | lo;
}

__device__ void bitonicShared(float* ss, int* si, int N) {
    for (int k = 2; k <= N; k <<= 1) {
        for (int j = k >> 1; j > 0; j >>= 1) {
            __syncthreads();
            for (int i = threadIdx.x; i < N; i += blockDim.x) {
                int ixj = i ^ j;
                if (ixj > i) {
                    float s1 = ss[i], s2 = ss[ixj];
                    int a1 = si[i], a2 = si[ixj];
                    bool bef = (s1 > s2) || (s1 == s2 && a1 < a2);   // desc, idx asc
                    bool up = ((i & k) == 0);
                    if (up ? !bef : bef) { ss[i] = s2; ss[ixj] = s1; si[i] = a2; si[ixj] = a1; }
                }
            }
        }
    }
    __syncthreads();
}

// ---------------- K0: zero hist + counters ----------------
__global__ void k_zero(unsigned* p, int n) {
    int i = blockIdx.x * THREADS + threadIdx.x;
    if (i < n) p[i] = 0;
}

// ---------------- K0b: precompute sigmoid(ctr) ----------------
__global__ __launch_bounds__(THREADS) void k_prep(
        const float* t0, const float* t1, const float* t2, const float* t3, const float* t4,
        float* __restrict__ sct) {
    int i = blockIdx.x * THREADS + threadIdx.x;
    if (i >= SCTN) return;
    float x;
    if (i < SCTB1)      x = t0[i - SCTB0];
    else if (i < SCTB2) x = t1[i - SCTB1];
    else if (i < SCTB3) x = t2[i - SCTB2];
    else if (i < SCTB4) x = t3[i - SCTB3];
    else                x = t4[i - SCTB4];
    sct[i] = sigm(x);   // exact: same formula as reference sigmoid usage
}

// ---------------- K1: histogram + per-256-group max key ----------------
template<int HW, int SCTB, int GPL, int GMXB>
__device__ __forceinline__ void histChunkV(int chunkLocal, int b,
        const float* __restrict__ cls, const float* __restrict__ sct,
        unsigned short* __restrict__ gmx, unsigned* __restrict__ h) {
    constexpr int NE = HW * NC;
    const float* cp = cls + (size_t)b * NE;
    const float* tb = sct + SCTB + b * HW;
    unsigned short* gp = gmx + GMXB + (size_t)b * GPL;
    int w = threadIdx.x >> 6, lane = threadIdx.x & 63;
    for (int gi = w; gi < 64; gi += 4) {
        int g = chunkLocal * 64 + gi;
        int ebase = g * 256;
        if (ebase >= NE) break;
        int e = ebase + lane * 4;
        int kmax = 0;
        if (e < NE) {
            int c = e / HW; int hwb = e - c * HW;        // 4 elems stay in one row (HW%4==0)
            float4 x4 = *(const float4*)(cp + e);
            float4 t4 = *(const float4*)(tb + hwb);
            #pragma unroll
            for (int q = 0; q < 4; ++q) {
                float x = (q == 0) ? x4.x : (q == 1) ? x4.y : (q == 2) ? x4.z : x4.w;
                float t = (q == 0) ? t4.x : (q == 1) ? t4.y : (q == 2) ? t4.z : t4.w;
                float scls = sigm(x);
                float s = __fmul_rn(scls, t);
                unsigned key = scoreKey(s);
                if (key) atomicAdd(&h[key], 1u);
                kmax = max(kmax, (int)key);
            }
        }
        #pragma unroll
        for (int sh = 1; sh < 64; sh <<= 1) kmax = max(kmax, __shfl_xor(kmax, sh, 64));
        if (lane == 0) gp[g] = (unsigned short)kmax;
    }
}

__global__ __launch_bounds__(THREADS) void k_hist(
        const float* c0, const float* c1, const float* c2, const float* c3, const float* c4,
        const float* __restrict__ sct, unsigned short* __restrict__ gmx, unsigned* ghist) {
    __shared__ unsigned h[NBINS];
    for (int k = threadIdx.x; k < NBINS; k += THREADS) h[k] = 0;
    __syncthreads();
    int cx = blockIdx.x, b = blockIdx.y;
    int li;
    if (cx < CH0)                 { histChunkV<HW0,SCTB0,GPL0,GMXB0>(cx, b, c0, sct, gmx, h); li = 0; }
    else if (cx < CH0+CH1)        { histChunkV<HW1,SCTB1,GPL1,GMXB1>(cx-CH0, b, c1, sct, gmx, h); li = 1; }
    else if (cx < CH0+CH1+CH2)    { histChunkV<HW2,SCTB2,GPL2,GMXB2>(cx-CH0-CH1, b, c2, sct, gmx, h); li = 2; }
    else if (cx < CH0+CH1+CH2+CH3){ histChunkV<HW3,SCTB3,GPL3,GMXB3>(cx-CH0-CH1-CH2, b, c3, sct, gmx, h); li = 3; }
    else                          { histChunkV<HW4,SCTB4,GPL4,GMXB4>(cx-CH0-CH1-CH2-CH3, b, c4, sct, gmx, h); li = 4; }
    __syncthreads();
    unsigned* gp = ghist + (size_t)(li * NB + b) * NBINS;
    for (int k = threadIdx.x; k < NBINS; k += THREADS) {
        unsigned v = h[k];
        if (v) atomicAdd(&gp[k], v);
    }
}

// ---------------- K2: find per-(b,level) key threshold ----------------
__global__ __launch_bounds__(THREADS) void k_thresh(const unsigned* __restrict__ ghist, unsigned* __restrict__ T) {
    int pid = blockIdx.x;
    const unsigned* h = ghist + (size_t)pid * NBINS;
    __shared__ unsigned seg[THREADS];
    constexpr int SB = NBINS / THREADS;   // 8
    unsigned s = 0;
    for (int k = 0; k < SB; ++k) s += h[threadIdx.x * SB + k];
    seg[threadIdx.x] = s;
    __syncthreads();
    if (threadIdx.x == 0) {
        unsigned acc = 0; unsigned Tv = 0;
        int t = THREADS - 1;
        for (; t >= 0; --t) {
            if (acc + seg[t] >= (unsigned)TOPN) break;
            acc += seg[t];
        }
        if (t >= 0) {
            int lo = t * SB;
            int bin = lo + SB - 1;
            for (; bin >= lo; --bin) { acc += h[bin]; if (acc >= (unsigned)TOPN) break; }
            Tv = (unsigned)max(bin, lo);
        }
        T[pid] = Tv;   // 0 => collect everything (degenerate, <300 passing)
    }
}

// ---------------- K3: skip-list-driven compaction ----------------
constexpr int LBUF = 1024;

template<int HW, int SCTB, int GPL, int GMXB>
__device__ __forceinline__ void collectChunkV(int chunkLocal, int b, int li,
        const float* __restrict__ cls, const float* __restrict__ sct,
        const unsigned short* __restrict__ gmx,
        const unsigned* __restrict__ T, Cand* __restrict__ candAll, unsigned* __restrict__ cnt,
        Cand* __restrict__ lbuf, unsigned* __restrict__ lcnt, unsigned long long* __restrict__ pmShared) {
    constexpr int NE = HW * NC;
    int pid = li * NB + b;
    unsigned Tv = T[pid];
    Cand* cd = candAll + (size_t)pid * CAP;
    const float* cp = cls + (size_t)b * NE;
    const float* tb = sct + SCTB + b * HW;
    const unsigned short* gp = gmx + GMXB + (size_t)b * GPL;
    if (threadIdx.x < 64) {
        int g = chunkLocal * 64 + threadIdx.x;
        bool ok = ((size_t)g * 256 < (size_t)NE);
        if (ok && Tv) ok = (gp[g] >= (unsigned short)Tv);
        unsigned long long m = __ballot(ok);
        if (threadIdx.x == 0) *pmShared = m;
    }
    __syncthreads();
    unsigned long long pm = *pmShared;
    while (pm) {
        int gi = __builtin_ctzll(pm);
        pm &= pm - 1;
        int e = (chunkLocal * 64 + gi) * 256 + threadIdx.x;
        if (e < NE) {
            float x = cp[e];
            int c = e / HW; int hw = e - c * HW;
            float scls = sigm(x);
            float s = __fmul_rn(scls, tb[hw]);
            unsigned key = scoreKey(s);
            bool take = Tv ? (key >= Tv) : (scls > 0.05f);
            if (take) {
                unsigned slot = atomicAdd(lcnt, 1u);
                if (slot < (unsigned)LBUF) { lbuf[slot].s = s; lbuf[slot].i = hw * NC + c; }
                else {
                    unsigned gs = atomicAdd(&cnt[pid], 1u);   // rare fallback
                    if (gs < (unsigned)CAP) { cd[gs].s = s; cd[gs].i = hw * NC + c; }
                }
            }
        }
    }
}

__global__ __launch_bounds__(THREADS) void k_collect(
        const float* c0, const float* c1, const float* c2, const float* c3, const float* c4,
        const float* __restrict__ sct, const unsigned short* __restrict__ gmx,
        const unsigned* T, Cand* cand, unsigned* cnt) {
    __shared__ Cand lbuf[LBUF];
    __shared__ unsigned lcnt, gbase;
    __shared__ unsigned long long pmShared;
    if (threadIdx.x == 0) lcnt = 0;
    __syncthreads();
    int cx = blockIdx.x, b = blockIdx.y;
    int li;
    if (cx < CH0)                 { collectChunkV<HW0,SCTB0,GPL0,GMXB0>(cx, b, 0, c0, sct, gmx, T, cand, cnt, lbuf, &lcnt, &pmShared); li = 0; }
    else if (cx < CH0+CH1)        { collectChunkV<HW1,SCTB1,GPL1,GMXB1>(cx-CH0, b, 1, c1, sct, gmx, T, cand, cnt, lbuf, &lcnt, &pmShared); li = 1; }
    else if (cx < CH0+CH1+CH2)    { collectChunkV<HW2,SCTB2,GPL2,GMXB2>(cx-CH0-CH1, b, 2, c2, sct, gmx, T, cand, cnt, lbuf, &lcnt, &pmShared); li = 2; }
    else if (cx < CH0+CH1+CH2+CH3){ collectChunkV<HW3,SCTB3,GPL3,GMXB3>(cx-CH0-CH1-CH2, b, 3, c3, sct, gmx, T, cand, cnt, lbuf, &lcnt, &pmShared); li = 3; }
    else                          { collectChunkV<HW4,SCTB4,GPL4,GMXB4>(cx-CH0-CH1-CH2-CH3, b, 4, c4, sct, gmx, T, cand, cnt, lbuf, &lcnt, &pmShared); li = 4; }
    __syncthreads();
    int pid = li * NB + b;
    unsigned n = lcnt; if (n > (unsigned)LBUF) n = LBUF;
    if (threadIdx.x == 0) gbase = n ? atomicAdd(&cnt[pid], n) : 0u;
    __syncthreads();
    Cand* cd = cand + (size_t)pid * CAP;
    for (unsigned i = threadIdx.x; i < n; i += THREADS) {
        unsigned s = gbase + i;
        if (s < (unsigned)CAP) cd[s] = lbuf[i];
    }
}

// ---------------- K4: exact top-300 per (b,level) + decode ----------------
__global__ __launch_bounds__(THREADS) void k_select(
        const Cand* __restrict__ candAll, const unsigned* __restrict__ cntAll,
        const float* l0, const float* l1, const float* l2, const float* l3, const float* l4,
        const float* b0, const float* b1, const float* b2, const float* b3, const float* b4,
        float* __restrict__ cbox, float* __restrict__ csc, int* __restrict__ clb) {
    __shared__ float ss[CAP];
    __shared__ int si[CAP];
    int pid = blockIdx.x;
    int li = pid / NB, b = pid - li * NB;
    int n = (int)min(cntAll[pid], (unsigned)CAP);
    const Cand* cd = candAll + (size_t)pid * CAP;
    int N = 2; while (N < n) N <<= 1;
    for (int k = threadIdx.x; k < N; k += THREADS) {
        if (k < n) { ss[k] = cd[k].s; si[k] = cd[k].i; }
        else       { ss[k] = -INFINITY; si[k] = 0x40000000 + k; }
    }
    __syncthreads();
    bitonicShared(ss, si, N);

    const float* locp; const float* boxp; int HW;
    switch (li) {
        case 0: locp = l0; boxp = b0; HW = HW0; break;
        case 1: locp = l1; boxp = b1; HW = HW1; break;
        case 2: locp = l2; boxp = b2; HW = HW2; break;
        case 3: locp = l3; boxp = b3; HW = HW3; break;
        default: locp = l4; boxp = b4; HW = HW4; break;
    }
    for (int j = threadIdx.x; j < TOPN; j += THREADS) {
        int cidx = b * KC + li * TOPN + j;
        bool ok = (j < n);
        float s = ok ? ss[j] : -INFINITY;
        ok = ok && (s > 0.0f);
        if (ok) {
            int idx = si[j];
            int hw = idx / NC, c = idx - hw * NC;
            float lx = locp[hw * 2 + 0], ly = locp[hw * 2 + 1];
            const float* bp = boxp + (size_t)b * 4 * HW + hw;
            float bl = bp[0], bt = bp[HW], br = bp[2 * HW], bb = bp[3 * HW];
            float x1 = fminf(fmaxf(__fsub_rn(lx, bl), 0.0f), 1023.0f);
            float y1 = fminf(fmaxf(__fsub_rn(ly, bt), 0.0f),  799.0f);
            float x2 = fminf(fmaxf(__fadd_rn(lx, br), 0.0f), 1023.0f);
            float y2 = fminf(fmaxf(__fadd_rn(ly, bb), 0.0f),  799.0f);
            cbox[cidx * 4 + 0] = x1; cbox[cidx * 4 + 1] = y1;
            cbox[cidx * 4 + 2] = x2; cbox[cidx * 4 + 3] = y2;
            csc[cidx] = sqrtf(fmaxf(s, 1e-12f));
            clb[cidx] = c + 1;
        } else {
            cbox[cidx * 4 + 0] = 0.0f; cbox[cidx * 4 + 1] = 0.0f;
            cbox[cidx * 4 + 2] = 0.0f; cbox[cidx * 4 + 3] = 0.0f;
            csc[cidx] = -INFINITY;
            clb[cidx] = 0;
        }
    }
}

// ---------------- K5a: per-image sort by score desc (1024 threads) ----------------
__global__ __launch_bounds__(SORTT) void k_sortimg(
        const float* __restrict__ csc, const int* __restrict__ clb, const float* __restrict__ cbox,
        float* __restrict__ ssc, int* __restrict__ slb, float* __restrict__ sbox, float* __restrict__ obox) {
    int b = blockIdx.x;
    __shared__ float ss[2048];
    __shared__ int si[2048];
    for (int k = threadIdx.x; k < 2048; k += SORTT) {
        if (k < KC) { ss[k] = csc[b * KC + k]; si[k] = k; }
        else        { ss[k] = -INFINITY; si[k] = 0x40000000 + k; }
    }
    __syncthreads();
    bitonicShared(ss, si, 2048);
    for (int k = threadIdx.x; k < KC; k += SORTT) {
        int sl = si[k];                 // all 1500 real entries sort before pads
        int src = b * KC + sl;
        int dst = b * KC + k;
        float sc = ss[k];
        int lab = clb[src];
        ssc[dst] = sc; slb[dst] = lab;
        float off = __fmul_rn((float)lab, 1025.0f);   // offset = max(800,1024)+1
        #pragma unroll
        for (int q = 0; q < 4; ++q) {
            float v = cbox[src * 4 + q];
            sbox[dst * 4 + q] = v;
            obox[dst * 4 + q] = __fadd_rn(v, off);
        }
    }
}

// ---------------- K5b: suppression bitmask (iou > 0.6 && j > i) ----------------
// Writes COLUMN-MAJOR: MT[b][w][row]  (coalesced store; coalesced column loads in k_nms)
__global__ __launch_bounds__(64) void k_iou(const float* __restrict__ obox,
                                            unsigned long long* __restrict__ MT) {
    int w = blockIdx.x, tile = blockIdx.y, b = blockIdx.z;
    if (w < tile) return;
    int lane = threadIdx.x;
    __shared__ float4 sj[64];
    __shared__ float aj[64];
    const float4* op = (const float4*)obox + (size_t)b * KC;
    int j0 = w * 64;
    int jl = j0 + lane;
    float4 vj = op[(jl < KC) ? jl : (KC - 1)];
    sj[lane] = vj;
    aj[lane] = __fmul_rn(__fsub_rn(vj.z, vj.x), __fsub_rn(vj.w, vj.y));
    int i = tile * 64 + lane;
    float4 bi = op[(i < KC) ? i : (KC - 1)];
    float ai = __fmul_rn(__fsub_rn(bi.z, bi.x), __fsub_rn(bi.w, bi.y));
    __syncthreads();
    unsigned long long bits = 0;
    int jmax = min(64, KC - j0);
    for (int jj = 0; jj < jmax; ++jj) {
        float4 bj = sj[jj];            // wave-uniform -> LDS broadcast
        float xx1 = fmaxf(bi.x, bj.x), yy1 = fmaxf(bi.y, bj.y);
        float xx2 = fminf(bi.z, bj.z), yy2 = fminf(bi.w, bj.w);
        float ww = fmaxf(__fsub_rn(xx2, xx1), 0.0f);
        float hh = fmaxf(__fsub_rn(yy2, yy1), 0.0f);
        float inter = __fmul_rn(ww, hh);
        float uni = __fsub_rn(__fadd_rn(ai, aj[jj]), inter);
        float iou = __fdiv_rn(inter, fmaxf(uni, 1e-9f));
        bool kp = ((j0 + jj) > i) && (iou > 0.6f);
        bits |= kp ? (1ull << jj) : 0ull;
    }
    if (i >= KC) bits = 0;
    MT[((size_t)b * WORDS + w) * KROWS + i] = bits;
}

// ---------------- K5c: pipelined pull-style greedy scan (1 wave/image) ----------------
// All load addresses are static -> prefetch column t+1 into registers while computing
// tile t; sched_barrier(0) pins the load batch above the compute so it can't be sunk.
__global__ __launch_bounds__(64) void k_nms(
        const unsigned long long* __restrict__ MT, const float* __restrict__ ssc,
        const int* __restrict__ slb, const float* __restrict__ sbox, float* __restrict__ out) {
    int b = blockIdx.x, lane = threadIdx.x;
    for (int k = lane; k < POSTN * 5; k += 64) out[(size_t)b * POSTN * 5 + k] = 0.0f;
    for (int k = lane; k < POSTN; k += 64) {
        out[(size_t)NB * POSTN * 5 + b * POSTN + k] = 0.0f;                 // labels
        out[(size_t)NB * POSTN * 5 + NB * POSTN + b * POSTN + k] = 0.0f;    // valid
    }
    const float* sp = ssc + b * KC;
    unsigned long long validV = 0;
    for (int c = 0; c < WORDS; ++c) {
        int i = c * 64 + lane;
        bool f = (i < KC) && (sp[i] > 0.0f);
        unsigned long long m = __ballot(f);
        validV = (lane == c) ? m : validV;
    }
    unsigned long long mybit = 1ull << lane;
    unsigned long long keptV = 0;
    const unsigned long long* Mb = MT + (size_t)b * WORDS * KROWS;

    // prefetch column 0 (only chunk 0 exists for t=0)
    unsigned long long pv[WORDS];
    pv[0] = Mb[lane];

    for (int t = 0; t < WORDS; ++t) {
        // ---- issue next column's loads (static addresses, coalesced) ----
        int tn = (t + 1 < WORDS) ? (t + 1) : t;
        const unsigned long long* cp = Mb + (size_t)tn * KROWS + lane;
        unsigned long long nv[WORDS];
        #pragma unroll
        for (int c = 0; c < WORDS; ++c) {
            int cc = (c <= tn) ? c : 0;       // clamp: harmless duplicate of chunk 0
            nv[c] = cp[(size_t)cc * 64];
        }
        __builtin_amdgcn_sched_barrier(0);    // loads stay above; compute below

        // ---- compute tile t from pv[] ----
        unsigned long long D = pv[t];
        unsigned long long acc = 0;
        #pragma unroll
        for (int c = 0; c < WORDS; ++c) {
            if (c < t) {
                unsigned long long kc = readlane64(keptV, c);
                if (kc & mybit) acc |= pv[c];
            }
        }
        #pragma unroll
        for (int s = 1; s < 64; s <<= 1) acc |= __shfl_xor(acc, s, 64);

        unsigned long long validT = readlane64(validV, t);
        unsigned long long rem = acc;
        unsigned long long sup = __ballot(D != 0ull) & validT;
        unsigned long long todoS = sup;
        while (todoS) {
            int r = __builtin_ctzll(todoS);
            todoS &= todoS - 1;
            if (!((rem >> r) & 1ull)) {
                unsigned long long Dr = readlane64(D, r);
                rem |= Dr;
                todoS &= ~Dr;
            }
        }
        unsigned long long kept = validT & ~rem;
        keptV = (lane == t) ? kept : keptV;

        // ---- rotate prefetch buffer ----
        #pragma unroll
        for (int c = 0; c < WORDS; ++c) pv[c] = nv[c];
    }

    int base = 0;
    for (int c = 0; c < WORDS && base < POSTN; ++c) {
        unsigned long long kw = readlane64(keptV, c);
        bool f = (kw & mybit) != 0ull;
        int rank = base + __popcll(kw & (mybit - 1ull));
        if (f && rank < POSTN) {
            int i = c * 64 + lane;
            int src = b * KC + i;
            float* o5 = out + ((size_t)b * POSTN + rank) * 5;
            o5[0] = sbox[src * 4 + 0]; o5[1] = sbox[src * 4 + 1];
            o5[2] = sbox[src * 4 + 2]; o5[3] = sbox[src * 4 + 3];
            o5[4] = ssc[src];
            out[(size_t)NB * POSTN * 5 + b * POSTN + rank] = (float)slb[src];
            out[(size_t)NB * POSTN * 5 + NB * POSTN + b * POSTN + rank] = 1.0f;
        }
        base += __popcll(kw);
    }
}

// ---------------- launch ----------------
extern "C" void kernel_launch(void* const* d_in, const int* in_sizes, int n_in,
                              void* d_out, int out_size, void* d_ws, size_t ws_size,
                              hipStream_t stream) {
    const float *loc[5], *cls[5], *box[5], *ctr[5];
    for (int l = 0; l < 5; ++l) {
        loc[l] = (const float*)d_in[l * 4 + 0];
        cls[l] = (const float*)d_in[l * 4 + 1];
        box[l] = (const float*)d_in[l * 4 + 2];
        ctr[l] = (const float*)d_in[l * 4 + 3];
    }
    char* ws = (char*)d_ws;
    unsigned* hist = (unsigned*)(ws + OFF_HIST);
    unsigned* T    = (unsigned*)(ws + OFF_T);
    unsigned* cnt  = (unsigned*)(ws + OFF_CNT);
    Cand* cand     = (Cand*)(ws + OFF_CAND);
    float* cbox    = (float*)(ws + OFF_CBOX);
    float* csc     = (float*)(ws + OFF_CSC);
    int*   clb     = (int*)(ws + OFF_CLB);
    float* ssc     = (float*)(ws + OFF_SSC);
    int*   slb     = (int*)(ws + OFF_SLB);
    float* sbox    = (float*)(ws + OFF_SBOX);
    float* obox    = (float*)(ws + OFF_OBOX);
    unsigned long long* MT = (unsigned long long*)(ws + OFF_M);
    float* sct     = (float*)(ws + OFF_SCT);
    unsigned short* gmx = (unsigned short*)(ws + OFF_GMX);
    float* out = (float*)d_out;

    int zn = (int)(OFF_CAND / 4);
    k_zero<<<(zn + THREADS - 1) / THREADS, THREADS, 0, stream>>>((unsigned*)ws, zn);
    k_prep<<<(SCTN + THREADS - 1) / THREADS, THREADS, 0, stream>>>(
        ctr[0], ctr[1], ctr[2], ctr[3], ctr[4], sct);
    k_hist<<<dim3(CHUNKS, NB), THREADS, 0, stream>>>(
        cls[0], cls[1], cls[2], cls[3], cls[4], sct, gmx, hist);
    k_thresh<<<NPAIR, THREADS, 0, stream>>>(hist, T);
    k_collect<<<dim3(CHUNKS, NB), THREADS, 0, stream>>>(
        cls[0], cls[1], cls[2], cls[3], cls[4], sct, gmx, T, cand, cnt);
    k_select<<<NPAIR, THREADS, 0, stream>>>(
        cand, cnt,
        loc[0], loc[1], loc[2], loc[3], loc[4],
        box[0], box[1], box[2], box[3], box[4],
        cbox, csc, clb);
    k_sortimg<<<NB, SORTT, 0, stream>>>(csc, clb, cbox, ssc, slb, sbox, obox);
    k_iou<<<dim3(WORDS, WORDS, NB), 64, 0, stream>>>(obox, MT);
    k_nms<<<NB, 64, 0, stream>>>(MT, ssc, slb, sbox, out);
}

// Round 7
// 317.306 us; speedup vs baseline: 2.1468x; 1.0487x over previous
//
#include <hip/hip_runtime.h>
#include <math.h>

#define THREADS 256
#define SORTT 1024

// ---------------- problem constants (fixed by reference setup) ----------------
constexpr int NLEV  = 5;
constexpr int NB    = 16;     // batch
constexpr int NC    = 80;     // classes (label = c+1)
constexpr int TOPN  = 300;
constexpr int KC    = NLEV * TOPN;   // 1500 candidates per image
constexpr int KROWS = 1536;          // padded rows for NMS bitmask
constexpr int WORDS = 24;            // 1536 / 64
constexpr int POSTN = 100;
constexpr int CAP   = 4096;          // per-(b,level) candidate pool
constexpr int NBINS = 2048;          // score-histogram bins over [0.25, 1.0)
constexpr int NPAIR = NLEV * NB;     // 80

constexpr int HW0 = 12800, HW1 = 3200, HW2 = 800, HW3 = 208, HW4 = 56;
constexpr int CH0 = 63, CH1 = 16, CH2 = 4, CH3 = 2, CH4 = 1;  // 16384-elem chunks per (b,level)
constexpr int CHUNKS = CH0 + CH1 + CH2 + CH3 + CH4;           // 86
constexpr int CHUNK_ELEMS = 16384;

// sigmoid(ctr) precompute: per-level bases into sct[] (floats), layout [li][b][hw]
constexpr int SCTB0 = 0;
constexpr int SCTB1 = 204800;
constexpr int SCTB2 = 256000;
constexpr int SCTB3 = 268800;
constexpr int SCTB4 = 272128;
constexpr int SCTN  = 273024;

// group-max skip list: 256-element groups, layout [li][b][g] (u16)
constexpr int GPL0 = 4000, GPL1 = 1000, GPL2 = 250, GPL3 = 65, GPL4 = 18;
constexpr int GMXB0 = 0;
constexpr int GMXB1 = GMXB0 + NB * GPL0;
constexpr int GMXB2 = GMXB1 + NB * GPL1;
constexpr int GMXB3 = GMXB2 + NB * GPL2;
constexpr int GMXB4 = GMXB3 + NB * GPL3;
constexpr int GMXN  = GMXB4 + NB * GPL4;

// ---------------- workspace layout ----------------
constexpr size_t align256(size_t x) { return (x + 255) & ~(size_t)255; }
constexpr size_t OFF_HIST = 0;
constexpr size_t OFF_T    = OFF_HIST + (size_t)NPAIR * NBINS * 4;
constexpr size_t OFF_CNT  = OFF_T + (size_t)NPAIR * 4;
constexpr size_t OFF_CAND = align256(OFF_CNT + (size_t)NPAIR * 4);
constexpr size_t OFF_CBOX = align256(OFF_CAND + (size_t)NPAIR * CAP * 8);
constexpr size_t OFF_CSC  = align256(OFF_CBOX + (size_t)NB * KC * 4 * 4);
constexpr size_t OFF_CLB  = align256(OFF_CSC  + (size_t)NB * KC * 4);
constexpr size_t OFF_SSC  = align256(OFF_CLB  + (size_t)NB * KC * 4);
constexpr size_t OFF_SLB  = align256(OFF_SSC  + (size_t)NB * KC * 4);
constexpr size_t OFF_SBOX = align256(OFF_SLB  + (size_t)NB * KC * 4);
constexpr size_t OFF_OBOX = align256(OFF_SBOX + (size_t)NB * KC * 4 * 4);
constexpr size_t OFF_M    = align256(OFF_OBOX + (size_t)NB * KC * 4 * 4);
constexpr size_t OFF_SCT  = align256(OFF_M + (size_t)NB * KROWS * WORDS * 8);
constexpr size_t OFF_GMX  = align256(OFF_SCT + (size_t)SCTN * 4);
// total ~15.8 MB

struct Cand { float s; int i; };

// ---------------- helpers ----------------
__device__ __forceinline__ float sigm(float x) { return 1.0f / (1.0f + expf(-x)); }

// fast sigmoid (hw v_exp_f32 + v_rcp_f32, <=~4 ulp). Used ONLY for the histogram /
// skip-list (threshold selection): |approx key - exact key| <= 1 bin, compensated
// by collecting key >= TA-1 and gating groups by gmx+1 >= Tv. Collect/select use
// the exact sigm() so the final output is bit-identical.
__device__ __forceinline__ float sigf(float x) {
#if __has_builtin(__builtin_amdgcn_exp2f) && __has_builtin(__builtin_amdgcn_rcpf)
    float e = __builtin_amdgcn_exp2f(__fmul_rn(x, -1.44269504088896340736f));
    return __builtin_amdgcn_rcpf(__fadd_rn(1.0f, e));
#else
    return 1.0f / (1.0f + __expf(-x));
#endif
}

// monotone key over score in (0,1): 2048 bins over [0.25,1.0), everything below -> bin 0
__device__ __forceinline__ unsigned scoreKey(float s) {
    unsigned b = __float_as_uint(s);
    unsigned k = (b < 0x3E800000u) ? 0u : ((b - 0x3E800000u) >> 13);
    return (k > 2047u) ? 2047u : k;
}

__device__ __forceinline__ unsigned long long readlane64(unsigned long long v, int l) {
    unsigned lo = (unsigned)__builtin_amdgcn_readlane((int)(unsigned)(v & 0xffffffffull), l);
    unsigned hi = (unsigned)__builtin_amdgcn_readlane((int)(unsigned)(v >> 32), l);
    return ((unsigned long long)hi << 32) | lo;
}

__device__ void bitonicShared(float* ss, int* si, int N) {
    for (int k = 2; k <= N; k <<= 1) {
        for (int j = k >> 1; j > 0; j >>= 1) {
            __syncthreads();
            for (int i = threadIdx.x; i < N; i += blockDim.x) {
                int ixj = i ^ j;
                if (ixj > i) {
                    float s1 = ss[i], s2 = ss[ixj];
                    int a1 = si[i], a2 = si[ixj];
                    bool bef = (s1 > s2) || (s1 == s2 && a1 < a2);   // desc, idx asc
                    bool up = ((i & k) == 0);
                    if (up ? !bef : bef) { ss[i] = s2; ss[ixj] = s1; si[i] = a2; si[ixj] = a1; }
                }
            }
        }
    }
    __syncthreads();
}

// ---------------- K0: zero hist + counters ----------------
__global__ void k_zero(unsigned* p, int n) {
    int i = blockIdx.x * THREADS + threadIdx.x;
    if (i < n) p[i] = 0;
}

// ---------------- K0b: precompute sigmoid(ctr) ----------------
__global__ __launch_bounds__(THREADS) void k_prep(
        const float* t0, const float* t1, const float* t2, const float* t3, const float* t4,
        float* __restrict__ sct) {
    int i = blockIdx.x * THREADS + threadIdx.x;
    if (i >= SCTN) return;
    float x;
    if (i < SCTB1)      x = t0[i - SCTB0];
    else if (i < SCTB2) x = t1[i - SCTB1];
    else if (i < SCTB3) x = t2[i - SCTB2];
    else if (i < SCTB4) x = t3[i - SCTB3];
    else                x = t4[i - SCTB4];
    sct[i] = sigm(x);   // exact: same formula as reference sigmoid usage
}

// ---------------- K1: approx histogram + per-256-group max approx key ----------------
template<int HW, int SCTB, int GPL, int GMXB>
__device__ __forceinline__ void histChunkV(int chunkLocal, int b,
        const float* __restrict__ cls, const float* __restrict__ sct,
        unsigned short* __restrict__ gmx, unsigned* __restrict__ h) {
    constexpr int NE = HW * NC;
    const float* cp = cls + (size_t)b * NE;
    const float* tb = sct + SCTB + b * HW;
    unsigned short* gp = gmx + GMXB + (size_t)b * GPL;
    int w = threadIdx.x >> 6, lane = threadIdx.x & 63;
    for (int gi = w; gi < 64; gi += 4) {
        int g = chunkLocal * 64 + gi;
        int ebase = g * 256;
        if (ebase >= NE) break;
        int e = ebase + lane * 4;
        int kmax = 0;
        if (e < NE) {
            int c = e / HW; int hwb = e - c * HW;        // 4 elems stay in one row (HW%4==0)
            float4 x4 = *(const float4*)(cp + e);
            float4 t4 = *(const float4*)(tb + hwb);
            #pragma unroll
            for (int q = 0; q < 4; ++q) {
                float x = (q == 0) ? x4.x : (q == 1) ? x4.y : (q == 2) ? x4.z : x4.w;
                float t = (q == 0) ? t4.x : (q == 1) ? t4.y : (q == 2) ? t4.z : t4.w;
                float scls = sigf(x);                    // FAST sigmoid (approx key)
                float s = __fmul_rn(scls, t);
                unsigned key = scoreKey(s);
                if (key) atomicAdd(&h[key], 1u);
                kmax = max(kmax, (int)key);
            }
        }
        #pragma unroll
        for (int sh = 1; sh < 64; sh <<= 1) kmax = max(kmax, __shfl_xor(kmax, sh, 64));
        if (lane == 0) gp[g] = (unsigned short)kmax;
    }
}

__global__ __launch_bounds__(THREADS) void k_hist(
        const float* c0, const float* c1, const float* c2, const float* c3, const float* c4,
        const float* __restrict__ sct, unsigned short* __restrict__ gmx, unsigned* ghist) {
    __shared__ unsigned h[NBINS];
    for (int k = threadIdx.x; k < NBINS; k += THREADS) h[k] = 0;
    __syncthreads();
    int cx = blockIdx.x, b = blockIdx.y;
    int li;
    if (cx < CH0)                 { histChunkV<HW0,SCTB0,GPL0,GMXB0>(cx, b, c0, sct, gmx, h); li = 0; }
    else if (cx < CH0+CH1)        { histChunkV<HW1,SCTB1,GPL1,GMXB1>(cx-CH0, b, c1, sct, gmx, h); li = 1; }
    else if (cx < CH0+CH1+CH2)    { histChunkV<HW2,SCTB2,GPL2,GMXB2>(cx-CH0-CH1, b, c2, sct, gmx, h); li = 2; }
    else if (cx < CH0+CH1+CH2+CH3){ histChunkV<HW3,SCTB3,GPL3,GMXB3>(cx-CH0-CH1-CH2, b, c3, sct, gmx, h); li = 3; }
    else                          { histChunkV<HW4,SCTB4,GPL4,GMXB4>(cx-CH0-CH1-CH2-CH3, b, c4, sct, gmx, h); li = 4; }
    __syncthreads();
    unsigned* gp = ghist + (size_t)(li * NB + b) * NBINS;
    for (int k = threadIdx.x; k < NBINS; k += THREADS) {
        unsigned v = h[k];
        if (v) atomicAdd(&gp[k], v);
    }
}

// ---------------- K2: per-(b,level) collect-threshold from approx hist ----------------
// TA = highest bin with cum-from-top >= TOPN (approx keys). Collect key >= TA-1:
// since |kapp-kex|<=1, all exact-top-300 elements are guaranteed collected.
__global__ __launch_bounds__(THREADS) void k_thresh(const unsigned* __restrict__ ghist, unsigned* __restrict__ T) {
    int pid = blockIdx.x;
    const unsigned* h = ghist + (size_t)pid * NBINS;
    __shared__ unsigned seg[THREADS];
    constexpr int SB = NBINS / THREADS;   // 8
    unsigned s = 0;
    for (int k = 0; k < SB; ++k) s += h[threadIdx.x * SB + k];
    seg[threadIdx.x] = s;
    __syncthreads();
    if (threadIdx.x == 0) {
        unsigned acc = 0; unsigned TA = 0;
        int t = THREADS - 1;
        for (; t >= 0; --t) {
            if (acc + seg[t] >= (unsigned)TOPN) break;
            acc += seg[t];
        }
        if (t >= 0) {
            int lo = t * SB;
            int bin = lo + SB - 1;
            for (; bin >= lo; --bin) { acc += h[bin]; if (acc >= (unsigned)TOPN) break; }
            TA = (unsigned)max(bin, lo);
        }
        T[pid] = (TA >= 1) ? (TA - 1) : 0;   // 0 => degenerate fallback (collect scls>0.05)
    }
}

// ---------------- K3: skip-list compaction, batched loads (MLP=8) ----------------
constexpr int LBUF = 1024;
constexpr int GB = 8;

template<int HW, int SCTB, int GPL, int GMXB>
__device__ __forceinline__ void collectChunkV(int chunkLocal, int b, int li,
        const float* __restrict__ cls, const float* __restrict__ sct,
        const unsigned short* __restrict__ gmx,
        const unsigned* __restrict__ T, Cand* __restrict__ candAll, unsigned* __restrict__ cnt,
        Cand* __restrict__ lbuf, unsigned* __restrict__ lcnt,
        short* __restrict__ glist, int* __restrict__ gcnt) {
    constexpr int NE = HW * NC;
    int pid = li * NB + b;
    unsigned Tv = T[pid];
    Cand* cd = candAll + (size_t)pid * CAP;
    const float* cp = cls + (size_t)b * NE;
    const float* tb = sct + SCTB + b * HW;
    const unsigned short* gp = gmx + GMXB + (size_t)b * GPL;
    // build compact passing-group list
    if (threadIdx.x < 64) {
        int g = chunkLocal * 64 + threadIdx.x;
        bool ok = ((size_t)g * 256 < (size_t)NE);
        if (ok && Tv) ok = ((unsigned)gp[g] + 1u >= Tv);   // gmx is max APPROX key: +1 slack
        unsigned long long m = __ballot(ok);
        int pos = __popcll(m & ((1ull << threadIdx.x) - 1ull));
        if (ok) glist[pos] = (short)g;
        if (threadIdx.x == 0) *gcnt = __popcll(m);
    }
    __syncthreads();
    int n = *gcnt;
    for (int base = 0; base < n; base += GB) {
        float xv[GB], tv[GB];
        int ev[GB];
        bool okv[GB];
        #pragma unroll
        for (int q = 0; q < GB; ++q) {
            int gi = base + q;
            int g = glist[(gi < n) ? gi : 0];
            int e = g * 256 + (int)threadIdx.x;
            bool ok = (gi < n) && (e < NE);
            e = ok ? e : 0;
            int c = e / HW; int hw = e - c * HW;
            xv[q] = cp[e];
            tv[q] = tb[hw];
            ev[q] = e;
            okv[q] = ok;
        }
        __builtin_amdgcn_sched_barrier(0);   // keep the 2*GB loads batched above the uses
        #pragma unroll
        for (int q = 0; q < GB; ++q) {
            float scls = sigm(xv[q]);        // EXACT sigmoid for stored score
            float s = __fmul_rn(scls, tv[q]);
            unsigned key = scoreKey(s);
            bool take = okv[q] && (Tv ? (key >= Tv) : (scls > 0.05f));
            if (take) {
                int e = ev[q];
                int c = e / HW; int hw = e - c * HW;
                unsigned slot = atomicAdd(lcnt, 1u);
                if (slot < (unsigned)LBUF) { lbuf[slot].s = s; lbuf[slot].i = hw * NC + c; }
                else {
                    unsigned gs = atomicAdd(&cnt[pid], 1u);   // rare fallback
                    if (gs < (unsigned)CAP) { cd[gs].s = s; cd[gs].i = hw * NC + c; }
                }
            }
        }
    }
}

__global__ __launch_bounds__(THREADS) void k_collect(
        const float* c0, const float* c1, const float* c2, const float* c3, const float* c4,
        const float* __restrict__ sct, const unsigned short* __restrict__ gmx,
        const unsigned* T, Cand* cand, unsigned* cnt) {
    __shared__ Cand lbuf[LBUF];
    __shared__ unsigned lcnt, gbase;
    __shared__ short glist[64];
    __shared__ int gcnt;
    if (threadIdx.x == 0) lcnt = 0;
    __syncthreads();
    int cx = blockIdx.x, b = blockIdx.y;
    int li;
    if (cx < CH0)                 { collectChunkV<HW0,SCTB0,GPL0,GMXB0>(cx, b, 0, c0, sct, gmx, T, cand, cnt, lbuf, &lcnt, glist, &gcnt); li = 0; }
    else if (cx < CH0+CH1)        { collectChunkV<HW1,SCTB1,GPL1,GMXB1>(cx-CH0, b, 1, c1, sct, gmx, T, cand, cnt, lbuf, &lcnt, glist, &gcnt); li = 1; }
    else if (cx < CH0+CH1+CH2)    { collectChunkV<HW2,SCTB2,GPL2,GMXB2>(cx-CH0-CH1, b, 2, c2, sct, gmx, T, cand, cnt, lbuf, &lcnt, glist, &gcnt); li = 2; }
    else if (cx < CH0+CH1+CH2+CH3){ collectChunkV<HW3,SCTB3,GPL3,GMXB3>(cx-CH0-CH1-CH2, b, 3, c3, sct, gmx, T, cand, cnt, lbuf, &lcnt, glist, &gcnt); li = 3; }
    else                          { collectChunkV<HW4,SCTB4,GPL4,GMXB4>(cx-CH0-CH1-CH2-CH3, b, 4, c4, sct, gmx, T, cand, cnt, lbuf, &lcnt, glist, &gcnt); li = 4; }
    __syncthreads();
    int pid = li * NB + b;
    unsigned n = lcnt; if (n > (unsigned)LBUF) n = LBUF;
    if (threadIdx.x == 0) gbase = n ? atomicAdd(&cnt[pid], n) : 0u;
    __syncthreads();
    Cand* cd = cand + (size_t)pid * CAP;
    for (unsigned i = threadIdx.x; i < n; i += THREADS) {
        unsigned s = gbase + i;
        if (s < (unsigned)CAP) cd[s] = lbuf[i];
    }
}

// ---------------- K4: exact top-300 per (b,level) + decode ----------------
__global__ __launch_bounds__(THREADS) void k_select(
        const Cand* __restrict__ candAll, const unsigned* __restrict__ cntAll,
        const float* l0, const float* l1, const float* l2, const float* l3, const float* l4,
        const float* b0, const float* b1, const float* b2, const float* b3, const float* b4,
        float* __restrict__ cbox, float* __restrict__ csc, int* __restrict__ clb) {
    __shared__ float ss[CAP];
    __shared__ int si[CAP];
    int pid = blockIdx.x;
    int li = pid / NB, b = pid - li * NB;
    int n = (int)min(cntAll[pid], (unsigned)CAP);
    const Cand* cd = candAll + (size_t)pid * CAP;
    int N = 2; while (N < n) N <<= 1;
    for (int k = threadIdx.x; k < N; k += THREADS) {
        if (k < n) { ss[k] = cd[k].s; si[k] = cd[k].i; }
        else       { ss[k] = -INFINITY; si[k] = 0x40000000 + k; }
    }
    __syncthreads();
    bitonicShared(ss, si, N);

    const float* locp; const float* boxp; int HW;
    switch (li) {
        case 0: locp = l0; boxp = b0; HW = HW0; break;
        case 1: locp = l1; boxp = b1; HW = HW1; break;
        case 2: locp = l2; boxp = b2; HW = HW2; break;
        case 3: locp = l3; boxp = b3; HW = HW3; break;
        default: locp = l4; boxp = b4; HW = HW4; break;
    }
    for (int j = threadIdx.x; j < TOPN; j += THREADS) {
        int cidx = b * KC + li * TOPN + j;
        bool ok = (j < n);
        float s = ok ? ss[j] : -INFINITY;
        ok = ok && (s > 0.0f);
        if (ok) {
            int idx = si[j];
            int hw = idx / NC, c = idx - hw * NC;
            float lx = locp[hw * 2 + 0], ly = locp[hw * 2 + 1];
            const float* bp = boxp + (size_t)b * 4 * HW + hw;
            float bl = bp[0], bt = bp[HW], br = bp[2 * HW], bb = bp[3 * HW];
            float x1 = fminf(fmaxf(__fsub_rn(lx, bl), 0.0f), 1023.0f);
            float y1 = fminf(fmaxf(__fsub_rn(ly, bt), 0.0f),  799.0f);
            float x2 = fminf(fmaxf(__fadd_rn(lx, br), 0.0f), 1023.0f);
            float y2 = fminf(fmaxf(__fadd_rn(ly, bb), 0.0f),  799.0f);
            cbox[cidx * 4 + 0] = x1; cbox[cidx * 4 + 1] = y1;
            cbox[cidx * 4 + 2] = x2; cbox[cidx * 4 + 3] = y2;
            csc[cidx] = sqrtf(fmaxf(s, 1e-12f));
            clb[cidx] = c + 1;
        } else {
            cbox[cidx * 4 + 0] = 0.0f; cbox[cidx * 4 + 1] = 0.0f;
            cbox[cidx * 4 + 2] = 0.0f; cbox[cidx * 4 + 3] = 0.0f;
            csc[cidx] = -INFINITY;
            clb[cidx] = 0;
        }
    }
}

// ---------------- K5a: per-image sort by score desc (1024 threads) ----------------
__global__ __launch_bounds__(SORTT) void k_sortimg(
        const float* __restrict__ csc, const int* __restrict__ clb, const float* __restrict__ cbox,
        float* __restrict__ ssc, int* __restrict__ slb, float* __restrict__ sbox, float* __restrict__ obox) {
    int b = blockIdx.x;
    __shared__ float ss[2048];
    __shared__ int si[2048];
    for (int k = threadIdx.x; k < 2048; k += SORTT) {
        if (k < KC) { ss[k] = csc[b * KC + k]; si[k] = k; }
        else        { ss[k] = -INFINITY; si[k] = 0x40000000 + k; }
    }
    __syncthreads();
    bitonicShared(ss, si, 2048);
    for (int k = threadIdx.x; k < KC; k += SORTT) {
        int sl = si[k];                 // all 1500 real entries sort before pads
        int src = b * KC + sl;
        int dst = b * KC + k;
        float sc = ss[k];
        int lab = clb[src];
        ssc[dst] = sc; slb[dst] = lab;
        float off = __fmul_rn((float)lab, 1025.0f);   // offset = max(800,1024)+1
        #pragma unroll
        for (int q = 0; q < 4; ++q) {
            float v = cbox[src * 4 + q];
            sbox[dst * 4 + q] = v;
            obox[dst * 4 + q] = __fadd_rn(v, off);
        }
    }
}

// ---------------- K5b: suppression bitmask (iou > 0.6 && j > i) ----------------
// Writes COLUMN-MAJOR: MT[b][w][row]  (coalesced store; coalesced column loads in k_nms)
__global__ __launch_bounds__(64) void k_iou(const float* __restrict__ obox,
                                            unsigned long long* __restrict__ MT) {
    int w = blockIdx.x, tile = blockIdx.y, b = blockIdx.z;
    if (w < tile) return;
    int lane = threadIdx.x;
    __shared__ float4 sj[64];
    __shared__ float aj[64];
    const float4* op = (const float4*)obox + (size_t)b * KC;
    int j0 = w * 64;
    int jl = j0 + lane;
    float4 vj = op[(jl < KC) ? jl : (KC - 1)];
    sj[lane] = vj;
    aj[lane] = __fmul_rn(__fsub_rn(vj.z, vj.x), __fsub_rn(vj.w, vj.y));
    int i = tile * 64 + lane;
    float4 bi = op[(i < KC) ? i : (KC - 1)];
    float ai = __fmul_rn(__fsub_rn(bi.z, bi.x), __fsub_rn(bi.w, bi.y));
    __syncthreads();
    unsigned long long bits = 0;
    int jmax = min(64, KC - j0);
    for (int jj = 0; jj < jmax; ++jj) {
        float4 bj = sj[jj];            // wave-uniform -> LDS broadcast
        float xx1 = fmaxf(bi.x, bj.x), yy1 = fmaxf(bi.y, bj.y);
        float xx2 = fminf(bi.z, bj.z), yy2 = fminf(bi.w, bj.w);
        float ww = fmaxf(__fsub_rn(xx2, xx1), 0.0f);
        float hh = fmaxf(__fsub_rn(yy2, yy1), 0.0f);
        float inter = __fmul_rn(ww, hh);
        float uni = __fsub_rn(__fadd_rn(ai, aj[jj]), inter);
        float iou = __fdiv_rn(inter, fmaxf(uni, 1e-9f));
        bool kp = ((j0 + jj) > i) && (iou > 0.6f);
        bits |= kp ? (1ull << jj) : 0ull;
    }
    if (i >= KC) bits = 0;
    MT[((size_t)b * WORDS + w) * KROWS + i] = bits;
}

// ---------------- K5c: pipelined pull-style greedy scan (1 wave/image) ----------------
__global__ __launch_bounds__(64) void k_nms(
        const unsigned long long* __restrict__ MT, const float* __restrict__ ssc,
        const int* __restrict__ slb, const float* __restrict__ sbox, float* __restrict__ out) {
    int b = blockIdx.x, lane = threadIdx.x;
    for (int k = lane; k < POSTN * 5; k += 64) out[(size_t)b * POSTN * 5 + k] = 0.0f;
    for (int k = lane; k < POSTN; k += 64) {
        out[(size_t)NB * POSTN * 5 + b * POSTN + k] = 0.0f;                 // labels
        out[(size_t)NB * POSTN * 5 + NB * POSTN + b * POSTN + k] = 0.0f;    // valid
    }
    const float* sp = ssc + b * KC;
    unsigned long long validV = 0;
    for (int c = 0; c < WORDS; ++c) {
        int i = c * 64 + lane;
        bool f = (i < KC) && (sp[i] > 0.0f);
        unsigned long long m = __ballot(f);
        validV = (lane == c) ? m : validV;
    }
    unsigned long long mybit = 1ull << lane;
    unsigned long long keptV = 0;
    const unsigned long long* Mb = MT + (size_t)b * WORDS * KROWS;

    unsigned long long pv[WORDS];
    pv[0] = Mb[lane];

    for (int t = 0; t < WORDS; ++t) {
        int tn = (t + 1 < WORDS) ? (t + 1) : t;
        const unsigned long long* cp = Mb + (size_t)tn * KROWS + lane;
        unsigned long long nv[WORDS];
        #pragma unroll
        for (int c = 0; c < WORDS; ++c) {
            int cc = (c <= tn) ? c : 0;
            nv[c] = cp[(size_t)cc * 64];
        }
        __builtin_amdgcn_sched_barrier(0);    // loads stay above; compute below

        unsigned long long D = pv[t];
        unsigned long long acc = 0;
        #pragma unroll
        for (int c = 0; c < WORDS; ++c) {
            if (c < t) {
                unsigned long long kc = readlane64(keptV, c);
                if (kc & mybit) acc |= pv[c];
            }
        }
        #pragma unroll
        for (int s = 1; s < 64; s <<= 1) acc |= __shfl_xor(acc, s, 64);

        unsigned long long validT = readlane64(validV, t);
        unsigned long long rem = acc;
        unsigned long long sup = __ballot(D != 0ull) & validT;
        unsigned long long todoS = sup;
        while (todoS) {
            int r = __builtin_ctzll(todoS);
            todoS &= todoS - 1;
            if (!((rem >> r) & 1ull)) {
                unsigned long long Dr = readlane64(D, r);
                rem |= Dr;
                todoS &= ~Dr;
            }
        }
        unsigned long long kept = validT & ~rem;
        keptV = (lane == t) ? kept : keptV;

        #pragma unroll
        for (int c = 0; c < WORDS; ++c) pv[c] = nv[c];
    }

    int base = 0;
    for (int c = 0; c < WORDS && base < POSTN; ++c) {
        unsigned long long kw = readlane64(keptV, c);
        bool f = (kw & mybit) != 0ull;
        int rank = base + __popcll(kw & (mybit - 1ull));
        if (f && rank < POSTN) {
            int i = c * 64 + lane;
            int src = b * KC + i;
            float* o5 = out + ((size_t)b * POSTN + rank) * 5;
            o5[0] = sbox[src * 4 + 0]; o5[1] = sbox[src * 4 + 1];
            o5[2] = sbox[src * 4 + 2]; o5[3] = sbox[src * 4 + 3];
            o5[4] = ssc[src];
            out[(size_t)NB * POSTN * 5 + b * POSTN + rank] = (float)slb[src];
            out[(size_t)NB * POSTN * 5 + NB * POSTN + b * POSTN + rank] = 1.0f;
        }
        base += __popcll(kw);
    }
}

// ---------------- launch ----------------
extern "C" void kernel_launch(void* const* d_in, const int* in_sizes, int n_in,
                              void* d_out, int out_size, void* d_ws, size_t ws_size,
                              hipStream_t stream) {
    const float *loc[5], *cls[5], *box[5], *ctr[5];
    for (int l = 0; l < 5; ++l) {
        loc[l] = (const float*)d_in[l * 4 + 0];
        cls[l] = (const float*)d_in[l * 4 + 1];
        box[l] = (const float*)d_in[l * 4 + 2];
        ctr[l] = (const float*)d_in[l * 4 + 3];
    }
    char* ws = (char*)d_ws;
    unsigned* hist = (unsigned*)(ws + OFF_HIST);
    unsigned* T    = (unsigned*)(ws + OFF_T);
    unsigned* cnt  = (unsigned*)(ws + OFF_CNT);
    Cand* cand     = (Cand*)(ws + OFF_CAND);
    float* cbox    = (float*)(ws + OFF_CBOX);
    float* csc     = (float*)(ws + OFF_CSC);
    int*   clb     = (int*)(ws + OFF_CLB);
    float* ssc     = (float*)(ws + OFF_SSC);
    int*   slb     = (int*)(ws + OFF_SLB);
    float* sbox    = (float*)(ws + OFF_SBOX);
    float* obox    = (float*)(ws + OFF_OBOX);
    unsigned long long* MT = (unsigned long long*)(ws + OFF_M);
    float* sct     = (float*)(ws + OFF_SCT);
    unsigned short* gmx = (unsigned short*)(ws + OFF_GMX);
    float* out = (float*)d_out;

    int zn = (int)(OFF_CAND / 4);
    k_zero<<<(zn + THREADS - 1) / THREADS, THREADS, 0, stream>>>((unsigned*)ws, zn);
    k_prep<<<(SCTN + THREADS - 1) / THREADS, THREADS, 0, stream>>>(
        ctr[0], ctr[1], ctr[2], ctr[3], ctr[4], sct);
    k_hist<<<dim3(CHUNKS, NB), THREADS, 0, stream>>>(
        cls[0], cls[1], cls[2], cls[3], cls[4], sct, gmx, hist);
    k_thresh<<<NPAIR, THREADS, 0, stream>>>(hist, T);
    k_collect<<<dim3(CHUNKS, NB), THREADS, 0, stream>>>(
        cls[0], cls[1], cls[2], cls[3], cls[4], sct, gmx, T, cand, cnt);
    k_select<<<NPAIR, THREADS, 0, stream>>>(
        cand, cnt,
        loc[0], loc[1], loc[2], loc[3], loc[4],
        box[0], box[1], box[2], box[3], box[4],
        cbox, csc, clb);
    k_sortimg<<<NB, SORTT, 0, stream>>>(csc, clb, cbox, ssc, slb, sbox, obox);
    k_iou<<<dim3(WORDS, WORDS, NB), 64, 0, stream>>>(obox, MT);
    k_nms<<<NB, 64, 0, stream>>>(MT, ssc, slb, sbox, out);
}

// Round 8
// 314.477 us; speedup vs baseline: 2.1662x; 1.0090x over previous
//
#include <hip/hip_runtime.h>
#include <math.h>

#define THREADS 256
#define SORTT 1024

// ---------------- problem constants (fixed by reference setup) ----------------
constexpr int NLEV  = 5;
constexpr int NB    = 16;     // batch
constexpr int NC    = 80;     // classes (label = c+1)
constexpr int TOPN  = 300;
constexpr int KC    = NLEV * TOPN;   // 1500 candidates per image
constexpr int KROWS = 1536;          // padded rows for NMS bitmask
constexpr int WORDS = 24;            // 1536 / 64
constexpr int POSTN = 100;
constexpr int CAP   = 4096;          // per-(b,level) candidate pool
constexpr int NBINS = 2048;          // score-histogram bins over [0.25, 1.0)
constexpr int NPAIR = NLEV * NB;     // 80

constexpr int HW0 = 12800, HW1 = 3200, HW2 = 800, HW3 = 208, HW4 = 56;
constexpr int CH0 = 63, CH1 = 16, CH2 = 4, CH3 = 2, CH4 = 1;  // 16384-elem chunks per (b,level)
constexpr int CHUNKS = CH0 + CH1 + CH2 + CH3 + CH4;           // 86
constexpr int CHUNK_ELEMS = 16384;

// sigmoid(ctr) precompute: per-level bases into sct[] (floats), layout [li][b][hw]
constexpr int SCTB0 = 0;
constexpr int SCTB1 = 204800;
constexpr int SCTB2 = 256000;
constexpr int SCTB3 = 268800;
constexpr int SCTB4 = 272128;
constexpr int SCTN  = 273024;

// group-max skip list: 256-element groups, layout [li][b][g] (u16)
constexpr int GPL0 = 4000, GPL1 = 1000, GPL2 = 250, GPL3 = 65, GPL4 = 18;
constexpr int GMXB0 = 0;
constexpr int GMXB1 = GMXB0 + NB * GPL0;
constexpr int GMXB2 = GMXB1 + NB * GPL1;
constexpr int GMXB3 = GMXB2 + NB * GPL2;
constexpr int GMXB4 = GMXB3 + NB * GPL3;
constexpr int GMXN  = GMXB4 + NB * GPL4;

// ---------------- workspace layout ----------------
constexpr size_t align256(size_t x) { return (x + 255) & ~(size_t)255; }
constexpr size_t OFF_HIST = 0;
constexpr size_t OFF_CNT  = OFF_HIST + (size_t)NPAIR * NBINS * 4;
constexpr size_t OFF_CAND = align256(OFF_CNT + (size_t)NPAIR * 4);
constexpr size_t OFF_CBOX = align256(OFF_CAND + (size_t)NPAIR * CAP * 8);
constexpr size_t OFF_CSC  = align256(OFF_CBOX + (size_t)NB * KC * 4 * 4);
constexpr size_t OFF_CLB  = align256(OFF_CSC  + (size_t)NB * KC * 4);
constexpr size_t OFF_SSC  = align256(OFF_CLB  + (size_t)NB * KC * 4);
constexpr size_t OFF_SLB  = align256(OFF_SSC  + (size_t)NB * KC * 4);
constexpr size_t OFF_SBOX = align256(OFF_SLB  + (size_t)NB * KC * 4);
constexpr size_t OFF_OBOX = align256(OFF_SBOX + (size_t)NB * KC * 4 * 4);
constexpr size_t OFF_M    = align256(OFF_OBOX + (size_t)NB * KC * 4 * 4);
constexpr size_t OFF_SCT  = align256(OFF_M + (size_t)NB * KROWS * WORDS * 8);
constexpr size_t OFF_GMX  = align256(OFF_SCT + (size_t)SCTN * 4);
// total ~15.8 MB

struct Cand { float s; int i; };

// ---------------- helpers ----------------
__device__ __forceinline__ float sigm(float x) { return 1.0f / (1.0f + expf(-x)); }

// fast sigmoid (hw v_exp_f32 + v_rcp_f32, <=~4 ulp). Used ONLY for the histogram /
// skip-list (threshold selection): |approx key - exact key| <= 1 bin, compensated
// by collecting key >= TA-1 and gating groups by gmx+1 >= Tv. Collect/select use
// the exact sigm() so the final output is bit-identical.
__device__ __forceinline__ float sigf(float x) {
#if __has_builtin(__builtin_amdgcn_exp2f) && __has_builtin(__builtin_amdgcn_rcpf)
    float e = __builtin_amdgcn_exp2f(__fmul_rn(x, -1.44269504088896340736f));
    return __builtin_amdgcn_rcpf(__fadd_rn(1.0f, e));
#else
    return 1.0f / (1.0f + __expf(-x));
#endif
}

// monotone key over score in (0,1): 2048 bins over [0.25,1.0), everything below -> bin 0
__device__ __forceinline__ unsigned scoreKey(float s) {
    unsigned b = __float_as_uint(s);
    unsigned k = (b < 0x3E800000u) ? 0u : ((b - 0x3E800000u) >> 13);
    return (k > 2047u) ? 2047u : k;
}

__device__ __forceinline__ unsigned long long readlane64(unsigned long long v, int l) {
    unsigned lo = (unsigned)__builtin_amdgcn_readlane((int)(unsigned)(v & 0xffffffffull), l);
    unsigned hi = (unsigned)__builtin_amdgcn_readlane((int)(unsigned)(v >> 32), l);
    return ((unsigned long long)hi << 32) | lo;
}

__device__ void bitonicShared(float* ss, int* si, int N) {
    for (int k = 2; k <= N; k <<= 1) {
        for (int j = k >> 1; j > 0; j >>= 1) {
            __syncthreads();
            for (int i = threadIdx.x; i < N; i += blockDim.x) {
                int ixj = i ^ j;
                if (ixj > i) {
                    float s1 = ss[i], s2 = ss[ixj];
                    int a1 = si[i], a2 = si[ixj];
                    bool bef = (s1 > s2) || (s1 == s2 && a1 < a2);   // desc, idx asc
                    bool up = ((i & k) == 0);
                    if (up ? !bef : bef) { ss[i] = s2; ss[ixj] = s1; si[i] = a2; si[ixj] = a1; }
                }
            }
        }
    }
    __syncthreads();
}

// ---------------- K0: fused zero (hist+cnt) + sigmoid(ctr) precompute ----------------
__global__ __launch_bounds__(THREADS) void k_init(
        const float* t0, const float* t1, const float* t2, const float* t3, const float* t4,
        float* __restrict__ sct, unsigned* __restrict__ zp, int zn) {
    int i = blockIdx.x * THREADS + threadIdx.x;
    if (i < zn) zp[i] = 0;
    if (i < SCTN) {
        float x;
        if (i < SCTB1)      x = t0[i - SCTB0];
        else if (i < SCTB2) x = t1[i - SCTB1];
        else if (i < SCTB3) x = t2[i - SCTB2];
        else if (i < SCTB4) x = t3[i - SCTB3];
        else                x = t4[i - SCTB4];
        sct[i] = sigm(x);   // exact: same formula as reference sigmoid usage
    }
}

// ---------------- K1: approx histogram + per-256-group max approx key ----------------
// 512-elem blocks: each lane loads 2x float4 (32B contiguous) -> 2x MLP vs round 7.
// All NE and HW are divisible by 8, so the two float4s never straddle a class row.
template<int HW, int SCTB, int GPL, int GMXB>
__device__ __forceinline__ void histChunkV(int chunkLocal, int b,
        const float* __restrict__ cls, const float* __restrict__ sct,
        unsigned short* __restrict__ gmx, unsigned* __restrict__ h) {
    constexpr int NE = HW * NC;
    const float* cp = cls + (size_t)b * NE;
    const float* tb = sct + SCTB + b * HW;
    unsigned short* gp = gmx + GMXB + (size_t)b * GPL;
    int w = threadIdx.x >> 6, lane = threadIdx.x & 63;
    int half = lane >> 5, hlane = lane & 31;
    for (int bi = w; bi < 32; bi += 4) {
        int ebase = (chunkLocal * 32 + bi) * 512;
        if (ebase >= NE) break;
        int e = ebase + lane * 8;
        int kmax = 0;
        if (e < NE) {   // NE%8==0 -> e<NE implies e+7<NE
            int c = e / HW; int hwb = e - c * HW;
            float4 xa = *(const float4*)(cp + e);
            float4 xb = *(const float4*)(cp + e + 4);
            float4 ta = *(const float4*)(tb + hwb);
            float4 tc = *(const float4*)(tb + hwb + 4);
            float xs[8] = {xa.x, xa.y, xa.z, xa.w, xb.x, xb.y, xb.z, xb.w};
            float ts[8] = {ta.x, ta.y, ta.z, ta.w, tc.x, tc.y, tc.z, tc.w};
            #pragma unroll
            for (int q = 0; q < 8; ++q) {
                float scls = sigf(xs[q]);                // FAST sigmoid (approx key)
                float s = __fmul_rn(scls, ts[q]);
                unsigned key = scoreKey(s);
                if (key) atomicAdd(&h[key], 1u);
                kmax = max(kmax, (int)key);
            }
        }
        // half-wave (32-lane) max reduce: each half covers one 256-elem group
        #pragma unroll
        for (int sh = 1; sh < 32; sh <<= 1) kmax = max(kmax, __shfl_xor(kmax, sh, 64));
        int g = (ebase >> 8) + half;
        if (hlane == 0 && g * 256 < NE) gp[g] = (unsigned short)kmax;
    }
}

__global__ __launch_bounds__(THREADS) void k_hist(
        const float* c0, const float* c1, const float* c2, const float* c3, const float* c4,
        const float* __restrict__ sct, unsigned short* __restrict__ gmx, unsigned* ghist) {
    __shared__ unsigned h[NBINS];
    for (int k = threadIdx.x; k < NBINS; k += THREADS) h[k] = 0;
    __syncthreads();
    int cx = blockIdx.x, b = blockIdx.y;
    int li;
    if (cx < CH0)                 { histChunkV<HW0,SCTB0,GPL0,GMXB0>(cx, b, c0, sct, gmx, h); li = 0; }
    else if (cx < CH0+CH1)        { histChunkV<HW1,SCTB1,GPL1,GMXB1>(cx-CH0, b, c1, sct, gmx, h); li = 1; }
    else if (cx < CH0+CH1+CH2)    { histChunkV<HW2,SCTB2,GPL2,GMXB2>(cx-CH0-CH1, b, c2, sct, gmx, h); li = 2; }
    else if (cx < CH0+CH1+CH2+CH3){ histChunkV<HW3,SCTB3,GPL3,GMXB3>(cx-CH0-CH1-CH2, b, c3, sct, gmx, h); li = 3; }
    else                          { histChunkV<HW4,SCTB4,GPL4,GMXB4>(cx-CH0-CH1-CH2-CH3, b, c4, sct, gmx, h); li = 4; }
    __syncthreads();
    unsigned* gp = ghist + (size_t)(li * NB + b) * NBINS;
    for (int k = threadIdx.x; k < NBINS; k += THREADS) {
        unsigned v = h[k];
        if (v) atomicAdd(&gp[k], v);
    }
}

// ---------------- K3: skip-list compaction, batched loads; inline threshold ----------------
constexpr int LBUF = 1024;
constexpr int GB = 8;

template<int HW, int SCTB, int GPL, int GMXB>
__device__ __forceinline__ void collectChunkV(int chunkLocal, int b, int li, unsigned Tv,
        const float* __restrict__ cls, const float* __restrict__ sct,
        const unsigned short* __restrict__ gmx,
        Cand* __restrict__ candAll, unsigned* __restrict__ cnt,
        Cand* __restrict__ lbuf, unsigned* __restrict__ lcnt,
        short* __restrict__ glist, int* __restrict__ gcnt) {
    constexpr int NE = HW * NC;
    int pid = li * NB + b;
    Cand* cd = candAll + (size_t)pid * CAP;
    const float* cp = cls + (size_t)b * NE;
    const float* tb = sct + SCTB + b * HW;
    const unsigned short* gp = gmx + GMXB + (size_t)b * GPL;
    // build compact passing-group list
    if (threadIdx.x < 64) {
        int g = chunkLocal * 64 + threadIdx.x;
        bool ok = ((size_t)g * 256 < (size_t)NE);
        if (ok && Tv) ok = ((unsigned)gp[g] + 1u >= Tv);   // gmx is max APPROX key: +1 slack
        unsigned long long m = __ballot(ok);
        int pos = __popcll(m & ((1ull << threadIdx.x) - 1ull));
        if (ok) glist[pos] = (short)g;
        if (threadIdx.x == 0) *gcnt = __popcll(m);
    }
    __syncthreads();
    int n = *gcnt;
    for (int base = 0; base < n; base += GB) {
        float xv[GB], tv[GB];
        int ev[GB];
        bool okv[GB];
        #pragma unroll
        for (int q = 0; q < GB; ++q) {
            int gi = base + q;
            int g = glist[(gi < n) ? gi : 0];
            int e = g * 256 + (int)threadIdx.x;
            bool ok = (gi < n) && (e < NE);
            e = ok ? e : 0;
            int c = e / HW; int hw = e - c * HW;
            xv[q] = cp[e];
            tv[q] = tb[hw];
            ev[q] = e;
            okv[q] = ok;
        }
        __builtin_amdgcn_sched_barrier(0);   // keep the 2*GB loads batched above the uses
        #pragma unroll
        for (int q = 0; q < GB; ++q) {
            float scls = sigm(xv[q]);        // EXACT sigmoid for stored score
            float s = __fmul_rn(scls, tv[q]);
            unsigned key = scoreKey(s);
            bool take = okv[q] && (Tv ? (key >= Tv) : (scls > 0.05f));
            if (take) {
                int e = ev[q];
                int c = e / HW; int hw = e - c * HW;
                unsigned slot = atomicAdd(lcnt, 1u);
                if (slot < (unsigned)LBUF) { lbuf[slot].s = s; lbuf[slot].i = hw * NC + c; }
                else {
                    unsigned gs = atomicAdd(&cnt[pid], 1u);   // rare fallback
                    if (gs < (unsigned)CAP) { cd[gs].s = s; cd[gs].i = hw * NC + c; }
                }
            }
        }
    }
}

__global__ __launch_bounds__(THREADS) void k_collect(
        const float* c0, const float* c1, const float* c2, const float* c3, const float* c4,
        const float* __restrict__ sct, const unsigned short* __restrict__ gmx,
        const unsigned* __restrict__ ghist, Cand* cand, unsigned* cnt) {
    __shared__ Cand lbuf[LBUF];
    __shared__ unsigned lcnt, gbase;
    __shared__ short glist[64];
    __shared__ int gcnt;
    __shared__ unsigned seg[THREADS];
    __shared__ unsigned shTv;
    if (threadIdx.x == 0) lcnt = 0;
    int cx = blockIdx.x, b = blockIdx.y;
    int li, cl;
    if (cx < CH0)                  { li = 0; cl = cx; }
    else if (cx < CH0+CH1)         { li = 1; cl = cx - CH0; }
    else if (cx < CH0+CH1+CH2)     { li = 2; cl = cx - CH0 - CH1; }
    else if (cx < CH0+CH1+CH2+CH3) { li = 3; cl = cx - CH0 - CH1 - CH2; }
    else                           { li = 4; cl = cx - CH0 - CH1 - CH2 - CH3; }
    int pid = li * NB + b;
    // inline threshold (same math as the old k_thresh, recomputed per block)
    {
        const unsigned* h = ghist + (size_t)pid * NBINS;
        constexpr int SB = NBINS / THREADS;   // 8
        unsigned s = 0;
        for (int k = 0; k < SB; ++k) s += h[threadIdx.x * SB + k];
        seg[threadIdx.x] = s;
        __syncthreads();
        if (threadIdx.x == 0) {
            unsigned acc = 0; unsigned TA = 0;
            int t = THREADS - 1;
            for (; t >= 0; --t) {
                if (acc + seg[t] >= (unsigned)TOPN) break;
                acc += seg[t];
            }
            if (t >= 0) {
                int lo = t * SB;
                int bin = lo + SB - 1;
                for (; bin >= lo; --bin) { acc += h[bin]; if (acc >= (unsigned)TOPN) break; }
                TA = (unsigned)max(bin, lo);
            }
            shTv = (TA >= 1) ? (TA - 1) : 0;   // 0 => degenerate fallback (collect scls>0.05)
        }
        __syncthreads();
    }
    unsigned Tv = shTv;
    switch (li) {
        case 0: collectChunkV<HW0,SCTB0,GPL0,GMXB0>(cl, b, 0, Tv, c0, sct, gmx, cand, cnt, lbuf, &lcnt, glist, &gcnt); break;
        case 1: collectChunkV<HW1,SCTB1,GPL1,GMXB1>(cl, b, 1, Tv, c1, sct, gmx, cand, cnt, lbuf, &lcnt, glist, &gcnt); break;
        case 2: collectChunkV<HW2,SCTB2,GPL2,GMXB2>(cl, b, 2, Tv, c2, sct, gmx, cand, cnt, lbuf, &lcnt, glist, &gcnt); break;
        case 3: collectChunkV<HW3,SCTB3,GPL3,GMXB3>(cl, b, 3, Tv, c3, sct, gmx, cand, cnt, lbuf, &lcnt, glist, &gcnt); break;
        default: collectChunkV<HW4,SCTB4,GPL4,GMXB4>(cl, b, 4, Tv, c4, sct, gmx, cand, cnt, lbuf, &lcnt, glist, &gcnt); break;
    }
    __syncthreads();
    unsigned n = lcnt; if (n > (unsigned)LBUF) n = LBUF;
    if (threadIdx.x == 0) gbase = n ? atomicAdd(&cnt[pid], n) : 0u;
    __syncthreads();
    Cand* cd = cand + (size_t)pid * CAP;
    for (unsigned i = threadIdx.x; i < n; i += THREADS) {
        unsigned s = gbase + i;
        if (s < (unsigned)CAP) cd[s] = lbuf[i];
    }
}

// ---------------- K4: exact top-300 per (b,level) + decode ----------------
__global__ __launch_bounds__(THREADS) void k_select(
        const Cand* __restrict__ candAll, const unsigned* __restrict__ cntAll,
        const float* l0, const float* l1, const float* l2, const float* l3, const float* l4,
        const float* b0, const float* b1, const float* b2, const float* b3, const float* b4,
        float* __restrict__ cbox, float* __restrict__ csc, int* __restrict__ clb) {
    __shared__ float ss[CAP];
    __shared__ int si[CAP];
    int pid = blockIdx.x;
    int li = pid / NB, b = pid - li * NB;
    int n = (int)min(cntAll[pid], (unsigned)CAP);
    const Cand* cd = candAll + (size_t)pid * CAP;
    int N = 2; while (N < n) N <<= 1;
    for (int k = threadIdx.x; k < N; k += THREADS) {
        if (k < n) { ss[k] = cd[k].s; si[k] = cd[k].i; }
        else       { ss[k] = -INFINITY; si[k] = 0x40000000 + k; }
    }
    __syncthreads();
    bitonicShared(ss, si, N);

    const float* locp; const float* boxp; int HW;
    switch (li) {
        case 0: locp = l0; boxp = b0; HW = HW0; break;
        case 1: locp = l1; boxp = b1; HW = HW1; break;
        case 2: locp = l2; boxp = b2; HW = HW2; break;
        case 3: locp = l3; boxp = b3; HW = HW3; break;
        default: locp = l4; boxp = b4; HW = HW4; break;
    }
    for (int j = threadIdx.x; j < TOPN; j += THREADS) {
        int cidx = b * KC + li * TOPN + j;
        bool ok = (j < n);
        float s = ok ? ss[j] : -INFINITY;
        ok = ok && (s > 0.0f);
        if (ok) {
            int idx = si[j];
            int hw = idx / NC, c = idx - hw * NC;
            float lx = locp[hw * 2 + 0], ly = locp[hw * 2 + 1];
            const float* bp = boxp + (size_t)b * 4 * HW + hw;
            float bl = bp[0], bt = bp[HW], br = bp[2 * HW], bb = bp[3 * HW];
            float x1 = fminf(fmaxf(__fsub_rn(lx, bl), 0.0f), 1023.0f);
            float y1 = fminf(fmaxf(__fsub_rn(ly, bt), 0.0f),  799.0f);
            float x2 = fminf(fmaxf(__fadd_rn(lx, br), 0.0f), 1023.0f);
            float y2 = fminf(fmaxf(__fadd_rn(ly, bb), 0.0f),  799.0f);
            cbox[cidx * 4 + 0] = x1; cbox[cidx * 4 + 1] = y1;
            cbox[cidx * 4 + 2] = x2; cbox[cidx * 4 + 3] = y2;
            csc[cidx] = sqrtf(fmaxf(s, 1e-12f));
            clb[cidx] = c + 1;
        } else {
            cbox[cidx * 4 + 0] = 0.0f; cbox[cidx * 4 + 1] = 0.0f;
            cbox[cidx * 4 + 2] = 0.0f; cbox[cidx * 4 + 3] = 0.0f;
            csc[cidx] = -INFINITY;
            clb[cidx] = 0;
        }
    }
}

// ---------------- K5a: per-image sort by score desc (1024 threads) ----------------
__global__ __launch_bounds__(SORTT) void k_sortimg(
        const float* __restrict__ csc, const int* __restrict__ clb, const float* __restrict__ cbox,
        float* __restrict__ ssc, int* __restrict__ slb, float* __restrict__ sbox, float* __restrict__ obox) {
    int b = blockIdx.x;
    __shared__ float ss[2048];
    __shared__ int si[2048];
    for (int k = threadIdx.x; k < 2048; k += SORTT) {
        if (k < KC) { ss[k] = csc[b * KC + k]; si[k] = k; }
        else        { ss[k] = -INFINITY; si[k] = 0x40000000 + k; }
    }
    __syncthreads();
    bitonicShared(ss, si, 2048);
    for (int k = threadIdx.x; k < KC; k += SORTT) {
        int sl = si[k];                 // all 1500 real entries sort before pads
        int src = b * KC + sl;
        int dst = b * KC + k;
        float sc = ss[k];
        int lab = clb[src];
        ssc[dst] = sc; slb[dst] = lab;
        float off = __fmul_rn((float)lab, 1025.0f);   // offset = max(800,1024)+1
        #pragma unroll
        for (int q = 0; q < 4; ++q) {
            float v = cbox[src * 4 + q];
            sbox[dst * 4 + q] = v;
            obox[dst * 4 + q] = __fadd_rn(v, off);
        }
    }
}

// ---------------- K5b: suppression bitmask (iou > 0.6 && j > i) ----------------
// Writes COLUMN-MAJOR: MT[b][w][row]  (coalesced store; coalesced column loads in k_nms)
__global__ __launch_bounds__(64) void k_iou(const float* __restrict__ obox,
                                            unsigned long long* __restrict__ MT) {
    int w = blockIdx.x, tile = blockIdx.y, b = blockIdx.z;
    if (w < tile) return;
    int lane = threadIdx.x;
    __shared__ float4 sj[64];
    __shared__ float aj[64];
    const float4* op = (const float4*)obox + (size_t)b * KC;
    int j0 = w * 64;
    int jl = j0 + lane;
    float4 vj = op[(jl < KC) ? jl : (KC - 1)];
    sj[lane] = vj;
    aj[lane] = __fmul_rn(__fsub_rn(vj.z, vj.x), __fsub_rn(vj.w, vj.y));
    int i = tile * 64 + lane;
    float4 bi = op[(i < KC) ? i : (KC - 1)];
    float ai = __fmul_rn(__fsub_rn(bi.z, bi.x), __fsub_rn(bi.w, bi.y));
    __syncthreads();
    unsigned long long bits = 0;
    int jmax = min(64, KC - j0);
    for (int jj = 0; jj < jmax; ++jj) {
        float4 bj = sj[jj];            // wave-uniform -> LDS broadcast
        float xx1 = fmaxf(bi.x, bj.x), yy1 = fmaxf(bi.y, bj.y);
        float xx2 = fminf(bi.z, bj.z), yy2 = fminf(bi.w, bj.w);
        float ww = fmaxf(__fsub_rn(xx2, xx1), 0.0f);
        float hh = fmaxf(__fsub_rn(yy2, yy1), 0.0f);
        float inter = __fmul_rn(ww, hh);
        float uni = __fsub_rn(__fadd_rn(ai, aj[jj]), inter);
        float iou = __fdiv_rn(inter, fmaxf(uni, 1e-9f));
        bool kp = ((j0 + jj) > i) && (iou > 0.6f);
        bits |= kp ? (1ull << jj) : 0ull;
    }
    if (i >= KC) bits = 0;
    MT[((size_t)b * WORDS + w) * KROWS + i] = bits;
}

// ---------------- K5c: pipelined pull-style greedy scan (1 wave/image) ----------------
__global__ __launch_bounds__(64) void k_nms(
        const unsigned long long* __restrict__ MT, const float* __restrict__ ssc,
        const int* __restrict__ slb, const float* __restrict__ sbox, float* __restrict__ out) {
    int b = blockIdx.x, lane = threadIdx.x;
    for (int k = lane; k < POSTN * 5; k += 64) out[(size_t)b * POSTN * 5 + k] = 0.0f;
    for (int k = lane; k < POSTN; k += 64) {
        out[(size_t)NB * POSTN * 5 + b * POSTN + k] = 0.0f;                 // labels
        out[(size_t)NB * POSTN * 5 + NB * POSTN + b * POSTN + k] = 0.0f;    // valid
    }
    const float* sp = ssc + b * KC;
    unsigned long long validV = 0;
    for (int c = 0; c < WORDS; ++c) {
        int i = c * 64 + lane;
        bool f = (i < KC) && (sp[i] > 0.0f);
        unsigned long long m = __ballot(f);
        validV = (lane == c) ? m : validV;
    }
    unsigned long long mybit = 1ull << lane;
    unsigned long long keptV = 0;
    const unsigned long long* Mb = MT + (size_t)b * WORDS * KROWS;

    unsigned long long pv[WORDS];
    pv[0] = Mb[lane];

    for (int t = 0; t < WORDS; ++t) {
        int tn = (t + 1 < WORDS) ? (t + 1) : t;
        const unsigned long long* cp = Mb + (size_t)tn * KROWS + lane;
        unsigned long long nv[WORDS];
        #pragma unroll
        for (int c = 0; c < WORDS; ++c) {
            int cc = (c <= tn) ? c : 0;
            nv[c] = cp[(size_t)cc * 64];
        }
        __builtin_amdgcn_sched_barrier(0);    // loads stay above; compute below

        unsigned long long D = pv[t];
        unsigned long long acc = 0;
        #pragma unroll
        for (int c = 0; c < WORDS; ++c) {
            if (c < t) {
                unsigned long long kc = readlane64(keptV, c);
                if (kc & mybit) acc |= pv[c];
            }
        }
        #pragma unroll
        for (int s = 1; s < 64; s <<= 1) acc |= __shfl_xor(acc, s, 64);

        unsigned long long validT = readlane64(validV, t);
        unsigned long long rem = acc;
        unsigned long long sup = __ballot(D != 0ull) & validT;
        unsigned long long todoS = sup;
        while (todoS) {
            int r = __builtin_ctzll(todoS);
            todoS &= todoS - 1;
            if (!((rem >> r) & 1ull)) {
                unsigned long long Dr = readlane64(D, r);
                rem |= Dr;
                todoS &= ~Dr;
            }
        }
        unsigned long long kept = validT & ~rem;
        keptV = (lane == t) ? kept : keptV;

        #pragma unroll
        for (int c = 0; c < WORDS; ++c) pv[c] = nv[c];
    }

    int base = 0;
    for (int c = 0; c < WORDS && base < POSTN; ++c) {
        unsigned long long kw = readlane64(keptV, c);
        bool f = (kw & mybit) != 0ull;
        int rank = base + __popcll(kw & (mybit - 1ull));
        if (f && rank < POSTN) {
            int i = c * 64 + lane;
            int src = b * KC + i;
            float* o5 = out + ((size_t)b * POSTN + rank) * 5;
            o5[0] = sbox[src * 4 + 0]; o5[1] = sbox[src * 4 + 1];
            o5[2] = sbox[src * 4 + 2]; o5[3] = sbox[src * 4 + 3];
            o5[4] = ssc[src];
            out[(size_t)NB * POSTN * 5 + b * POSTN + rank] = (float)slb[src];
            out[(size_t)NB * POSTN * 5 + NB * POSTN + b * POSTN + rank] = 1.0f;
        }
        base += __popcll(kw);
    }
}

// ---------------- launch ----------------
extern "C" void kernel_launch(void* const* d_in, const int* in_sizes, int n_in,
                              void* d_out, int out_size, void* d_ws, size_t ws_size,
                              hipStream_t stream) {
    const float *loc[5], *cls[5], *box[5], *ctr[5];
    for (int l = 0; l < 5; ++l) {
        loc[l] = (const float*)d_in[l * 4 + 0];
        cls[l] = (const float*)d_in[l * 4 + 1];
        box[l] = (const float*)d_in[l * 4 + 2];
        ctr[l] = (const float*)d_in[l * 4 + 3];
    }
    char* ws = (char*)d_ws;
    unsigned* hist = (unsigned*)(ws + OFF_HIST);
    unsigned* cnt  = (unsigned*)(ws + OFF_CNT);
    Cand* cand     = (Cand*)(ws + OFF_CAND);
    float* cbox    = (float*)(ws + OFF_CBOX);
    float* csc     = (float*)(ws + OFF_CSC);
    int*   clb     = (int*)(ws + OFF_CLB);
    float* ssc     = (float*)(ws + OFF_SSC);
    int*   slb     = (int*)(ws + OFF_SLB);
    float* sbox    = (float*)(ws + OFF_SBOX);
    float* obox    = (float*)(ws + OFF_OBOX);
    unsigned long long* MT = (unsigned long long*)(ws + OFF_M);
    float* sct     = (float*)(ws + OFF_SCT);
    unsigned short* gmx = (unsigned short*)(ws + OFF_GMX);
    float* out = (float*)d_out;

    int zn = (int)(OFF_CAND / 4);
    int initBlocks = (max(zn, SCTN) + THREADS - 1) / THREADS;
    k_init<<<initBlocks, THREADS, 0, stream>>>(
        ctr[0], ctr[1], ctr[2], ctr[3], ctr[4], sct, (unsigned*)ws, zn);
    k_hist<<<dim3(CHUNKS, NB), THREADS, 0, stream>>>(
        cls[0], cls[1], cls[2], cls[3], cls[4], sct, gmx, hist);
    k_collect<<<dim3(CHUNKS, NB), THREADS, 0, stream>>>(
        cls[0], cls[1], cls[2], cls[3], cls[4], sct, gmx, hist, cand, cnt);
    k_select<<<NPAIR, THREADS, 0, stream>>>(
        cand, cnt,
        loc[0], loc[1], loc[2], loc[3], loc[4],
        box[0], box[1], box[2], box[3], box[4],
        cbox, csc, clb);
    k_sortimg<<<NB, SORTT, 0, stream>>>(csc, clb, cbox, ssc, slb, sbox, obox);
    k_iou<<<dim3(WORDS, WORDS, NB), 64, 0, stream>>>(obox, MT);
    k_nms<<<NB, 64, 0, stream>>>(MT, ssc, slb, sbox, out);
}